// Round 1
// baseline (1806.910 us; speedup 1.0000x reference)
//
#include <hip/hip_runtime.h>
#include <hip/hip_bf16.h>
#include <math.h>

#define BATCH 2
#define SEQ 1024
#define HIDDIM 2048
#define NH 8
#define DKD 64
#define DVD 128
#define TKD 512
#define TVD 1024
#define NCOL 3088   // TK+TK+TV+H+H+TV
#define GHD 128
#define KSZ 4

__device__ __forceinline__ float sigm(float x){ return 1.f/(1.f+expf(-x)); }
__device__ __forceinline__ float siluf(float x){ return x/(1.f+expf(-x)); }

// ---------------- generic fp32 tiled GEMM, C = A(MxK) @ B(KxN) [+epilogue] ----
// EPI: 0 = none, 1 = silu, 2 = +bias
template<int BM,int BN,int BK,int TM,int TN,int EPI>
__global__ __launch_bounds__(256) void gemm_k(const float* __restrict__ A,
    const float* __restrict__ Bm, const float* __restrict__ bias,
    float* __restrict__ C, int M, int N, int K)
{
  __shared__ float As[BK][BM];
  __shared__ float Bs[BK][BN];
  const int tid = threadIdx.x;
  constexpr int NTX = BN/TN;
  const int tx = tid % NTX;
  const int ty = tid / NTX;
  const int row0 = blockIdx.y*BM;
  const int col0 = blockIdx.x*BN;
  float acc[TM][TN] = {};
  constexpr int AK4 = BK/4;
  constexpr int ALOADS = BM*AK4;       // number of float4 loads for A tile
  constexpr int BN4 = BN/4;
  constexpr int BLOADS = BK*BN4;
  const int arow = tid / AK4;
  const int ak4  = (tid % AK4)*4;
  const int brow = tid / BN4;
  const int bc4  = (tid % BN4)*4;

  for (int k0 = 0; k0 < K; k0 += BK) {
    if (tid < ALOADS) {
      float4 av = make_float4(0.f,0.f,0.f,0.f);
      int r = row0 + arow;
      if (r < M) av = *(const float4*)&A[(size_t)r*K + k0 + ak4];
      As[ak4+0][arow]=av.x; As[ak4+1][arow]=av.y;
      As[ak4+2][arow]=av.z; As[ak4+3][arow]=av.w;
    }
    if (tid < BLOADS) {
      float4 bv = make_float4(0.f,0.f,0.f,0.f);
      int c = col0 + bc4;
      if (c < N) bv = *(const float4*)&Bm[(size_t)(k0+brow)*N + c];
      *(float4*)&Bs[brow][bc4] = bv;
    }
    __syncthreads();
    #pragma unroll
    for (int kk = 0; kk < BK; ++kk) {
      float af[TM], bf[TN];
      #pragma unroll
      for (int i4 = 0; i4 < TM/4; ++i4) {
        float4 t = *(const float4*)&As[kk][ty*4 + i4*(BM*4/TM)];
        af[i4*4+0]=t.x; af[i4*4+1]=t.y; af[i4*4+2]=t.z; af[i4*4+3]=t.w;
      }
      #pragma unroll
      for (int j4 = 0; j4 < TN/4; ++j4) {
        float4 t = *(const float4*)&Bs[kk][tx*4 + j4*(BN*4/TN)];
        bf[j4*4+0]=t.x; bf[j4*4+1]=t.y; bf[j4*4+2]=t.z; bf[j4*4+3]=t.w;
      }
      #pragma unroll
      for (int i = 0; i < TM; ++i)
        #pragma unroll
        for (int j = 0; j < TN; ++j)
          acc[i][j] = fmaf(af[i], bf[j], acc[i][j]);
    }
    __syncthreads();
  }
  // epilogue (float4 stores; N is always a multiple of 4 here)
  #pragma unroll
  for (int i = 0; i < TM; ++i) {
    int r = row0 + ty*4 + (i/4)*(BM*4/TM) + (i%4);
    if (r >= M) continue;
    #pragma unroll
    for (int j4 = 0; j4 < TN/4; ++j4) {
      int c = col0 + tx*4 + j4*(BN*4/TN);
      if (c >= N) continue;
      float vals[4];
      #pragma unroll
      for (int u = 0; u < 4; ++u) {
        float v = acc[i][j4*4+u];
        if (EPI == 1) v = siluf(v);
        else if (EPI == 2) v += bias[c+u];
        vals[u] = v;
      }
      *(float4*)&C[(size_t)r*N + c] = make_float4(vals[0],vals[1],vals[2],vals[3]);
    }
  }
}

// ---------------- silu + l2norm for q,k; g and beta ------------------------
// one wave per (row, head); grid = B*S*H/4 blocks of 256
__global__ __launch_bounds__(256) void actv_k(const float* __restrict__ qkvabz,
    const float* __restrict__ A_log, const float* __restrict__ dt_bias,
    float* __restrict__ qn, float* __restrict__ kn,
    float* __restrict__ g, float* __restrict__ beta)
{
  int gid = blockIdx.x*4 + (threadIdx.x >> 6);   // 0 .. B*S*H-1
  int lane = threadIdx.x & 63;
  int row = gid >> 3; int h = gid & 7;
  const float* base = qkvabz + (size_t)row * NCOL;
  float qv = base[h*64 + lane];
  float kv = base[TKD + h*64 + lane];
  float sq = siluf(qv), sk = siluf(kv);
  float ssq = sq*sq, ssk = sk*sk;
  #pragma unroll
  for (int o = 32; o; o >>= 1) { ssq += __shfl_xor(ssq, o); ssk += __shfl_xor(ssk, o); }
  qn[(size_t)row*TKD + h*64 + lane] = sq * rsqrtf(ssq + 1e-6f) * 0.125f; // DK^-0.5
  kn[(size_t)row*TKD + h*64 + lane] = sk * rsqrtf(ssk + 1e-6f);
  if (lane == 0) {
    float av = base[2048 + h] + dt_bias[h];
    float sp = fmaxf(av, 0.f) + log1pf(expf(-fabsf(av)));   // stable softplus
    g[(size_t)row*NH + h] = -expf(A_log[h]) * sp;
    float bv = base[2056 + h];
    beta[(size_t)row*NH + h] = sigm(bv);
  }
}

// ---------------- dynamic conv --------------------------------------------
// one thread per (b,s,c); kern layout [(b*S+s)*TV + c]*4 + j
__global__ __launch_bounds__(256) void conv_k(const float* __restrict__ qkvabz,
   const float* __restrict__ kern, const float* __restrict__ conv_state,
   float* __restrict__ vconv)
{
  int idx = blockIdx.x*256 + threadIdx.x;      // 0 .. B*S*TV-1
  int c = idx & (TVD-1);
  int bs = idx >> 10;
  int s = bs & (SEQ-1); int b = bs >> 10;
  float4 kf = *(const float4*)&kern[(size_t)idx * 4];
  float kj[4] = {kf.x, kf.y, kf.z, kf.w};
  float acc = 0.f;
  #pragma unroll
  for (int j = 0; j < 4; ++j) {
    int i = s + j;
    float xv = (i < 3) ? conv_state[((size_t)b*TVD + c)*3 + i]
                       : qkvabz[((size_t)(b*SEQ + (i-3)))*NCOL + TKD*2 + c];
    acc = fmaf(xv, kj[j], acc);
  }
  vconv[idx] = siluf(acc);
}

// ---------------- gated delta rule scan ------------------------------------
// one block per (b,h); 512 threads: col v = tid>>2, quad = tid&3 owns 16 rows
__global__ __launch_bounds__(512) void scan_k(const float* __restrict__ qn,
   const float* __restrict__ kn, const float* __restrict__ vconv,
   const float* __restrict__ gb, const float* __restrict__ bb,
   const float* __restrict__ init, float* __restrict__ oattn)
{
  const int bh = blockIdx.x; const int b = bh >> 3; const int h = bh & 7;
  const int tid = threadIdx.x;
  const int v = tid >> 2;
  const int quad = tid & 3;
  const int r0 = quad*16;
  float hreg[16];
  #pragma unroll
  for (int r = 0; r < 16; ++r)
    hreg[r] = init[((size_t)bh*64 + r0 + r)*DVD + v];
  __shared__ float sK[64], sQ[64], sV[128], sGB[2];
  for (int s = 0; s < SEQ; ++s) {
    const size_t row = (size_t)b*SEQ + s;
    if (tid < 64)        sK[tid]      = kn[row*TKD + h*64 + tid];
    else if (tid < 128)  sQ[tid-64]   = qn[row*TKD + h*64 + (tid-64)];
    else if (tid < 256)  sV[tid-128]  = vconv[row*TVD + h*128 + (tid-128)];
    else if (tid == 256) sGB[0] = gb[row*NH + h];
    else if (tid == 257) sGB[1] = bb[row*NH + h];
    __syncthreads();
    const float eg = expf(sGB[0]);
    const float bet = sGB[1];
    float kf[16], qf[16];
    const float4* k4 = (const float4*)sK;
    const float4* q4 = (const float4*)sQ;
    #pragma unroll
    for (int i = 0; i < 4; ++i) {
      float4 t = k4[quad*4+i]; kf[i*4]=t.x; kf[i*4+1]=t.y; kf[i*4+2]=t.z; kf[i*4+3]=t.w;
      float4 u = q4[quad*4+i]; qf[i*4]=u.x; qf[i*4+1]=u.y; qf[i*4+2]=u.z; qf[i*4+3]=u.w;
    }
    float kvp = 0.f;
    #pragma unroll
    for (int r = 0; r < 16; ++r) { hreg[r] *= eg; kvp = fmaf(kf[r], hreg[r], kvp); }
    kvp += __shfl_xor(kvp, 1);
    kvp += __shfl_xor(kvp, 2);
    const float delta = (sV[v] - kvp) * bet;
    float op = 0.f;
    #pragma unroll
    for (int r = 0; r < 16; ++r) { hreg[r] = fmaf(kf[r], delta, hreg[r]); op = fmaf(qf[r], hreg[r], op); }
    op += __shfl_xor(op, 1);
    op += __shfl_xor(op, 2);
    if (quad == 0) oattn[row*TVD + h*128 + v] = op;
    __syncthreads();
  }
}

// ---------------- gated RMSNorm --------------------------------------------
// one wave per (row, head) of DV=128 (2 elems/lane)
__global__ __launch_bounds__(256) void norm_k(const float* __restrict__ oattn,
   const float* __restrict__ qkvabz, const float* __restrict__ onw,
   float* __restrict__ ofin)
{
  int gid = blockIdx.x*4 + (threadIdx.x >> 6);
  int lane = threadIdx.x & 63;
  int row = gid >> 3; int h = gid & 7;
  size_t ob = (size_t)row*TVD + h*128;
  float2 ov = *(const float2*)&oattn[ob + lane*2];
  float2 zv = *(const float2*)&qkvabz[(size_t)row*NCOL + 2064 + h*128 + lane*2];
  float g0 = ov.x * siluf(zv.x), g1 = ov.y * siluf(zv.y);
  float ss = g0*g0 + g1*g1;
  #pragma unroll
  for (int o = 32; o; o >>= 1) ss += __shfl_xor(ss, o);
  float r = rsqrtf(ss * (1.f/128.f) + 1e-6f);
  float2 outv;
  outv.x = g0 * r * onw[lane*2];
  outv.y = g1 * r * onw[lane*2+1];
  *(float2*)&ofin[ob + lane*2] = outv;
}

extern "C" void kernel_launch(void* const* d_in, const int* in_sizes, int n_in,
                              void* d_out, int out_size, void* d_ws, size_t ws_size,
                              hipStream_t stream) {
  const float* hidden     = (const float*)d_in[0];
  const float* Wqkvabz    = (const float*)d_in[1];
  const float* A_log      = (const float*)d_in[2];
  const float* dt_bias    = (const float*)d_in[3];
  const float* conv_state = (const float*)d_in[4];
  const float* w1         = (const float*)d_in[5];
  const float* w2         = (const float*)d_in[6];
  const float* b2         = (const float*)d_in[7];
  const float* init_state = (const float*)d_in[8];
  const float* o_norm_w   = (const float*)d_in[9];
  const float* W_o        = (const float*)d_in[10];
  float* out = (float*)d_out;

  float* ws = (float*)d_ws;
  float* qkvabz = ws;                                  // 2048*3088
  float* x1s    = qkvabz + (size_t)2048*3088;          // 2048*128
  float* kern   = x1s    + (size_t)2048*128;           // 2048*4096
  float* qn     = kern   + (size_t)2048*4096;          // 2048*512
  float* kn     = qn     + (size_t)2048*512;           // 2048*512
  float* gbuf   = kn     + (size_t)2048*512;           // 2048*8
  float* bbuf   = gbuf   + (size_t)2048*8;             // 2048*8
  float* vconv  = bbuf   + (size_t)2048*8;             // 2048*1024
  // kern is dead after conv_k -> reuse its space for oattn/ofin
  float* oattn  = kern;                                // 2048*1024
  float* ofin   = kern   + (size_t)2048*1024;          // 2048*1024

  dim3 blk(256);
  // 1. qkvabz = hidden @ W_qkvabz          (M=2048, N=3088, K=2048)
  gemm_k<128,128,8,8,8,0><<<dim3(25,16),blk,0,stream>>>(hidden, Wqkvabz, nullptr, qkvabz, 2048, 3088, 2048);
  // 2. x1s = silu(hidden @ w1)             (M=2048, N=128,  K=2048)
  gemm_k<64,64,8,4,4,1><<<dim3(2,32),blk,0,stream>>>(hidden, w1, nullptr, x1s, 2048, 128, 2048);
  // 3. kern = x1s @ w2 + b2                (M=2048, N=4096, K=128)
  gemm_k<128,128,8,8,8,2><<<dim3(32,16),blk,0,stream>>>(x1s, w2, b2, kern, 2048, 4096, 128);
  // 4. q/k silu+l2norm, g, beta
  actv_k<<<4096, 256, 0, stream>>>(qkvabz, A_log, dt_bias, qn, kn, gbuf, bbuf);
  // 5. dynamic conv -> vconv
  conv_k<<<8192, 256, 0, stream>>>(qkvabz, kern, conv_state, vconv);
  // 6. gated delta rule scan -> oattn
  scan_k<<<16, 512, 0, stream>>>(qn, kn, vconv, gbuf, bbuf, init_state, oattn);
  // 7. gated RMSNorm -> ofin
  norm_k<<<4096, 256, 0, stream>>>(oattn, qkvabz, o_norm_w, ofin);
  // 8. out = ofin @ W_o                    (M=2048, N=2048, K=1024)
  gemm_k<128,128,8,8,8,0><<<dim3(16,16),blk,0,stream>>>(ofin, W_o, nullptr, out, 2048, 2048, 1024);
}

// Round 2
// 1053.468 us; speedup vs baseline: 1.7152x; 1.7152x over previous
//
#include <hip/hip_runtime.h>
#include <hip/hip_bf16.h>
#include <math.h>

#define BATCH 2
#define SEQ 1024
#define HIDDIM 2048
#define NH 8
#define DKD 64
#define DVD 128
#define TKD 512
#define TVD 1024
#define NCOL 3088   // TK+TK+TV+H+H+TV
#define KSZ 4
#define NCHK 16     // chunks per (b,h), chunk size 64

__device__ __forceinline__ float sigm(float x){ return 1.f/(1.f+expf(-x)); }
__device__ __forceinline__ float siluf(float x){ return x/(1.f+expf(-x)); }

// ---------------- generic fp32 tiled GEMM, C = A(MxK) @ B(KxN) [+epilogue] ----
// EPI: 0 = none, 1 = silu, 2 = +bias
template<int BM,int BN,int BK,int TM,int TN,int EPI>
__global__ __launch_bounds__(256) void gemm_k(const float* __restrict__ A,
    const float* __restrict__ Bm, const float* __restrict__ bias,
    float* __restrict__ C, int M, int N, int K)
{
  __shared__ float As[BK][BM];
  __shared__ float Bs[BK][BN];
  const int tid = threadIdx.x;
  constexpr int NTX = BN/TN;
  const int tx = tid % NTX;
  const int ty = tid / NTX;
  const int row0 = blockIdx.y*BM;
  const int col0 = blockIdx.x*BN;
  float acc[TM][TN] = {};
  constexpr int AK4 = BK/4;
  constexpr int ALOADS = BM*AK4;
  constexpr int BN4 = BN/4;
  constexpr int BLOADS = BK*BN4;
  const int arow = tid / AK4;
  const int ak4  = (tid % AK4)*4;
  const int brow = tid / BN4;
  const int bc4  = (tid % BN4)*4;

  for (int k0 = 0; k0 < K; k0 += BK) {
    if (tid < ALOADS) {
      float4 av = make_float4(0.f,0.f,0.f,0.f);
      int r = row0 + arow;
      if (r < M) av = *(const float4*)&A[(size_t)r*K + k0 + ak4];
      As[ak4+0][arow]=av.x; As[ak4+1][arow]=av.y;
      As[ak4+2][arow]=av.z; As[ak4+3][arow]=av.w;
    }
    if (tid < BLOADS) {
      float4 bv = make_float4(0.f,0.f,0.f,0.f);
      int c = col0 + bc4;
      if (c < N) bv = *(const float4*)&Bm[(size_t)(k0+brow)*N + c];
      *(float4*)&Bs[brow][bc4] = bv;
    }
    __syncthreads();
    #pragma unroll
    for (int kk = 0; kk < BK; ++kk) {
      float af[TM], bf[TN];
      #pragma unroll
      for (int i4 = 0; i4 < TM/4; ++i4) {
        float4 t = *(const float4*)&As[kk][ty*4 + i4*(BM*4/TM)];
        af[i4*4+0]=t.x; af[i4*4+1]=t.y; af[i4*4+2]=t.z; af[i4*4+3]=t.w;
      }
      #pragma unroll
      for (int j4 = 0; j4 < TN/4; ++j4) {
        float4 t = *(const float4*)&Bs[kk][tx*4 + j4*(BN*4/TN)];
        bf[j4*4+0]=t.x; bf[j4*4+1]=t.y; bf[j4*4+2]=t.z; bf[j4*4+3]=t.w;
      }
      #pragma unroll
      for (int i = 0; i < TM; ++i)
        #pragma unroll
        for (int j = 0; j < TN; ++j)
          acc[i][j] = fmaf(af[i], bf[j], acc[i][j]);
    }
    __syncthreads();
  }
  #pragma unroll
  for (int i = 0; i < TM; ++i) {
    int r = row0 + ty*4 + (i/4)*(BM*4/TM) + (i%4);
    if (r >= M) continue;
    #pragma unroll
    for (int j4 = 0; j4 < TN/4; ++j4) {
      int c = col0 + tx*4 + j4*(BN*4/TN);
      if (c >= N) continue;
      float vals[4];
      #pragma unroll
      for (int u = 0; u < 4; ++u) {
        float v = acc[i][j4*4+u];
        if (EPI == 1) v = siluf(v);
        else if (EPI == 2) v += bias[c+u];
        vals[u] = v;
      }
      *(float4*)&C[(size_t)r*N + c] = make_float4(vals[0],vals[1],vals[2],vals[3]);
    }
  }
}

// ---------------- silu + l2norm for q,k; g and beta ------------------------
__global__ __launch_bounds__(256) void actv_k(const float* __restrict__ qkvabz,
    const float* __restrict__ A_log, const float* __restrict__ dt_bias,
    float* __restrict__ qn, float* __restrict__ kn,
    float* __restrict__ g, float* __restrict__ beta)
{
  int gid = blockIdx.x*4 + (threadIdx.x >> 6);
  int lane = threadIdx.x & 63;
  int row = gid >> 3; int h = gid & 7;
  const float* base = qkvabz + (size_t)row * NCOL;
  float qv = base[h*64 + lane];
  float kv = base[TKD + h*64 + lane];
  float sq = siluf(qv), sk = siluf(kv);
  float ssq = sq*sq, ssk = sk*sk;
  #pragma unroll
  for (int o = 32; o; o >>= 1) { ssq += __shfl_xor(ssq, o); ssk += __shfl_xor(ssk, o); }
  qn[(size_t)row*TKD + h*64 + lane] = sq * rsqrtf(ssq + 1e-6f) * 0.125f;
  kn[(size_t)row*TKD + h*64 + lane] = sk * rsqrtf(ssk + 1e-6f);
  if (lane == 0) {
    float av = base[2048 + h] + dt_bias[h];
    float sp = fmaxf(av, 0.f) + log1pf(expf(-fabsf(av)));
    g[(size_t)row*NH + h] = -expf(A_log[h]) * sp;
    float bv = base[2056 + h];
    beta[(size_t)row*NH + h] = sigm(bv);
  }
}

// ---------------- dynamic conv --------------------------------------------
__global__ __launch_bounds__(256) void conv_k(const float* __restrict__ qkvabz,
   const float* __restrict__ kern, const float* __restrict__ conv_state,
   float* __restrict__ vconv)
{
  int idx = blockIdx.x*256 + threadIdx.x;
  int c = idx & (TVD-1);
  int bs = idx >> 10;
  int s = bs & (SEQ-1); int b = bs >> 10;
  float4 kf = *(const float4*)&kern[(size_t)idx * 4];
  float kj[4] = {kf.x, kf.y, kf.z, kf.w};
  float acc = 0.f;
  #pragma unroll
  for (int j = 0; j < 4; ++j) {
    int i = s + j;
    float xv = (i < 3) ? conv_state[((size_t)b*TVD + c)*3 + i]
                       : qkvabz[((size_t)(b*SEQ + (i-3)))*NCOL + TKD*2 + c];
    acc = fmaf(xv, kj[j], acc);
  }
  vconv[idx] = siluf(acc);
}

// ============ chunked gated delta rule =====================================
// Phase A: per (bh, chunk): build A, solve (I+A)[Xv|Xw] = [bV | bEK]
// 256 blocks x 256 threads
__global__ __launch_bounds__(256) void chunkA_k(const float* __restrict__ kn,
   const float* __restrict__ vconv, const float* __restrict__ gb,
   const float* __restrict__ bb, float* __restrict__ Uv,
   float* __restrict__ Wbuf, float* __restrict__ Gcbuf)
{
  const int blk = blockIdx.x;          // bh*16 + c
  const int bh = blk >> 4, c = blk & 15;
  const int b = bh >> 3, h = bh & 7;
  const int tid = threadIdx.x;
  const int row0 = b*SEQ + c*64;
  __shared__ float Ksh[64][65];
  __shared__ float Xv[64][129];
  __shared__ float Xw[64][65];
  __shared__ float Ash[64][65];
  __shared__ float Gsh[64], Bsh[64];

  #pragma unroll
  for (int i = 0; i < 4; ++i) {
    int lin = tid + i*256; int t = lin >> 4, d4 = (lin & 15)*4;
    float4 kv = *(const float4*)&kn[(size_t)(row0+t)*TKD + h*64 + d4];
    Ksh[t][d4]=kv.x; Ksh[t][d4+1]=kv.y; Ksh[t][d4+2]=kv.z; Ksh[t][d4+3]=kv.w;
  }
  #pragma unroll
  for (int i = 0; i < 8; ++i) {
    int lin = tid + i*256; int t = lin >> 5, v4 = (lin & 31)*4;
    float4 vv = *(const float4*)&vconv[(size_t)(row0+t)*TVD + h*128 + v4];
    Xv[t][v4]=vv.x; Xv[t][v4+1]=vv.y; Xv[t][v4+2]=vv.z; Xv[t][v4+3]=vv.w;
  }
  if (tid < 64) {
    float gv = gb[(size_t)(row0+tid)*NH + h];
    #pragma unroll
    for (int o = 1; o < 64; o <<= 1) {
      float oth = __shfl_up(gv, o);
      if (tid >= o) gv += oth;
    }
    Gsh[tid] = gv;
    Bsh[tid] = bb[(size_t)(row0+tid)*NH + h];
    Gcbuf[(size_t)blk*64 + tid] = gv;
  }
  __syncthreads();

  // A[t][s] = beta_t * exp(G_t - G_s) * (k_t . k_s), s < t
  #pragma unroll
  for (int i = 0; i < 16; ++i) {
    int e = tid + i*256; int t = e >> 6, s = e & 63;
    float val = 0.f;
    if (s < t) {
      float acc = 0.f;
      #pragma unroll 8
      for (int d = 0; d < 64; ++d) acc = fmaf(Ksh[t][d], Ksh[s][d], acc);
      val = Bsh[t] * expf(Gsh[t] - Gsh[s]) * acc;
    }
    Ash[t][s] = val;
  }
  // RHS: Xv *= beta ; Xw = beta * exp(G) * K
  #pragma unroll
  for (int i = 0; i < 8; ++i) {
    int lin = tid + i*256; int t = lin >> 5, v4 = (lin & 31)*4;
    float bt = Bsh[t];
    Xv[t][v4]*=bt; Xv[t][v4+1]*=bt; Xv[t][v4+2]*=bt; Xv[t][v4+3]*=bt;
  }
  #pragma unroll
  for (int i = 0; i < 4; ++i) {
    int lin = tid + i*256; int t = lin >> 4, d4 = (lin & 15)*4;
    float f = Bsh[t]*expf(Gsh[t]);
    Xw[t][d4+0]=f*Ksh[t][d4+0]; Xw[t][d4+1]=f*Ksh[t][d4+1];
    Xw[t][d4+2]=f*Ksh[t][d4+2]; Xw[t][d4+3]=f*Ksh[t][d4+3];
  }
  __syncthreads();

  // forward substitution: thread j owns one column (128 V cols + 64 W cols)
  if (tid < 192) {
    float* colp; int stride;
    if (tid < 128) { colp = &Xv[0][tid];     stride = 129; }
    else           { colp = &Xw[0][tid-128]; stride = 65;  }
    for (int t = 1; t < 64; ++t) {
      float a0 = 0.f, a1 = 0.f;
      int s = 0;
      for (; s + 1 < t; s += 2) {
        a0 = fmaf(Ash[t][s],   colp[s*stride],     a0);
        a1 = fmaf(Ash[t][s+1], colp[(s+1)*stride], a1);
      }
      if (s < t) a0 = fmaf(Ash[t][s], colp[s*stride], a0);
      colp[t*stride] -= (a0 + a1);
    }
  }
  __syncthreads();

  #pragma unroll
  for (int i = 0; i < 8; ++i) {
    int lin = tid + i*256; int t = lin >> 5, v4 = (lin & 31)*4;
    *(float4*)&Uv[((size_t)blk*64 + t)*128 + v4] =
      make_float4(Xv[t][v4],Xv[t][v4+1],Xv[t][v4+2],Xv[t][v4+3]);
  }
  #pragma unroll
  for (int i = 0; i < 4; ++i) {
    int lin = tid + i*256; int t = lin >> 4, d4 = (lin & 15)*4;
    *(float4*)&Wbuf[((size_t)blk*64 + t)*64 + d4] =
      make_float4(Xw[t][d4],Xw[t][d4+1],Xw[t][d4+2],Xw[t][d4+3]);
  }
}

// Phase B: sequential over 16 chunks; 128 blocks (bh x 8 col-groups of 16)
// writes Hc (chunk-initial states) and overwrites Uv with Uc = Uv - W*h
__global__ __launch_bounds__(256) void chunkB_k(const float* __restrict__ kn,
   float* __restrict__ Uv, const float* __restrict__ Wbuf,
   const float* __restrict__ Gcbuf, const float* __restrict__ init,
   float* __restrict__ Hc)
{
  const int blk = blockIdx.x;          // bh*8 + grp
  const int bh = blk >> 3, grp = blk & 7;
  const int b = bh >> 3, h = bh & 7;
  const int v0 = grp*16;
  const int tid = threadIdx.x;
  __shared__ float hsh[64][17];
  __shared__ float Wsh[64][65];
  __shared__ float Kw[64][65];
  __shared__ float Ut[64][17];
  __shared__ float ush[64][17];

  #pragma unroll
  for (int i = 0; i < 4; ++i) {
    int cell = tid + i*256; int d = cell >> 4, v = cell & 15;
    hsh[d][v] = init[((size_t)bh*64 + d)*128 + v0 + v];
  }
  __syncthreads();

  for (int c = 0; c < 16; ++c) {
    const int cblk = bh*16 + c;
    const float* gcp = Gcbuf + (size_t)cblk*64;
    const float Gtot = gcp[63];
    const int row0 = b*SEQ + c*64;
    #pragma unroll
    for (int i = 0; i < 4; ++i) {
      int lin = tid + i*256; int t = lin >> 4, d4 = (lin & 15)*4;
      float4 wv = *(const float4*)&Wbuf[((size_t)cblk*64 + t)*64 + d4];
      Wsh[t][d4]=wv.x; Wsh[t][d4+1]=wv.y; Wsh[t][d4+2]=wv.z; Wsh[t][d4+3]=wv.w;
      float f = expf(Gtot - gcp[t]);
      float4 kv = *(const float4*)&kn[(size_t)(row0+t)*TKD + h*64 + d4];
      Kw[t][d4]=f*kv.x; Kw[t][d4+1]=f*kv.y; Kw[t][d4+2]=f*kv.z; Kw[t][d4+3]=f*kv.w;
    }
    {
      int t = tid >> 2, v4 = (tid & 3)*4;
      float4 uv = *(const float4*)&Uv[((size_t)cblk*64 + t)*128 + v0 + v4];
      Ut[t][v4]=uv.x; Ut[t][v4+1]=uv.y; Ut[t][v4+2]=uv.z; Ut[t][v4+3]=uv.w;
    }
    #pragma unroll
    for (int i = 0; i < 4; ++i) {
      int cell = tid + i*256; int d = cell >> 4, v = cell & 15;
      Hc[((size_t)cblk*64 + d)*128 + v0 + v] = hsh[d][v];
    }
    __syncthreads();
    // u = Ut - W*h
    #pragma unroll
    for (int i = 0; i < 4; ++i) {
      int cell = tid + i*256; int t = cell >> 4, v = cell & 15;
      float acc = 0.f;
      #pragma unroll 8
      for (int d = 0; d < 64; ++d) acc = fmaf(Wsh[t][d], hsh[d][v], acc);
      ush[t][v] = Ut[t][v] - acc;
    }
    __syncthreads();
    // write Uc back over Uv; update h = eG*h + Kw^T u
    {
      int t = tid >> 2, v4 = (tid & 3)*4;
      *(float4*)&Uv[((size_t)cblk*64 + t)*128 + v0 + v4] =
        make_float4(ush[t][v4],ush[t][v4+1],ush[t][v4+2],ush[t][v4+3]);
    }
    const float eG = expf(Gtot);
    #pragma unroll
    for (int i = 0; i < 4; ++i) {
      int cell = tid + i*256; int d = cell >> 4, v = cell & 15;
      float acc = 0.f;
      #pragma unroll 8
      for (int t = 0; t < 64; ++t) acc = fmaf(Kw[t][d], ush[t][v], acc);
      hsh[d][v] = eG*hsh[d][v] + acc;
    }
    __syncthreads();
  }
}

// Phase C: per (bh, chunk): O = exp(G)*(Q h_c) + S * Uc ; 256 blocks
__global__ __launch_bounds__(256) void chunkC_k(const float* __restrict__ qn,
   const float* __restrict__ kn, const float* __restrict__ Uc,
   const float* __restrict__ Gcbuf, const float* __restrict__ Hc,
   float* __restrict__ oattn)
{
  const int blk = blockIdx.x; const int bh = blk >> 4, c = blk & 15;
  const int b = bh >> 3, h = bh & 7;
  const int row0 = b*SEQ + c*64;
  const int tid = threadIdx.x;
  __shared__ float Qsh[64][65];
  __shared__ float KS[64][65];     // K, then overwritten by S
  __shared__ float hsh[64][129];
  __shared__ float Ush[64][129];
  __shared__ float Gsh[64];

  #pragma unroll
  for (int i = 0; i < 4; ++i) {
    int lin = tid + i*256; int t = lin >> 4, d4 = (lin & 15)*4;
    float4 qv = *(const float4*)&qn[(size_t)(row0+t)*TKD + h*64 + d4];
    Qsh[t][d4]=qv.x; Qsh[t][d4+1]=qv.y; Qsh[t][d4+2]=qv.z; Qsh[t][d4+3]=qv.w;
    float4 kv = *(const float4*)&kn[(size_t)(row0+t)*TKD + h*64 + d4];
    KS[t][d4]=kv.x; KS[t][d4+1]=kv.y; KS[t][d4+2]=kv.z; KS[t][d4+3]=kv.w;
  }
  #pragma unroll
  for (int i = 0; i < 8; ++i) {
    int lin = tid + i*256; int d = lin >> 5, v4 = (lin & 31)*4;
    float4 hv = *(const float4*)&Hc[((size_t)blk*64 + d)*128 + v4];
    hsh[d][v4]=hv.x; hsh[d][v4+1]=hv.y; hsh[d][v4+2]=hv.z; hsh[d][v4+3]=hv.w;
    float4 uv = *(const float4*)&Uc[((size_t)blk*64 + d)*128 + v4];
    Ush[d][v4]=uv.x; Ush[d][v4+1]=uv.y; Ush[d][v4+2]=uv.z; Ush[d][v4+3]=uv.w;
  }
  if (tid < 64) Gsh[tid] = Gcbuf[(size_t)blk*64 + tid];
  __syncthreads();

  float sreg[16];
  #pragma unroll
  for (int i = 0; i < 16; ++i) {
    int e = tid + i*256; int t = e >> 6, s = e & 63;
    float val = 0.f;
    if (s <= t) {
      float acc = 0.f;
      #pragma unroll 8
      for (int d = 0; d < 64; ++d) acc = fmaf(Qsh[t][d], KS[s][d], acc);
      val = expf(Gsh[t] - Gsh[s]) * acc;
    }
    sreg[i] = val;
  }
  __syncthreads();
  #pragma unroll
  for (int i = 0; i < 16; ++i) { int e = tid + i*256; KS[e>>6][e&63] = sreg[i]; }
  __syncthreads();

  #pragma unroll
  for (int i = 0; i < 32; ++i) {
    int e = tid + i*256; int t = e >> 7, v = e & 127;
    float a1 = 0.f, a2 = 0.f;
    #pragma unroll 8
    for (int d = 0; d < 64; ++d) a1 = fmaf(Qsh[t][d], hsh[d][v], a1);
    #pragma unroll 8
    for (int s = 0; s < 64; ++s) a2 = fmaf(KS[t][s], Ush[s][v], a2);
    oattn[(size_t)(row0+t)*TVD + h*128 + v] = expf(Gsh[t])*a1 + a2;
  }
}

// ---------------- gated RMSNorm --------------------------------------------
__global__ __launch_bounds__(256) void norm_k(const float* __restrict__ oattn,
   const float* __restrict__ qkvabz, const float* __restrict__ onw,
   float* __restrict__ ofin)
{
  int gid = blockIdx.x*4 + (threadIdx.x >> 6);
  int lane = threadIdx.x & 63;
  int row = gid >> 3; int h = gid & 7;
  size_t ob = (size_t)row*TVD + h*128;
  float2 ov = *(const float2*)&oattn[ob + lane*2];
  float2 zv = *(const float2*)&qkvabz[(size_t)row*NCOL + 2064 + h*128 + lane*2];
  float g0 = ov.x * siluf(zv.x), g1 = ov.y * siluf(zv.y);
  float ss = g0*g0 + g1*g1;
  #pragma unroll
  for (int o = 32; o; o >>= 1) ss += __shfl_xor(ss, o);
  float r = rsqrtf(ss * (1.f/128.f) + 1e-6f);
  float2 outv;
  outv.x = g0 * r * onw[lane*2];
  outv.y = g1 * r * onw[lane*2+1];
  *(float2*)&ofin[ob + lane*2] = outv;
}

extern "C" void kernel_launch(void* const* d_in, const int* in_sizes, int n_in,
                              void* d_out, int out_size, void* d_ws, size_t ws_size,
                              hipStream_t stream) {
  const float* hidden     = (const float*)d_in[0];
  const float* Wqkvabz    = (const float*)d_in[1];
  const float* A_log      = (const float*)d_in[2];
  const float* dt_bias    = (const float*)d_in[3];
  const float* conv_state = (const float*)d_in[4];
  const float* w1         = (const float*)d_in[5];
  const float* w2         = (const float*)d_in[6];
  const float* b2         = (const float*)d_in[7];
  const float* init_state = (const float*)d_in[8];
  const float* o_norm_w   = (const float*)d_in[9];
  const float* W_o        = (const float*)d_in[10];
  float* out = (float*)d_out;

  float* ws = (float*)d_ws;
  float* qkvabz = ws;                                  // 2048*3088
  float* x1s    = qkvabz + (size_t)2048*3088;          // 2048*128
  float* kern   = x1s    + (size_t)2048*128;           // 2048*4096
  float* qn     = kern   + (size_t)2048*4096;          // 2048*512
  float* kn     = qn     + (size_t)2048*512;           // 2048*512
  float* gbuf   = kn     + (size_t)2048*512;           // 2048*8
  float* bbuf   = gbuf   + (size_t)2048*8;             // 2048*8
  float* vconv  = bbuf   + (size_t)2048*8;             // 2048*1024
  // aliases in dead regions:
  float* oattn  = kern;                                // 2M floats
  float* ofin   = kern + (size_t)2097152;              // 2M
  float* Uv     = kern + (size_t)4194304;              // 2M  (becomes Uc)
  float* Wbuf   = kern + (size_t)6291456;              // 1M
  float* Gcbuf  = kern + (size_t)7340032;              // 16K
  float* Hc     = vconv;                               // 2M (vconv dead after chunkA)

  dim3 blk(256);
  gemm_k<128,128,8,8,8,0><<<dim3(25,16),blk,0,stream>>>(hidden, Wqkvabz, nullptr, qkvabz, 2048, 3088, 2048);
  gemm_k<64,64,8,4,4,1><<<dim3(2,32),blk,0,stream>>>(hidden, w1, nullptr, x1s, 2048, 128, 2048);
  gemm_k<128,128,8,8,8,2><<<dim3(32,16),blk,0,stream>>>(x1s, w2, b2, kern, 2048, 4096, 128);
  actv_k<<<4096, 256, 0, stream>>>(qkvabz, A_log, dt_bias, qn, kn, gbuf, bbuf);
  conv_k<<<8192, 256, 0, stream>>>(qkvabz, kern, conv_state, vconv);
  chunkA_k<<<256, 256, 0, stream>>>(kn, vconv, gbuf, bbuf, Uv, Wbuf, Gcbuf);
  chunkB_k<<<128, 256, 0, stream>>>(kn, Uv, Wbuf, Gcbuf, init_state, Hc);
  chunkC_k<<<256, 256, 0, stream>>>(qn, kn, Uv, Gcbuf, Hc, oattn);
  norm_k<<<4096, 256, 0, stream>>>(oattn, qkvabz, o_norm_w, ofin);
  gemm_k<128,128,8,8,8,0><<<dim3(16,16),blk,0,stream>>>(ofin, W_o, nullptr, out, 2048, 2048, 1024);
}

// Round 3
// 415.865 us; speedup vs baseline: 4.3449x; 2.5332x over previous
//
#include <hip/hip_runtime.h>
#include <hip/hip_bf16.h>
#include <math.h>
#include <stdint.h>

#define BATCH 2
#define SEQ 1024
#define HIDDIM 2048
#define NH 8
#define DKD 64
#define DVD 128
#define TKD 512
#define TVD 1024
#define NCOL 3088   // TK+TK+TV+H+H+TV
#define KSZ 4
#define NCHK 16

typedef __attribute__((ext_vector_type(8))) short bf16x8;
typedef __attribute__((ext_vector_type(4))) float f32x4;

__device__ __forceinline__ float sigm(float x){ return 1.f/(1.f+expf(-x)); }
__device__ __forceinline__ float siluf(float x){ return x/(1.f+expf(-x)); }

__device__ __forceinline__ void glds16(const __hip_bfloat16* g, void* l) {
  __builtin_amdgcn_global_load_lds((const __attribute__((address_space(1))) void*)g,
                                   (__attribute__((address_space(3))) void*)l, 16, 0, 0);
}

// ---------------- casts -----------------------------------------------------
__global__ __launch_bounds__(256) void cast_k(const float* __restrict__ in,
    unsigned short* __restrict__ out, int n4)
{
  int i = blockIdx.x*256 + threadIdx.x;
  if (i >= n4) return;
  float4 v = ((const float4*)in)[i];
  __hip_bfloat16 h0 = __float2bfloat16(v.x), h1 = __float2bfloat16(v.y);
  __hip_bfloat16 h2 = __float2bfloat16(v.z), h3 = __float2bfloat16(v.w);
  ushort4 o;
  o.x = *(unsigned short*)&h0; o.y = *(unsigned short*)&h1;
  o.z = *(unsigned short*)&h2; o.w = *(unsigned short*)&h3;
  ((ushort4*)out)[i] = o;
}

// transpose + cast: in fp32 [R][C] -> out bf16 [Cpad][R] (pad rows zero)
__global__ __launch_bounds__(256) void tcast_k(const float* __restrict__ in,
    __hip_bfloat16* __restrict__ out, int R, int C, int Cpad)
{
  __shared__ float tile[32][33];
  const int tx = threadIdx.x & 31, ty = threadIdx.x >> 5;
  const int c = blockIdx.x*32 + tx;
  #pragma unroll
  for (int i = 0; i < 4; ++i) {
    int r = blockIdx.y*32 + ty + i*8;
    tile[ty + i*8][tx] = (c < C) ? in[(size_t)r*C + c] : 0.f;
  }
  __syncthreads();
  #pragma unroll
  for (int i = 0; i < 4; ++i) {
    int orow = blockIdx.x*32 + ty + i*8;   // = original col
    int ocol = blockIdx.y*32 + tx;         // = original row
    out[(size_t)orow*R + ocol] = __float2bfloat16(tile[tx][ty + i*8]);
  }
}

// ---------------- bf16 MFMA GEMM: C = A[M][K] @ Bt[N][K]^T ------------------
// EPI: 0 = fp32 out, 1 = silu -> bf16 out, 2 = +bias -> fp32 out
template<int EPI>
__global__ __launch_bounds__(256) void mgemm_k(
    const __hip_bfloat16* __restrict__ A,
    const __hip_bfloat16* __restrict__ Bt,
    const float* __restrict__ bias,
    float* __restrict__ Cf, __hip_bfloat16* __restrict__ Cb,
    int M, int N, int K)
{
  __shared__ __hip_bfloat16 As[128*32];
  __shared__ __hip_bfloat16 Bs[128*32];
  const int tid = threadIdx.x;
  const int w = tid >> 6, l = tid & 63;
  const int wr = w >> 1, wc = w & 1;
  const int row0 = blockIdx.y*128, col0 = blockIdx.x*128;
  const int fr = l & 15, fq = l >> 4;

  f32x4 acc[4][4];
  #pragma unroll
  for (int m = 0; m < 4; ++m)
    #pragma unroll
    for (int n = 0; n < 4; ++n)
      acc[m][n] = (f32x4){0.f,0.f,0.f,0.f};

  // staging: tile [128][32] bf16 linear; 2 issues of 256thr*16B each
  const int e0 = w*512 + l*8;          // element offset, issue 0
  const int r0s = e0 >> 5, c0s = e0 & 31;

  for (int k0 = 0; k0 < K; k0 += 32) {
    glds16(&A[(size_t)(row0 + r0s)*K + k0 + c0s],       (char*)As + w*1024);
    glds16(&A[(size_t)(row0 + r0s + 64)*K + k0 + c0s],  (char*)As + 4096 + w*1024);
    glds16(&Bt[(size_t)(col0 + r0s)*K + k0 + c0s],      (char*)Bs + w*1024);
    glds16(&Bt[(size_t)(col0 + r0s + 64)*K + k0 + c0s], (char*)Bs + 4096 + w*1024);
    __syncthreads();

    bf16x8 af[4], bfv[4];
    #pragma unroll
    for (int m = 0; m < 4; ++m)
      af[m] = *(const bf16x8*)&As[(wr*64 + m*16 + fr)*32 + fq*8];
    #pragma unroll
    for (int n = 0; n < 4; ++n)
      bfv[n] = *(const bf16x8*)&Bs[(wc*64 + n*16 + fr)*32 + fq*8];
    #pragma unroll
    for (int m = 0; m < 4; ++m)
      #pragma unroll
      for (int n = 0; n < 4; ++n)
        acc[m][n] = __builtin_amdgcn_mfma_f32_16x16x32_bf16(af[m], bfv[n], acc[m][n], 0, 0, 0);
    __syncthreads();
  }

  // epilogue: D col = lane&15, row = (lane>>4)*4 + reg
  #pragma unroll
  for (int n = 0; n < 4; ++n) {
    const int ccol = col0 + wc*64 + n*16 + fr;
    if (ccol >= N) continue;
    #pragma unroll
    for (int m = 0; m < 4; ++m) {
      #pragma unroll
      for (int r = 0; r < 4; ++r) {
        const int crow = row0 + wr*64 + m*16 + fq*4 + r;
        float v = acc[m][n][r];
        if (EPI == 2) v += bias[ccol];
        if (EPI == 1) Cb[(size_t)crow*N + ccol] = __float2bfloat16(siluf(v));
        else          Cf[(size_t)crow*N + ccol] = v;
      }
    }
  }
}

// ---------------- silu + l2norm for q,k; g and beta ------------------------
__global__ __launch_bounds__(256) void actv_k(const float* __restrict__ qkvabz,
    const float* __restrict__ A_log, const float* __restrict__ dt_bias,
    float* __restrict__ qn, float* __restrict__ kn,
    float* __restrict__ g, float* __restrict__ beta)
{
  int gid = blockIdx.x*4 + (threadIdx.x >> 6);
  int lane = threadIdx.x & 63;
  int row = gid >> 3; int h = gid & 7;
  const float* base = qkvabz + (size_t)row * NCOL;
  float qv = base[h*64 + lane];
  float kv = base[TKD + h*64 + lane];
  float sq = siluf(qv), sk = siluf(kv);
  float ssq = sq*sq, ssk = sk*sk;
  #pragma unroll
  for (int o = 32; o; o >>= 1) { ssq += __shfl_xor(ssq, o); ssk += __shfl_xor(ssk, o); }
  qn[(size_t)row*TKD + h*64 + lane] = sq * rsqrtf(ssq + 1e-6f) * 0.125f;
  kn[(size_t)row*TKD + h*64 + lane] = sk * rsqrtf(ssk + 1e-6f);
  if (lane == 0) {
    float av = base[2048 + h] + dt_bias[h];
    float sp = fmaxf(av, 0.f) + log1pf(expf(-fabsf(av)));
    g[(size_t)row*NH + h] = -expf(A_log[h]) * sp;
    float bv = base[2056 + h];
    beta[(size_t)row*NH + h] = sigm(bv);
  }
}

// ---------------- dynamic conv --------------------------------------------
__global__ __launch_bounds__(256) void conv_k(const float* __restrict__ qkvabz,
   const float* __restrict__ kern, const float* __restrict__ conv_state,
   float* __restrict__ vconv)
{
  int idx = blockIdx.x*256 + threadIdx.x;
  int c = idx & (TVD-1);
  int bs = idx >> 10;
  int s = bs & (SEQ-1); int b = bs >> 10;
  float4 kf = *(const float4*)&kern[(size_t)idx * 4];
  float kj[4] = {kf.x, kf.y, kf.z, kf.w};
  float acc = 0.f;
  #pragma unroll
  for (int j = 0; j < 4; ++j) {
    int i = s + j;
    float xv = (i < 3) ? conv_state[((size_t)b*TVD + c)*3 + i]
                       : qkvabz[((size_t)(b*SEQ + (i-3)))*NCOL + TKD*2 + c];
    acc = fmaf(xv, kj[j], acc);
  }
  vconv[idx] = siluf(acc);
}

// ============ chunked gated delta rule =====================================
__global__ __launch_bounds__(256) void chunkA_k(const float* __restrict__ kn,
   const float* __restrict__ vconv, const float* __restrict__ gb,
   const float* __restrict__ bb, float* __restrict__ Uv,
   float* __restrict__ Wbuf, float* __restrict__ Gcbuf)
{
  const int blk = blockIdx.x;
  const int bh = blk >> 4, c = blk & 15;
  const int b = bh >> 3, h = bh & 7;
  const int tid = threadIdx.x;
  const int row0 = b*SEQ + c*64;
  __shared__ float Ksh[64][65];
  __shared__ float Xv[64][129];
  __shared__ float Xw[64][65];
  __shared__ float Ash[64][65];
  __shared__ float Gsh[64], Bsh[64];

  #pragma unroll
  for (int i = 0; i < 4; ++i) {
    int lin = tid + i*256; int t = lin >> 4, d4 = (lin & 15)*4;
    float4 kv = *(const float4*)&kn[(size_t)(row0+t)*TKD + h*64 + d4];
    Ksh[t][d4]=kv.x; Ksh[t][d4+1]=kv.y; Ksh[t][d4+2]=kv.z; Ksh[t][d4+3]=kv.w;
  }
  #pragma unroll
  for (int i = 0; i < 8; ++i) {
    int lin = tid + i*256; int t = lin >> 5, v4 = (lin & 31)*4;
    float4 vv = *(const float4*)&vconv[(size_t)(row0+t)*TVD + h*128 + v4];
    Xv[t][v4]=vv.x; Xv[t][v4+1]=vv.y; Xv[t][v4+2]=vv.z; Xv[t][v4+3]=vv.w;
  }
  if (tid < 64) {
    float gv = gb[(size_t)(row0+tid)*NH + h];
    #pragma unroll
    for (int o = 1; o < 64; o <<= 1) {
      float oth = __shfl_up(gv, o);
      if (tid >= o) gv += oth;
    }
    Gsh[tid] = gv;
    Bsh[tid] = bb[(size_t)(row0+tid)*NH + h];
    Gcbuf[(size_t)blk*64 + tid] = gv;
  }
  __syncthreads();

  #pragma unroll
  for (int i = 0; i < 16; ++i) {
    int e = tid + i*256; int t = e >> 6, s = e & 63;
    float val = 0.f;
    if (s < t) {
      float acc = 0.f;
      #pragma unroll 8
      for (int d = 0; d < 64; ++d) acc = fmaf(Ksh[t][d], Ksh[s][d], acc);
      val = Bsh[t] * expf(Gsh[t] - Gsh[s]) * acc;
    }
    Ash[t][s] = val;
  }
  #pragma unroll
  for (int i = 0; i < 8; ++i) {
    int lin = tid + i*256; int t = lin >> 5, v4 = (lin & 31)*4;
    float bt = Bsh[t];
    Xv[t][v4]*=bt; Xv[t][v4+1]*=bt; Xv[t][v4+2]*=bt; Xv[t][v4+3]*=bt;
  }
  #pragma unroll
  for (int i = 0; i < 4; ++i) {
    int lin = tid + i*256; int t = lin >> 4, d4 = (lin & 15)*4;
    float f = Bsh[t]*expf(Gsh[t]);
    Xw[t][d4+0]=f*Ksh[t][d4+0]; Xw[t][d4+1]=f*Ksh[t][d4+1];
    Xw[t][d4+2]=f*Ksh[t][d4+2]; Xw[t][d4+3]=f*Ksh[t][d4+3];
  }
  __syncthreads();

  if (tid < 192) {
    float* colp; int stride;
    if (tid < 128) { colp = &Xv[0][tid];     stride = 129; }
    else           { colp = &Xw[0][tid-128]; stride = 65;  }
    for (int t = 1; t < 64; ++t) {
      float a0 = 0.f, a1 = 0.f;
      int s = 0;
      for (; s + 1 < t; s += 2) {
        a0 = fmaf(Ash[t][s],   colp[s*stride],     a0);
        a1 = fmaf(Ash[t][s+1], colp[(s+1)*stride], a1);
      }
      if (s < t) a0 = fmaf(Ash[t][s], colp[s*stride], a0);
      colp[t*stride] -= (a0 + a1);
    }
  }
  __syncthreads();

  #pragma unroll
  for (int i = 0; i < 8; ++i) {
    int lin = tid + i*256; int t = lin >> 5, v4 = (lin & 31)*4;
    *(float4*)&Uv[((size_t)blk*64 + t)*128 + v4] =
      make_float4(Xv[t][v4],Xv[t][v4+1],Xv[t][v4+2],Xv[t][v4+3]);
  }
  #pragma unroll
  for (int i = 0; i < 4; ++i) {
    int lin = tid + i*256; int t = lin >> 4, d4 = (lin & 15)*4;
    *(float4*)&Wbuf[((size_t)blk*64 + t)*64 + d4] =
      make_float4(Xw[t][d4],Xw[t][d4+1],Xw[t][d4+2],Xw[t][d4+3]);
  }
}

__global__ __launch_bounds__(256) void chunkB_k(const float* __restrict__ kn,
   float* __restrict__ Uv, const float* __restrict__ Wbuf,
   const float* __restrict__ Gcbuf, const float* __restrict__ init,
   float* __restrict__ Hc)
{
  const int blk = blockIdx.x;
  const int bh = blk >> 3, grp = blk & 7;
  const int b = bh >> 3, h = bh & 7;
  const int v0 = grp*16;
  const int tid = threadIdx.x;
  __shared__ float hsh[64][17];
  __shared__ float Wsh[64][65];
  __shared__ float Kw[64][65];
  __shared__ float Ut[64][17];
  __shared__ float ush[64][17];

  #pragma unroll
  for (int i = 0; i < 4; ++i) {
    int cell = tid + i*256; int d = cell >> 4, v = cell & 15;
    hsh[d][v] = init[((size_t)bh*64 + d)*128 + v0 + v];
  }
  __syncthreads();

  for (int c = 0; c < 16; ++c) {
    const int cblk = bh*16 + c;
    const float* gcp = Gcbuf + (size_t)cblk*64;
    const float Gtot = gcp[63];
    const int row0 = b*SEQ + c*64;
    #pragma unroll
    for (int i = 0; i < 4; ++i) {
      int lin = tid + i*256; int t = lin >> 4, d4 = (lin & 15)*4;
      float4 wv = *(const float4*)&Wbuf[((size_t)cblk*64 + t)*64 + d4];
      Wsh[t][d4]=wv.x; Wsh[t][d4+1]=wv.y; Wsh[t][d4+2]=wv.z; Wsh[t][d4+3]=wv.w;
      float f = expf(Gtot - gcp[t]);
      float4 kv = *(const float4*)&kn[(size_t)(row0+t)*TKD + h*64 + d4];
      Kw[t][d4]=f*kv.x; Kw[t][d4+1]=f*kv.y; Kw[t][d4+2]=f*kv.z; Kw[t][d4+3]=f*kv.w;
    }
    {
      int t = tid >> 2, v4 = (tid & 3)*4;
      float4 uv = *(const float4*)&Uv[((size_t)cblk*64 + t)*128 + v0 + v4];
      Ut[t][v4]=uv.x; Ut[t][v4+1]=uv.y; Ut[t][v4+2]=uv.z; Ut[t][v4+3]=uv.w;
    }
    #pragma unroll
    for (int i = 0; i < 4; ++i) {
      int cell = tid + i*256; int d = cell >> 4, v = cell & 15;
      Hc[((size_t)cblk*64 + d)*128 + v0 + v] = hsh[d][v];
    }
    __syncthreads();
    #pragma unroll
    for (int i = 0; i < 4; ++i) {
      int cell = tid + i*256; int t = cell >> 4, v = cell & 15;
      float acc = 0.f;
      #pragma unroll 8
      for (int d = 0; d < 64; ++d) acc = fmaf(Wsh[t][d], hsh[d][v], acc);
      ush[t][v] = Ut[t][v] - acc;
    }
    __syncthreads();
    {
      int t = tid >> 2, v4 = (tid & 3)*4;
      *(float4*)&Uv[((size_t)cblk*64 + t)*128 + v0 + v4] =
        make_float4(ush[t][v4],ush[t][v4+1],ush[t][v4+2],ush[t][v4+3]);
    }
    const float eG = expf(Gtot);
    #pragma unroll
    for (int i = 0; i < 4; ++i) {
      int cell = tid + i*256; int d = cell >> 4, v = cell & 15;
      float acc = 0.f;
      #pragma unroll 8
      for (int t = 0; t < 64; ++t) acc = fmaf(Kw[t][d], ush[t][v], acc);
      hsh[d][v] = eG*hsh[d][v] + acc;
    }
    __syncthreads();
  }
}

__global__ __launch_bounds__(256) void chunkC_k(const float* __restrict__ qn,
   const float* __restrict__ kn, const float* __restrict__ Uc,
   const float* __restrict__ Gcbuf, const float* __restrict__ Hc,
   float* __restrict__ oattn)
{
  const int blk = blockIdx.x; const int bh = blk >> 4, c = blk & 15;
  const int b = bh >> 3, h = bh & 7;
  const int row0 = b*SEQ + c*64;
  const int tid = threadIdx.x;
  __shared__ float Qsh[64][65];
  __shared__ float KS[64][65];
  __shared__ float hsh[64][129];
  __shared__ float Ush[64][129];
  __shared__ float Gsh[64];

  #pragma unroll
  for (int i = 0; i < 4; ++i) {
    int lin = tid + i*256; int t = lin >> 4, d4 = (lin & 15)*4;
    float4 qv = *(const float4*)&qn[(size_t)(row0+t)*TKD + h*64 + d4];
    Qsh[t][d4]=qv.x; Qsh[t][d4+1]=qv.y; Qsh[t][d4+2]=qv.z; Qsh[t][d4+3]=qv.w;
    float4 kv = *(const float4*)&kn[(size_t)(row0+t)*TKD + h*64 + d4];
    KS[t][d4]=kv.x; KS[t][d4+1]=kv.y; KS[t][d4+2]=kv.z; KS[t][d4+3]=kv.w;
  }
  #pragma unroll
  for (int i = 0; i < 8; ++i) {
    int lin = tid + i*256; int d = lin >> 5, v4 = (lin & 31)*4;
    float4 hv = *(const float4*)&Hc[((size_t)blk*64 + d)*128 + v4];
    hsh[d][v4]=hv.x; hsh[d][v4+1]=hv.y; hsh[d][v4+2]=hv.z; hsh[d][v4+3]=hv.w;
    float4 uv = *(const float4*)&Uc[((size_t)blk*64 + d)*128 + v4];
    Ush[d][v4]=uv.x; Ush[d][v4+1]=uv.y; Ush[d][v4+2]=uv.z; Ush[d][v4+3]=uv.w;
  }
  if (tid < 64) Gsh[tid] = Gcbuf[(size_t)blk*64 + tid];
  __syncthreads();

  float sreg[16];
  #pragma unroll
  for (int i = 0; i < 16; ++i) {
    int e = tid + i*256; int t = e >> 6, s = e & 63;
    float val = 0.f;
    if (s <= t) {
      float acc = 0.f;
      #pragma unroll 8
      for (int d = 0; d < 64; ++d) acc = fmaf(Qsh[t][d], KS[s][d], acc);
      val = expf(Gsh[t] - Gsh[s]) * acc;
    }
    sreg[i] = val;
  }
  __syncthreads();
  #pragma unroll
  for (int i = 0; i < 16; ++i) { int e = tid + i*256; KS[e>>6][e&63] = sreg[i]; }
  __syncthreads();

  #pragma unroll
  for (int i = 0; i < 32; ++i) {
    int e = tid + i*256; int t = e >> 7, v = e & 127;
    float a1 = 0.f, a2 = 0.f;
    #pragma unroll 8
    for (int d = 0; d < 64; ++d) a1 = fmaf(Qsh[t][d], hsh[d][v], a1);
    #pragma unroll 8
    for (int s = 0; s < 64; ++s) a2 = fmaf(KS[t][s], Ush[s][v], a2);
    oattn[(size_t)(row0+t)*TVD + h*128 + v] = expf(Gsh[t])*a1 + a2;
  }
}

// ---------------- gated RMSNorm -> bf16 ------------------------------------
__global__ __launch_bounds__(256) void norm_k(const float* __restrict__ oattn,
   const float* __restrict__ qkvabz, const float* __restrict__ onw,
   __hip_bfloat16* __restrict__ ofin)
{
  int gid = blockIdx.x*4 + (threadIdx.x >> 6);
  int lane = threadIdx.x & 63;
  int row = gid >> 3; int h = gid & 7;
  size_t ob = (size_t)row*TVD + h*128;
  float2 ov = *(const float2*)&oattn[ob + lane*2];
  float2 zv = *(const float2*)&qkvabz[(size_t)row*NCOL + 2064 + h*128 + lane*2];
  float g0 = ov.x * siluf(zv.x), g1 = ov.y * siluf(zv.y);
  float ss = g0*g0 + g1*g1;
  #pragma unroll
  for (int o = 32; o; o >>= 1) ss += __shfl_xor(ss, o);
  float r = rsqrtf(ss * (1.f/128.f) + 1e-6f);
  ofin[ob + lane*2]     = __float2bfloat16(g0 * r * onw[lane*2]);
  ofin[ob + lane*2 + 1] = __float2bfloat16(g1 * r * onw[lane*2+1]);
}

extern "C" void kernel_launch(void* const* d_in, const int* in_sizes, int n_in,
                              void* d_out, int out_size, void* d_ws, size_t ws_size,
                              hipStream_t stream) {
  const float* hidden     = (const float*)d_in[0];
  const float* Wqkvabz    = (const float*)d_in[1];
  const float* A_log      = (const float*)d_in[2];
  const float* dt_bias    = (const float*)d_in[3];
  const float* conv_state = (const float*)d_in[4];
  const float* w1         = (const float*)d_in[5];
  const float* w2         = (const float*)d_in[6];
  const float* b2         = (const float*)d_in[7];
  const float* init_state = (const float*)d_in[8];
  const float* o_norm_w   = (const float*)d_in[9];
  const float* W_o        = (const float*)d_in[10];
  float* out = (float*)d_out;

  float* ws = (float*)d_ws;
  float* qkvabz = ws;                                  // 6,324,224
  float* kern   = qkvabz + (size_t)6324224;            // 8,388,608
  float* qn     = kern   + (size_t)8388608;            // 1,048,576
  float* kn     = qn     + (size_t)1048576;            // 1,048,576
  float* gbuf   = kn     + (size_t)1048576;            // 16,384
  float* bbuf   = gbuf   + (size_t)16384;              // 16,384
  float* vconv  = bbuf   + (size_t)16384;              // 2,097,152
  float* bfpool = vconv  + (size_t)2097152;
  __hip_bfloat16* hidden_bf = (__hip_bfloat16*)bfpool;       // 4,194,304
  __hip_bfloat16* w1t   = hidden_bf + (size_t)4194304;       // 262,144  [128][2048]
  __hip_bfloat16* w2t   = w1t + (size_t)262144;              // 524,288  [4096][128]
  __hip_bfloat16* Wot   = w2t + (size_t)524288;              // 2,097,152 [2048][1024]
  __hip_bfloat16* x1sb  = Wot + (size_t)2097152;             // 262,144  [2048][128]
  __hip_bfloat16* ofinb = x1sb + (size_t)262144;             // 2,097,152 [2048][1024]
  // aliases in the kern region (Wqkvt dead after GEMM1; kern written by GEMM3;
  // kern dead after conv_k):
  __hip_bfloat16* Wqkvt = (__hip_bfloat16*)kern;             // [3200][2048] bf16
  float* oattn  = kern;                                // 2,097,152
  float* Uv     = kern + (size_t)2097152;              // 2,097,152
  float* Wbuf   = kern + (size_t)4194304;              // 1,048,576
  float* Gcbuf  = kern + (size_t)5242880;              // 16,384
  float* Hc     = vconv;                               // vconv dead after chunkA

  dim3 blk(256);
  // casts
  cast_k<<<4096, blk, 0, stream>>>(hidden, (unsigned short*)hidden_bf, 1048576);
  tcast_k<<<dim3(100,64), blk, 0, stream>>>(Wqkvabz, Wqkvt, 2048, 3088, 3200);
  tcast_k<<<dim3(4,64),   blk, 0, stream>>>(w1,  w1t, 2048, 128, 128);
  tcast_k<<<dim3(128,4),  blk, 0, stream>>>(w2,  w2t, 128, 4096, 4096);
  tcast_k<<<dim3(64,32),  blk, 0, stream>>>(W_o, Wot, 1024, 2048, 2048);
  // GEMMs (MFMA)
  mgemm_k<0><<<dim3(25,16), blk, 0, stream>>>(hidden_bf, Wqkvt, nullptr, qkvabz, nullptr, 2048, 3088, 2048);
  mgemm_k<1><<<dim3(1,16),  blk, 0, stream>>>(hidden_bf, w1t, nullptr, nullptr, x1sb, 2048, 128, 2048);
  mgemm_k<2><<<dim3(32,16), blk, 0, stream>>>(x1sb, w2t, b2, kern, nullptr, 2048, 4096, 128);
  // pointwise + scan
  actv_k<<<4096, blk, 0, stream>>>(qkvabz, A_log, dt_bias, qn, kn, gbuf, bbuf);
  conv_k<<<8192, blk, 0, stream>>>(qkvabz, kern, conv_state, vconv);
  chunkA_k<<<256, blk, 0, stream>>>(kn, vconv, gbuf, bbuf, Uv, Wbuf, Gcbuf);
  chunkB_k<<<128, blk, 0, stream>>>(kn, Uv, Wbuf, Gcbuf, init_state, Hc);
  chunkC_k<<<256, blk, 0, stream>>>(qn, kn, Uv, Gcbuf, Hc, oattn);
  norm_k<<<4096, blk, 0, stream>>>(oattn, qkvabz, o_norm_w, ofinb);
  mgemm_k<0><<<dim3(16,16), blk, 0, stream>>>(ofinb, Wot, nullptr, out, nullptr, 2048, 2048, 1024);
}

// Round 4
// 336.558 us; speedup vs baseline: 5.3688x; 1.2356x over previous
//
#include <hip/hip_runtime.h>
#include <hip/hip_bf16.h>
#include <math.h>
#include <stdint.h>

#define BATCH 2
#define SEQ 1024
#define HIDDIM 2048
#define NH 8
#define DKD 64
#define DVD 128
#define TKD 512
#define TVD 1024
#define NCOL 3088   // TK+TK+TV+H+H+TV
#define KSZ 4
#define NCHK 16

typedef __attribute__((ext_vector_type(8))) short bf16x8;
typedef __attribute__((ext_vector_type(4))) float f32x4;

__device__ __forceinline__ float sigm(float x){ return 1.f/(1.f+expf(-x)); }
__device__ __forceinline__ float siluf(float x){ return x/(1.f+expf(-x)); }
__device__ __forceinline__ float b2f(unsigned short u){
  union { unsigned int i; float f; } x; x.i = ((unsigned int)u) << 16; return x.f;
}

__device__ __forceinline__ void glds16(const __hip_bfloat16* g, void* l) {
  __builtin_amdgcn_global_load_lds((const __attribute__((address_space(1))) void*)g,
                                   (__attribute__((address_space(3))) void*)l, 16, 0, 0);
}

// ---------------- casts -----------------------------------------------------
__global__ __launch_bounds__(256) void cast_k(const float* __restrict__ in,
    unsigned short* __restrict__ out, int n4)
{
  int i = blockIdx.x*256 + threadIdx.x;
  if (i >= n4) return;
  float4 v = ((const float4*)in)[i];
  __hip_bfloat16 h0 = __float2bfloat16(v.x), h1 = __float2bfloat16(v.y);
  __hip_bfloat16 h2 = __float2bfloat16(v.z), h3 = __float2bfloat16(v.w);
  ushort4 o;
  o.x = *(unsigned short*)&h0; o.y = *(unsigned short*)&h1;
  o.z = *(unsigned short*)&h2; o.w = *(unsigned short*)&h3;
  ((ushort4*)out)[i] = o;
}

// transpose + cast: in fp32 [R][C] -> out bf16 [Cpad][R] (pad rows zero)
__global__ __launch_bounds__(256) void tcast_k(const float* __restrict__ in,
    __hip_bfloat16* __restrict__ out, int R, int C, int Cpad)
{
  __shared__ float tile[32][33];
  const int tx = threadIdx.x & 31, ty = threadIdx.x >> 5;
  const int c = blockIdx.x*32 + tx;
  #pragma unroll
  for (int i = 0; i < 4; ++i) {
    int r = blockIdx.y*32 + ty + i*8;
    tile[ty + i*8][tx] = (c < C) ? in[(size_t)r*C + c] : 0.f;
  }
  __syncthreads();
  #pragma unroll
  for (int i = 0; i < 4; ++i) {
    int orow = blockIdx.x*32 + ty + i*8;
    int ocol = blockIdx.y*32 + tx;
    out[(size_t)orow*R + ocol] = __float2bfloat16(tile[tx][ty + i*8]);
  }
}

// ---------------- bf16 MFMA GEMM: C = A[M][K] @ Bt[N][K]^T ------------------
// EPI: 0 = fp32 out, 1 = silu -> bf16, 2 = +bias -> bf16
template<int EPI>
__global__ __launch_bounds__(256) void mgemm_k(
    const __hip_bfloat16* __restrict__ A,
    const __hip_bfloat16* __restrict__ Bt,
    const float* __restrict__ bias,
    float* __restrict__ Cf, __hip_bfloat16* __restrict__ Cb,
    int M, int N, int K)
{
  __shared__ __hip_bfloat16 As[128*32];
  __shared__ __hip_bfloat16 Bs[128*32];
  const int tid = threadIdx.x;
  const int w = tid >> 6, l = tid & 63;
  const int wr = w >> 1, wc = w & 1;
  const int row0 = blockIdx.y*128, col0 = blockIdx.x*128;
  const int fr = l & 15, fq = l >> 4;

  f32x4 acc[4][4];
  #pragma unroll
  for (int m = 0; m < 4; ++m)
    #pragma unroll
    for (int n = 0; n < 4; ++n)
      acc[m][n] = (f32x4){0.f,0.f,0.f,0.f};

  const int e0 = w*512 + l*8;
  const int r0s = e0 >> 5, c0s = e0 & 31;

  for (int k0 = 0; k0 < K; k0 += 32) {
    glds16(&A[(size_t)(row0 + r0s)*K + k0 + c0s],       (char*)As + w*1024);
    glds16(&A[(size_t)(row0 + r0s + 64)*K + k0 + c0s],  (char*)As + 4096 + w*1024);
    glds16(&Bt[(size_t)(col0 + r0s)*K + k0 + c0s],      (char*)Bs + w*1024);
    glds16(&Bt[(size_t)(col0 + r0s + 64)*K + k0 + c0s], (char*)Bs + 4096 + w*1024);
    __syncthreads();

    bf16x8 af[4], bfv[4];
    #pragma unroll
    for (int m = 0; m < 4; ++m)
      af[m] = *(const bf16x8*)&As[(wr*64 + m*16 + fr)*32 + fq*8];
    #pragma unroll
    for (int n = 0; n < 4; ++n)
      bfv[n] = *(const bf16x8*)&Bs[(wc*64 + n*16 + fr)*32 + fq*8];
    #pragma unroll
    for (int m = 0; m < 4; ++m)
      #pragma unroll
      for (int n = 0; n < 4; ++n)
        acc[m][n] = __builtin_amdgcn_mfma_f32_16x16x32_bf16(af[m], bfv[n], acc[m][n], 0, 0, 0);
    __syncthreads();
  }

  #pragma unroll
  for (int n = 0; n < 4; ++n) {
    const int ccol = col0 + wc*64 + n*16 + fr;
    if (ccol >= N) continue;
    #pragma unroll
    for (int m = 0; m < 4; ++m) {
      #pragma unroll
      for (int r = 0; r < 4; ++r) {
        const int crow = row0 + wr*64 + m*16 + fq*4 + r;
        float v = acc[m][n][r];
        if (EPI == 1)      Cb[(size_t)crow*N + ccol] = __float2bfloat16(siluf(v));
        else if (EPI == 2) Cb[(size_t)crow*N + ccol] = __float2bfloat16(v + bias[ccol]);
        else               Cf[(size_t)crow*N + ccol] = v;
      }
    }
  }
}

// ---------------- silu + l2norm for q,k; g and beta ------------------------
__global__ __launch_bounds__(256) void actv_k(const float* __restrict__ qkvabz,
    const float* __restrict__ A_log, const float* __restrict__ dt_bias,
    float* __restrict__ qn, float* __restrict__ kn,
    float* __restrict__ g, float* __restrict__ beta)
{
  int gid = blockIdx.x*4 + (threadIdx.x >> 6);
  int lane = threadIdx.x & 63;
  int row = gid >> 3; int h = gid & 7;
  const float* base = qkvabz + (size_t)row * NCOL;
  float qv = base[h*64 + lane];
  float kv = base[TKD + h*64 + lane];
  float sq = siluf(qv), sk = siluf(kv);
  float ssq = sq*sq, ssk = sk*sk;
  #pragma unroll
  for (int o = 32; o; o >>= 1) { ssq += __shfl_xor(ssq, o); ssk += __shfl_xor(ssk, o); }
  qn[(size_t)row*TKD + h*64 + lane] = sq * rsqrtf(ssq + 1e-6f) * 0.125f;
  kn[(size_t)row*TKD + h*64 + lane] = sk * rsqrtf(ssk + 1e-6f);
  if (lane == 0) {
    float av = base[2048 + h] + dt_bias[h];
    float sp = fmaxf(av, 0.f) + log1pf(expf(-fabsf(av)));
    g[(size_t)row*NH + h] = -expf(A_log[h]) * sp;
    float bv = base[2056 + h];
    beta[(size_t)row*NH + h] = sigm(bv);
  }
}

// ---------------- dynamic conv (bf16 kernels) -------------------------------
__global__ __launch_bounds__(256) void conv_k(const float* __restrict__ qkvabz,
   const __hip_bfloat16* __restrict__ kern, const float* __restrict__ conv_state,
   float* __restrict__ vconv)
{
  int idx = blockIdx.x*256 + threadIdx.x;
  int c = idx & (TVD-1);
  int bs = idx >> 10;
  int s = bs & (SEQ-1); int b = bs >> 10;
  ushort4 kf = *(const ushort4*)&kern[(size_t)idx * 4];
  float kj[4] = { b2f(kf.x), b2f(kf.y), b2f(kf.z), b2f(kf.w) };
  float acc = 0.f;
  #pragma unroll
  for (int j = 0; j < 4; ++j) {
    int i = s + j;
    float xv = (i < 3) ? conv_state[((size_t)b*TVD + c)*3 + i]
                       : qkvabz[((size_t)(b*SEQ + (i-3)))*NCOL + TKD*2 + c];
    acc = fmaf(xv, kj[j], acc);
  }
  vconv[idx] = siluf(acc);
}

// ============ chunked gated delta rule =====================================
// Phase A: per (bh, chunk): A-matrix, trisolve -> Utilde, Wtilde;
//          then D = eG*I - Kw^T Wtilde, b = Kw^T Utilde
__global__ __launch_bounds__(256) void chunkA_k(const float* __restrict__ kn,
   const float* __restrict__ vconv, const float* __restrict__ gb,
   const float* __restrict__ bb, float* __restrict__ Uv,
   float* __restrict__ Wbuf, float* __restrict__ Gcbuf,
   float* __restrict__ Dbuf, float* __restrict__ Bvec)
{
  const int blk = blockIdx.x;
  const int bh = blk >> 4, c = blk & 15;
  const int b = bh >> 3, h = bh & 7;
  const int tid = threadIdx.x;
  const int row0 = b*SEQ + c*64;
  __shared__ float Ksh[64][68];
  __shared__ float Xv[64][132];
  __shared__ float Xw[64][68];
  __shared__ float Ash[64][68];   // A-matrix; later reused for Kw
  __shared__ float Gsh[64], Bsh[64];

  #pragma unroll
  for (int i = 0; i < 4; ++i) {
    int lin = tid + i*256; int t = lin >> 4, d4 = (lin & 15)*4;
    float4 kv = *(const float4*)&kn[(size_t)(row0+t)*TKD + h*64 + d4];
    Ksh[t][d4]=kv.x; Ksh[t][d4+1]=kv.y; Ksh[t][d4+2]=kv.z; Ksh[t][d4+3]=kv.w;
  }
  #pragma unroll
  for (int i = 0; i < 8; ++i) {
    int lin = tid + i*256; int t = lin >> 5, v4 = (lin & 31)*4;
    float4 vv = *(const float4*)&vconv[(size_t)(row0+t)*TVD + h*128 + v4];
    Xv[t][v4]=vv.x; Xv[t][v4+1]=vv.y; Xv[t][v4+2]=vv.z; Xv[t][v4+3]=vv.w;
  }
  if (tid < 64) {
    float gv = gb[(size_t)(row0+tid)*NH + h];
    #pragma unroll
    for (int o = 1; o < 64; o <<= 1) {
      float oth = __shfl_up(gv, o);
      if (tid >= o) gv += oth;
    }
    Gsh[tid] = gv;
    Bsh[tid] = bb[(size_t)(row0+tid)*NH + h];
    Gcbuf[(size_t)blk*64 + tid] = gv;
  }
  __syncthreads();

  #pragma unroll
  for (int i = 0; i < 16; ++i) {
    int e = tid + i*256; int t = e >> 6, s = e & 63;
    float val = 0.f;
    if (s < t) {
      float acc = 0.f;
      #pragma unroll 8
      for (int d = 0; d < 64; ++d) acc = fmaf(Ksh[t][d], Ksh[s][d], acc);
      val = Bsh[t] * expf(Gsh[t] - Gsh[s]) * acc;
    }
    Ash[t][s] = val;
  }
  #pragma unroll
  for (int i = 0; i < 8; ++i) {
    int lin = tid + i*256; int t = lin >> 5, v4 = (lin & 31)*4;
    float bt = Bsh[t];
    Xv[t][v4]*=bt; Xv[t][v4+1]*=bt; Xv[t][v4+2]*=bt; Xv[t][v4+3]*=bt;
  }
  #pragma unroll
  for (int i = 0; i < 4; ++i) {
    int lin = tid + i*256; int t = lin >> 4, d4 = (lin & 15)*4;
    float f = Bsh[t]*expf(Gsh[t]);
    Xw[t][d4+0]=f*Ksh[t][d4+0]; Xw[t][d4+1]=f*Ksh[t][d4+1];
    Xw[t][d4+2]=f*Ksh[t][d4+2]; Xw[t][d4+3]=f*Ksh[t][d4+3];
  }
  __syncthreads();

  // forward substitution
  if (tid < 192) {
    float* colp; int stride;
    if (tid < 128) { colp = &Xv[0][tid];     stride = 132; }
    else           { colp = &Xw[0][tid-128]; stride = 68;  }
    for (int t = 1; t < 64; ++t) {
      float a0 = 0.f, a1 = 0.f;
      int s = 0;
      for (; s + 1 < t; s += 2) {
        a0 = fmaf(Ash[t][s],   colp[s*stride],     a0);
        a1 = fmaf(Ash[t][s+1], colp[(s+1)*stride], a1);
      }
      if (s < t) a0 = fmaf(Ash[t][s], colp[s*stride], a0);
      colp[t*stride] -= (a0 + a1);
    }
  }
  __syncthreads();

  // store Utilde, Wtilde
  #pragma unroll
  for (int i = 0; i < 8; ++i) {
    int lin = tid + i*256; int t = lin >> 5, v4 = (lin & 31)*4;
    *(float4*)&Uv[((size_t)blk*64 + t)*128 + v4] =
      make_float4(Xv[t][v4],Xv[t][v4+1],Xv[t][v4+2],Xv[t][v4+3]);
  }
  #pragma unroll
  for (int i = 0; i < 4; ++i) {
    int lin = tid + i*256; int t = lin >> 4, d4 = (lin & 15)*4;
    *(float4*)&Wbuf[((size_t)blk*64 + t)*64 + d4] =
      make_float4(Xw[t][d4],Xw[t][d4+1],Xw[t][d4+2],Xw[t][d4+3]);
  }

  // Kw[t][d] = exp(Gtot - G_t) * k_t  into Ash (A-matrix dead)
  const float Gtot = Gsh[63];
  #pragma unroll
  for (int i = 0; i < 4; ++i) {
    int lin = tid + i*256; int t = lin >> 4, d4 = (lin & 15)*4;
    float f = expf(Gtot - Gsh[t]);
    Ash[t][d4+0]=f*Ksh[t][d4+0]; Ash[t][d4+1]=f*Ksh[t][d4+1];
    Ash[t][d4+2]=f*Ksh[t][d4+2]; Ash[t][d4+3]=f*Ksh[t][d4+3];
  }
  __syncthreads();

  // D = eG*I - Kw^T Wtilde   (thread tile 4x4)
  {
    const int d1b = (tid >> 4)*4, d2b = (tid & 15)*4;
    float dacc[4][4] = {};
    #pragma unroll 8
    for (int t = 0; t < 64; ++t) {
      float4 kw = *(const float4*)&Ash[t][d1b];
      float4 wv = *(const float4*)&Xw[t][d2b];
      float kwa[4] = {kw.x,kw.y,kw.z,kw.w};
      float wva[4] = {wv.x,wv.y,wv.z,wv.w};
      #pragma unroll
      for (int i = 0; i < 4; ++i)
        #pragma unroll
        for (int j = 0; j < 4; ++j)
          dacc[i][j] = fmaf(kwa[i], wva[j], dacc[i][j]);
    }
    const float eG = expf(Gtot);
    #pragma unroll
    for (int i = 0; i < 4; ++i) {
      float vals[4];
      #pragma unroll
      for (int j = 0; j < 4; ++j) {
        float v = -dacc[i][j];
        if (d1b + i == d2b + j) v += eG;
        vals[j] = v;
      }
      *(float4*)&Dbuf[(size_t)blk*4096 + (d1b+i)*64 + d2b] =
        make_float4(vals[0],vals[1],vals[2],vals[3]);
    }
  }
  // b = Kw^T Utilde  (thread tile 4x8)
  {
    const int d1b = (tid >> 4)*4, vb = (tid & 15)*8;
    float bacc[4][8] = {};
    #pragma unroll 4
    for (int t = 0; t < 64; ++t) {
      float4 kw = *(const float4*)&Ash[t][d1b];
      float4 u0 = *(const float4*)&Xv[t][vb];
      float4 u1 = *(const float4*)&Xv[t][vb+4];
      float kwa[4] = {kw.x,kw.y,kw.z,kw.w};
      float ua[8] = {u0.x,u0.y,u0.z,u0.w,u1.x,u1.y,u1.z,u1.w};
      #pragma unroll
      for (int i = 0; i < 4; ++i)
        #pragma unroll
        for (int j = 0; j < 8; ++j)
          bacc[i][j] = fmaf(kwa[i], ua[j], bacc[i][j]);
    }
    #pragma unroll
    for (int i = 0; i < 4; ++i) {
      *(float4*)&Bvec[(size_t)blk*8192 + (d1b+i)*128 + vb] =
        make_float4(bacc[i][0],bacc[i][1],bacc[i][2],bacc[i][3]);
      *(float4*)&Bvec[(size_t)blk*8192 + (d1b+i)*128 + vb + 4] =
        make_float4(bacc[i][4],bacc[i][5],bacc[i][6],bacc[i][7]);
    }
  }
}

// Phase B: h_{c+1} = D_c h_c + b_c ; 128 blocks (bh x 8 vgroups of 16)
// registers double-buffer next chunk's D/b; writes Hc (chunk-initial states)
__global__ __launch_bounds__(256) void chunkB2_k(const float* __restrict__ Dbuf,
   const float* __restrict__ Bvec, const float* __restrict__ init,
   float* __restrict__ Hc)
{
  const int blk = blockIdx.x;
  const int bh = blk >> 3, grp = blk & 7;
  const int v0 = grp*16;
  const int tid = threadIdx.x;
  const int v = tid & 15;
  const int d1b = (tid >> 4) * 4;
  __shared__ float DT[64][68];   // DT[d2][d1]
  __shared__ float bsh[64][17];
  __shared__ float hsh[64][17];

  float hreg[4];
  #pragma unroll
  for (int j = 0; j < 4; ++j) {
    hreg[j] = init[((size_t)bh*64 + d1b + j)*128 + v0 + v];
    hsh[d1b + j][v] = hreg[j];
  }
  float Dreg[16], breg[4];
  {
    const float* Dp = Dbuf + (size_t)(bh*16)*4096;
    const float* bp = Bvec + (size_t)(bh*16)*8192;
    #pragma unroll
    for (int i = 0; i < 16; ++i) Dreg[i] = Dp[tid + i*256];
    #pragma unroll
    for (int i = 0; i < 4; ++i)  breg[i] = bp[(size_t)((tid>>4) + i*16)*128 + v0 + v];
  }
  #pragma unroll
  for (int i = 0; i < 16; ++i) {
    int cell = tid + i*256; DT[cell & 63][cell >> 6] = Dreg[i];
  }
  #pragma unroll
  for (int i = 0; i < 4; ++i) bsh[(tid>>4) + i*16][v] = breg[i];
  __syncthreads();

  for (int c = 0; c < 16; ++c) {
    if (c < 15) {
      const float* Dn = Dbuf + (size_t)(bh*16 + c + 1)*4096;
      const float* bn = Bvec + (size_t)(bh*16 + c + 1)*8192;
      #pragma unroll
      for (int i = 0; i < 16; ++i) Dreg[i] = Dn[tid + i*256];
      #pragma unroll
      for (int i = 0; i < 4; ++i)  breg[i] = bn[(size_t)((tid>>4) + i*16)*128 + v0 + v];
    }
    // write chunk-initial state
    #pragma unroll
    for (int j = 0; j < 4; ++j)
      Hc[((size_t)(bh*16 + c)*64 + d1b + j)*128 + v0 + v] = hreg[j];
    // newh = b + D*h
    float nh[4];
    #pragma unroll
    for (int j = 0; j < 4; ++j) nh[j] = bsh[d1b + j][v];
    #pragma unroll 8
    for (int d2 = 0; d2 < 64; ++d2) {
      float hv = hsh[d2][v];
      float4 dv = *(const float4*)&DT[d2][d1b];
      nh[0] = fmaf(dv.x, hv, nh[0]);
      nh[1] = fmaf(dv.y, hv, nh[1]);
      nh[2] = fmaf(dv.z, hv, nh[2]);
      nh[3] = fmaf(dv.w, hv, nh[3]);
    }
    __syncthreads();
    #pragma unroll
    for (int j = 0; j < 4; ++j) { hreg[j] = nh[j]; hsh[d1b + j][v] = nh[j]; }
    if (c < 15) {
      #pragma unroll
      for (int i = 0; i < 16; ++i) {
        int cell = tid + i*256; DT[cell & 63][cell >> 6] = Dreg[i];
      }
      #pragma unroll
      for (int i = 0; i < 4; ++i) bsh[(tid>>4) + i*16][v] = breg[i];
    }
    __syncthreads();
  }
}

// Phase C: o = Qtilde h_c + S Utilde, Qtilde = E.Q - S Wtilde ; 256 blocks
__global__ __launch_bounds__(256) void chunkC_k(const float* __restrict__ qn,
   const float* __restrict__ kn, const float* __restrict__ Uc,
   const float* __restrict__ Gcbuf, const float* __restrict__ Hc,
   const float* __restrict__ Wbuf, float* __restrict__ oattn)
{
  const int blk = blockIdx.x; const int bh = blk >> 4, c = blk & 15;
  const int b = bh >> 3, h = bh & 7;
  const int row0 = b*SEQ + c*64;
  const int tid = threadIdx.x;
  __shared__ float Qsh[64][68];    // Q, later Qtilde
  __shared__ float KS[64][68];     // K, then S
  __shared__ float Wsh[64][68];    // Wtilde
  __shared__ float hsh[64][132];
  __shared__ float Ush[64][132];
  __shared__ float Gsh[64];

  #pragma unroll
  for (int i = 0; i < 4; ++i) {
    int lin = tid + i*256; int t = lin >> 4, d4 = (lin & 15)*4;
    float4 qv = *(const float4*)&qn[(size_t)(row0+t)*TKD + h*64 + d4];
    Qsh[t][d4]=qv.x; Qsh[t][d4+1]=qv.y; Qsh[t][d4+2]=qv.z; Qsh[t][d4+3]=qv.w;
    float4 kv = *(const float4*)&kn[(size_t)(row0+t)*TKD + h*64 + d4];
    KS[t][d4]=kv.x; KS[t][d4+1]=kv.y; KS[t][d4+2]=kv.z; KS[t][d4+3]=kv.w;
    float4 wv = *(const float4*)&Wbuf[((size_t)blk*64 + t)*64 + d4];
    Wsh[t][d4]=wv.x; Wsh[t][d4+1]=wv.y; Wsh[t][d4+2]=wv.z; Wsh[t][d4+3]=wv.w;
  }
  #pragma unroll
  for (int i = 0; i < 8; ++i) {
    int lin = tid + i*256; int d = lin >> 5, v4 = (lin & 31)*4;
    float4 hv = *(const float4*)&Hc[((size_t)blk*64 + d)*128 + v4];
    hsh[d][v4]=hv.x; hsh[d][v4+1]=hv.y; hsh[d][v4+2]=hv.z; hsh[d][v4+3]=hv.w;
    float4 uv = *(const float4*)&Uc[((size_t)blk*64 + d)*128 + v4];
    Ush[d][v4]=uv.x; Ush[d][v4+1]=uv.y; Ush[d][v4+2]=uv.z; Ush[d][v4+3]=uv.w;
  }
  if (tid < 64) Gsh[tid] = Gcbuf[(size_t)blk*64 + tid];
  __syncthreads();

  // S = masked decayed QK^T
  float sreg[16];
  #pragma unroll
  for (int i = 0; i < 16; ++i) {
    int e = tid + i*256; int t = e >> 6, s = e & 63;
    float val = 0.f;
    if (s <= t) {
      float acc = 0.f;
      #pragma unroll 8
      for (int d = 0; d < 64; ++d) acc = fmaf(Qsh[t][d], KS[s][d], acc);
      val = expf(Gsh[t] - Gsh[s]) * acc;
    }
    sreg[i] = val;
  }
  __syncthreads();
  #pragma unroll
  for (int i = 0; i < 16; ++i) { int e = tid + i*256; KS[e>>6][e&63] = sreg[i]; }
  __syncthreads();

  // Qtilde = E.Q - S*Wtilde  (thread tile 4x4)
  {
    const int t4 = (tid >> 4)*4, d4 = (tid & 15)*4;
    float qacc[4][4] = {};
    #pragma unroll 8
    for (int s = 0; s < 64; ++s) {
      float4 wv = *(const float4*)&Wsh[s][d4];
      float wva[4] = {wv.x,wv.y,wv.z,wv.w};
      float sv[4];
      #pragma unroll
      for (int i = 0; i < 4; ++i) sv[i] = KS[t4+i][s];
      #pragma unroll
      for (int i = 0; i < 4; ++i)
        #pragma unroll
        for (int j = 0; j < 4; ++j)
          qacc[i][j] = fmaf(sv[i], wva[j], qacc[i][j]);
    }
    float qt[4][4];
    #pragma unroll
    for (int i = 0; i < 4; ++i) {
      float e = expf(Gsh[t4+i]);
      #pragma unroll
      for (int j = 0; j < 4; ++j)
        qt[i][j] = e*Qsh[t4+i][d4+j] - qacc[i][j];
    }
    __syncthreads();
    #pragma unroll
    for (int i = 0; i < 4; ++i)
      *(float4*)&Qsh[t4+i][d4] = make_float4(qt[i][0],qt[i][1],qt[i][2],qt[i][3]);
  }
  __syncthreads();

  // o = Qtilde*h_c + S*Utilde
  #pragma unroll
  for (int i = 0; i < 32; ++i) {
    int e = tid + i*256; int t = e >> 7, v = e & 127;
    float a1 = 0.f, a2 = 0.f;
    #pragma unroll 8
    for (int d = 0; d < 64; ++d) a1 = fmaf(Qsh[t][d], hsh[d][v], a1);
    #pragma unroll 8
    for (int s = 0; s < 64; ++s) a2 = fmaf(KS[t][s], Ush[s][v], a2);
    oattn[(size_t)(row0+t)*TVD + h*128 + v] = a1 + a2;
  }
}

// ---------------- gated RMSNorm -> bf16 ------------------------------------
__global__ __launch_bounds__(256) void norm_k(const float* __restrict__ oattn,
   const float* __restrict__ qkvabz, const float* __restrict__ onw,
   __hip_bfloat16* __restrict__ ofin)
{
  int gid = blockIdx.x*4 + (threadIdx.x >> 6);
  int lane = threadIdx.x & 63;
  int row = gid >> 3; int h = gid & 7;
  size_t ob = (size_t)row*TVD + h*128;
  float2 ov = *(const float2*)&oattn[ob + lane*2];
  float2 zv = *(const float2*)&qkvabz[(size_t)row*NCOL + 2064 + h*128 + lane*2];
  float g0 = ov.x * siluf(zv.x), g1 = ov.y * siluf(zv.y);
  float ss = g0*g0 + g1*g1;
  #pragma unroll
  for (int o = 32; o; o >>= 1) ss += __shfl_xor(ss, o);
  float r = rsqrtf(ss * (1.f/128.f) + 1e-6f);
  ofin[ob + lane*2]     = __float2bfloat16(g0 * r * onw[lane*2]);
  ofin[ob + lane*2 + 1] = __float2bfloat16(g1 * r * onw[lane*2+1]);
}

extern "C" void kernel_launch(void* const* d_in, const int* in_sizes, int n_in,
                              void* d_out, int out_size, void* d_ws, size_t ws_size,
                              hipStream_t stream) {
  const float* hidden     = (const float*)d_in[0];
  const float* Wqkvabz    = (const float*)d_in[1];
  const float* A_log      = (const float*)d_in[2];
  const float* dt_bias    = (const float*)d_in[3];
  const float* conv_state = (const float*)d_in[4];
  const float* w1         = (const float*)d_in[5];
  const float* w2         = (const float*)d_in[6];
  const float* b2         = (const float*)d_in[7];
  const float* init_state = (const float*)d_in[8];
  const float* o_norm_w   = (const float*)d_in[9];
  const float* W_o        = (const float*)d_in[10];
  float* out = (float*)d_out;

  float* ws = (float*)d_ws;
  float* qkvabz = ws;                                  // 6,324,224 f
  float* kern   = qkvabz + (size_t)6324224;            // 8,388,608 f region
  float* qn     = kern   + (size_t)8388608;            // 1,048,576
  float* kn     = qn     + (size_t)1048576;            // 1,048,576
  float* gbuf   = kn     + (size_t)1048576;            // 16,384
  float* bbuf   = gbuf   + (size_t)16384;              // 16,384
  float* vconv  = bbuf   + (size_t)16384;              // 2,097,152
  float* bfpool = vconv  + (size_t)2097152;
  __hip_bfloat16* hidden_bf = (__hip_bfloat16*)bfpool;       // 4,194,304 e
  __hip_bfloat16* w1t   = hidden_bf + (size_t)4194304;       // 262,144
  __hip_bfloat16* w2t   = w1t + (size_t)262144;              // 524,288
  __hip_bfloat16* Wot   = w2t + (size_t)524288;              // 2,097,152
  __hip_bfloat16* x1sb  = Wot + (size_t)2097152;             // 262,144
  __hip_bfloat16* ofinb = x1sb + (size_t)262144;             // 2,097,152
  float* Gcbuf  = (float*)(ofinb + (size_t)2097152);         // 16,384 f
  // aliases inside the kern region (all dead-kern reuse):
  __hip_bfloat16* Wqkvt  = (__hip_bfloat16*)kern;            // [3200][2048] bf16 (dead after GEMM1)
  __hip_bfloat16* kernbf = (__hip_bfloat16*)kern;            // 8,388,608 bf16 (dead after conv)
  float* oattn  = kern;                                // 2,097,152 f
  float* Uv     = kern + (size_t)2097152;              // 2,097,152 f
  float* Wbuf   = kern + (size_t)4194304;              // 1,048,576 f
  float* Dbuf   = kern + (size_t)5242880;              // 1,048,576 f
  float* Bvec   = kern + (size_t)6291456;              // 2,097,152 f
  float* Hc     = vconv;                               // vconv dead after chunkA

  dim3 blk(256);
  cast_k<<<4096, blk, 0, stream>>>(hidden, (unsigned short*)hidden_bf, 1048576);
  tcast_k<<<dim3(100,64), blk, 0, stream>>>(Wqkvabz, Wqkvt, 2048, 3088, 3200);
  tcast_k<<<dim3(4,64),   blk, 0, stream>>>(w1,  w1t, 2048, 128, 128);
  tcast_k<<<dim3(128,4),  blk, 0, stream>>>(w2,  w2t, 128, 4096, 4096);
  tcast_k<<<dim3(64,32),  blk, 0, stream>>>(W_o, Wot, 1024, 2048, 2048);
  mgemm_k<0><<<dim3(25,16), blk, 0, stream>>>(hidden_bf, Wqkvt, nullptr, qkvabz, nullptr, 2048, 3088, 2048);
  mgemm_k<1><<<dim3(1,16),  blk, 0, stream>>>(hidden_bf, w1t, nullptr, nullptr, x1sb, 2048, 128, 2048);
  mgemm_k<2><<<dim3(32,16), blk, 0, stream>>>(x1sb, w2t, b2, nullptr, kernbf, 2048, 4096, 128);
  actv_k<<<4096, blk, 0, stream>>>(qkvabz, A_log, dt_bias, qn, kn, gbuf, bbuf);
  conv_k<<<8192, blk, 0, stream>>>(qkvabz, kernbf, conv_state, vconv);
  chunkA_k<<<256, blk, 0, stream>>>(kn, vconv, gbuf, bbuf, Uv, Wbuf, Gcbuf, Dbuf, Bvec);
  chunkB2_k<<<128, blk, 0, stream>>>(Dbuf, Bvec, init_state, Hc);
  chunkC_k<<<256, blk, 0, stream>>>(qn, kn, Uv, Gcbuf, Hc, Wbuf, oattn);
  norm_k<<<4096, blk, 0, stream>>>(oattn, qkvabz, o_norm_w, ofinb);
  mgemm_k<0><<<dim3(16,16), blk, 0, stream>>>(ofinb, Wot, nullptr, out, nullptr, 2048, 2048, 1024);
}

// Round 5
// 283.929 us; speedup vs baseline: 6.3639x; 1.1854x over previous
//
#include <hip/hip_runtime.h>
#include <hip/hip_bf16.h>
#include <math.h>
#include <stdint.h>

#define BATCH 2
#define SEQ 1024
#define HIDDIM 2048
#define NH 8
#define DKD 64
#define DVD 128
#define TKD 512
#define TVD 1024
#define NCOL 3088   // TK+TK+TV+H+H+TV
#define KSZ 4
#define NCHK 16

typedef __attribute__((ext_vector_type(8))) short bf16x8;
typedef __attribute__((ext_vector_type(4))) float f32x4;

__device__ __forceinline__ float sigm(float x){ return 1.f/(1.f+expf(-x)); }
__device__ __forceinline__ float siluf(float x){ return x/(1.f+expf(-x)); }
__device__ __forceinline__ float b2f(unsigned short u){
  union { unsigned int i; float f; } x; x.i = ((unsigned int)u) << 16; return x.f;
}
__device__ __forceinline__ unsigned short f2bu(float f){
  __hip_bfloat16 h = __float2bfloat16(f);
  return *(unsigned short*)&h;
}

__device__ __forceinline__ void glds16(const __hip_bfloat16* g, void* l) {
  __builtin_amdgcn_global_load_lds((const __attribute__((address_space(1))) void*)g,
                                   (__attribute__((address_space(3))) void*)l, 16, 0, 0);
}

// ---------------- casts -----------------------------------------------------
__global__ __launch_bounds__(256) void cast_k(const float* __restrict__ in,
    unsigned short* __restrict__ out, int n4)
{
  int i = blockIdx.x*256 + threadIdx.x;
  if (i >= n4) return;
  float4 v = ((const float4*)in)[i];
  ushort4 o;
  o.x = f2bu(v.x); o.y = f2bu(v.y); o.z = f2bu(v.z); o.w = f2bu(v.w);
  ((ushort4*)out)[i] = o;
}

// transpose + cast: in fp32 [R][C] -> out bf16 [Cpad][R]
__global__ __launch_bounds__(256) void tcast_k(const float* __restrict__ in,
    __hip_bfloat16* __restrict__ out, int R, int C, int Cpad)
{
  __shared__ float tile[32][33];
  const int tx = threadIdx.x & 31, ty = threadIdx.x >> 5;
  const int c = blockIdx.x*32 + tx;
  #pragma unroll
  for (int i = 0; i < 4; ++i) {
    int r = blockIdx.y*32 + ty + i*8;
    tile[ty + i*8][tx] = (c < C) ? in[(size_t)r*C + c] : 0.f;
  }
  __syncthreads();
  #pragma unroll
  for (int i = 0; i < 4; ++i) {
    int orow = blockIdx.x*32 + ty + i*8;
    int ocol = blockIdx.y*32 + tx;
    out[(size_t)orow*R + ocol] = __float2bfloat16(tile[tx][ty + i*8]);
  }
}

// ---------------- bf16 MFMA GEMM: C = A[M][K] @ Bt[N][K]^T ------------------
// EPI: 0 = fp32 out, 1 = silu -> bf16, 2 = +bias -> bf16
template<int EPI>
__global__ __launch_bounds__(256) void mgemm_k(
    const __hip_bfloat16* __restrict__ A,
    const __hip_bfloat16* __restrict__ Bt,
    const float* __restrict__ bias,
    float* __restrict__ Cf, __hip_bfloat16* __restrict__ Cb,
    int M, int N, int K)
{
  __shared__ __hip_bfloat16 As[128*32];
  __shared__ __hip_bfloat16 Bs[128*32];
  const int tid = threadIdx.x;
  const int w = tid >> 6, l = tid & 63;
  const int wr = w >> 1, wc = w & 1;
  const int row0 = blockIdx.y*128, col0 = blockIdx.x*128;
  const int fr = l & 15, fq = l >> 4;

  f32x4 acc[4][4];
  #pragma unroll
  for (int m = 0; m < 4; ++m)
    #pragma unroll
    for (int n = 0; n < 4; ++n)
      acc[m][n] = (f32x4){0.f,0.f,0.f,0.f};

  const int e0 = w*512 + l*8;
  const int r0s = e0 >> 5, c0s = e0 & 31;

  for (int k0 = 0; k0 < K; k0 += 32) {
    glds16(&A[(size_t)(row0 + r0s)*K + k0 + c0s],       (char*)As + w*1024);
    glds16(&A[(size_t)(row0 + r0s + 64)*K + k0 + c0s],  (char*)As + 4096 + w*1024);
    glds16(&Bt[(size_t)(col0 + r0s)*K + k0 + c0s],      (char*)Bs + w*1024);
    glds16(&Bt[(size_t)(col0 + r0s + 64)*K + k0 + c0s], (char*)Bs + 4096 + w*1024);
    __syncthreads();

    bf16x8 af[4], bfv[4];
    #pragma unroll
    for (int m = 0; m < 4; ++m)
      af[m] = *(const bf16x8*)&As[(wr*64 + m*16 + fr)*32 + fq*8];
    #pragma unroll
    for (int n = 0; n < 4; ++n)
      bfv[n] = *(const bf16x8*)&Bs[(wc*64 + n*16 + fr)*32 + fq*8];
    #pragma unroll
    for (int m = 0; m < 4; ++m)
      #pragma unroll
      for (int n = 0; n < 4; ++n)
        acc[m][n] = __builtin_amdgcn_mfma_f32_16x16x32_bf16(af[m], bfv[n], acc[m][n], 0, 0, 0);
    __syncthreads();
  }

  #pragma unroll
  for (int n = 0; n < 4; ++n) {
    const int ccol = col0 + wc*64 + n*16 + fr;
    if (ccol >= N) continue;
    #pragma unroll
    for (int m = 0; m < 4; ++m) {
      #pragma unroll
      for (int r = 0; r < 4; ++r) {
        const int crow = row0 + wr*64 + m*16 + fq*4 + r;
        float v = acc[m][n][r];
        if (EPI == 1)      Cb[(size_t)crow*N + ccol] = __float2bfloat16(siluf(v));
        else if (EPI == 2) Cb[(size_t)crow*N + ccol] = __float2bfloat16(v + bias[ccol]);
        else               Cf[(size_t)crow*N + ccol] = v;
      }
    }
  }
}

// ---------------- silu + l2norm for q,k; g and beta ------------------------
__global__ __launch_bounds__(256) void actv_k(const float* __restrict__ qkvabz,
    const float* __restrict__ A_log, const float* __restrict__ dt_bias,
    float* __restrict__ kn, unsigned short* __restrict__ qnb,
    unsigned short* __restrict__ knb,
    float* __restrict__ g, float* __restrict__ beta)
{
  int gid = blockIdx.x*4 + (threadIdx.x >> 6);
  int lane = threadIdx.x & 63;
  int row = gid >> 3; int h = gid & 7;
  const float* base = qkvabz + (size_t)row * NCOL;
  float qv = base[h*64 + lane];
  float kv = base[TKD + h*64 + lane];
  float sq = siluf(qv), sk = siluf(kv);
  float ssq = sq*sq, ssk = sk*sk;
  #pragma unroll
  for (int o = 32; o; o >>= 1) { ssq += __shfl_xor(ssq, o); ssk += __shfl_xor(ssk, o); }
  float qn_v = sq * rsqrtf(ssq + 1e-6f) * 0.125f;
  float kn_v = sk * rsqrtf(ssk + 1e-6f);
  size_t idx = (size_t)row*TKD + h*64 + lane;
  kn[idx]  = kn_v;
  qnb[idx] = f2bu(qn_v);
  knb[idx] = f2bu(kn_v);
  if (lane == 0) {
    float av = base[2048 + h] + dt_bias[h];
    float sp = fmaxf(av, 0.f) + log1pf(expf(-fabsf(av)));
    g[(size_t)row*NH + h] = -expf(A_log[h]) * sp;
    float bv = base[2056 + h];
    beta[(size_t)row*NH + h] = sigm(bv);
  }
}

// ---------------- dynamic conv (bf16 kernels) -------------------------------
__global__ __launch_bounds__(256) void conv_k(const float* __restrict__ qkvabz,
   const __hip_bfloat16* __restrict__ kern, const float* __restrict__ conv_state,
   float* __restrict__ vconv)
{
  int idx = blockIdx.x*256 + threadIdx.x;
  int c = idx & (TVD-1);
  int bs = idx >> 10;
  int s = bs & (SEQ-1); int b = bs >> 10;
  ushort4 kf = *(const ushort4*)&kern[(size_t)idx * 4];
  float kj[4] = { b2f(kf.x), b2f(kf.y), b2f(kf.z), b2f(kf.w) };
  float acc = 0.f;
  #pragma unroll
  for (int j = 0; j < 4; ++j) {
    int i = s + j;
    float xv = (i < 3) ? conv_state[((size_t)b*TVD + c)*3 + i]
                       : qkvabz[((size_t)(b*SEQ + (i-3)))*NCOL + TKD*2 + c];
    acc = fmaf(xv, kj[j], acc);
  }
  vconv[idx] = siluf(acc);
}

// ============ chunked gated delta rule =====================================
// Phase A: per (bh, chunk): A-matrix, trisolve -> Utilde, Wtilde;
//          D = eG*I - Kw^T Wtilde, b = Kw^T Utilde;
//          emits bf16 transposed UvT [v][t], WnTb = -Wtilde^T [d][t]
__global__ __launch_bounds__(256) void chunkA_k(const float* __restrict__ kn,
   const float* __restrict__ vconv, const float* __restrict__ gb,
   const float* __restrict__ bb, float* __restrict__ Gcbuf,
   float* __restrict__ Dbuf, float* __restrict__ Bvec,
   unsigned short* __restrict__ UvT, unsigned short* __restrict__ WnTb)
{
  const int blk = blockIdx.x;
  const int bh = blk >> 4, c = blk & 15;
  const int b = bh >> 3, h = bh & 7;
  const int tid = threadIdx.x;
  const int row0 = b*SEQ + c*64;
  __shared__ float Ksh[64][68];
  __shared__ float Xv[64][132];
  __shared__ float Xw[64][68];
  __shared__ float Ash[64][68];   // A-matrix; later reused for Kw
  __shared__ float Gsh[64], Bsh[64];

  #pragma unroll
  for (int i = 0; i < 4; ++i) {
    int lin = tid + i*256; int t = lin >> 4, d4 = (lin & 15)*4;
    float4 kv = *(const float4*)&kn[(size_t)(row0+t)*TKD + h*64 + d4];
    Ksh[t][d4]=kv.x; Ksh[t][d4+1]=kv.y; Ksh[t][d4+2]=kv.z; Ksh[t][d4+3]=kv.w;
  }
  #pragma unroll
  for (int i = 0; i < 8; ++i) {
    int lin = tid + i*256; int t = lin >> 5, v4 = (lin & 31)*4;
    float4 vv = *(const float4*)&vconv[(size_t)(row0+t)*TVD + h*128 + v4];
    Xv[t][v4]=vv.x; Xv[t][v4+1]=vv.y; Xv[t][v4+2]=vv.z; Xv[t][v4+3]=vv.w;
  }
  if (tid < 64) {
    float gv = gb[(size_t)(row0+tid)*NH + h];
    #pragma unroll
    for (int o = 1; o < 64; o <<= 1) {
      float oth = __shfl_up(gv, o);
      if (tid >= o) gv += oth;
    }
    Gsh[tid] = gv;
    Bsh[tid] = bb[(size_t)(row0+tid)*NH + h];
    Gcbuf[(size_t)blk*64 + tid] = gv;
  }
  __syncthreads();

  #pragma unroll
  for (int i = 0; i < 16; ++i) {
    int e = tid + i*256; int t = e >> 6, s = e & 63;
    float val = 0.f;
    if (s < t) {
      float acc = 0.f;
      #pragma unroll 8
      for (int d = 0; d < 64; ++d) acc = fmaf(Ksh[t][d], Ksh[s][d], acc);
      val = Bsh[t] * expf(Gsh[t] - Gsh[s]) * acc;
    }
    Ash[t][s] = val;
  }
  #pragma unroll
  for (int i = 0; i < 8; ++i) {
    int lin = tid + i*256; int t = lin >> 5, v4 = (lin & 31)*4;
    float bt = Bsh[t];
    Xv[t][v4]*=bt; Xv[t][v4+1]*=bt; Xv[t][v4+2]*=bt; Xv[t][v4+3]*=bt;
  }
  #pragma unroll
  for (int i = 0; i < 4; ++i) {
    int lin = tid + i*256; int t = lin >> 4, d4 = (lin & 15)*4;
    float f = Bsh[t]*expf(Gsh[t]);
    Xw[t][d4+0]=f*Ksh[t][d4+0]; Xw[t][d4+1]=f*Ksh[t][d4+1];
    Xw[t][d4+2]=f*Ksh[t][d4+2]; Xw[t][d4+3]=f*Ksh[t][d4+3];
  }
  __syncthreads();

  // forward substitution
  if (tid < 192) {
    float* colp; int stride;
    if (tid < 128) { colp = &Xv[0][tid];     stride = 132; }
    else           { colp = &Xw[0][tid-128]; stride = 68;  }
    for (int t = 1; t < 64; ++t) {
      float a0 = 0.f, a1 = 0.f;
      int s = 0;
      for (; s + 1 < t; s += 2) {
        a0 = fmaf(Ash[t][s],   colp[s*stride],     a0);
        a1 = fmaf(Ash[t][s+1], colp[(s+1)*stride], a1);
      }
      if (s < t) a0 = fmaf(Ash[t][s], colp[s*stride], a0);
      colp[t*stride] -= (a0 + a1);
    }
  }
  __syncthreads();

  // Kw[t][d] = exp(Gtot - G_t) * k_t  into Ash (A-matrix dead)
  const float Gtot = Gsh[63];
  #pragma unroll
  for (int i = 0; i < 4; ++i) {
    int lin = tid + i*256; int t = lin >> 4, d4 = (lin & 15)*4;
    float f = expf(Gtot - Gsh[t]);
    Ash[t][d4+0]=f*Ksh[t][d4+0]; Ash[t][d4+1]=f*Ksh[t][d4+1];
    Ash[t][d4+2]=f*Ksh[t][d4+2]; Ash[t][d4+3]=f*Ksh[t][d4+3];
  }
  __syncthreads();

  // D = eG*I - Kw^T Wtilde
  {
    const int d1b = (tid >> 4)*4, d2b = (tid & 15)*4;
    float dacc[4][4] = {};
    #pragma unroll 8
    for (int t = 0; t < 64; ++t) {
      float4 kw = *(const float4*)&Ash[t][d1b];
      float4 wv = *(const float4*)&Xw[t][d2b];
      float kwa[4] = {kw.x,kw.y,kw.z,kw.w};
      float wva[4] = {wv.x,wv.y,wv.z,wv.w};
      #pragma unroll
      for (int i = 0; i < 4; ++i)
        #pragma unroll
        for (int j = 0; j < 4; ++j)
          dacc[i][j] = fmaf(kwa[i], wva[j], dacc[i][j]);
    }
    const float eG = expf(Gtot);
    #pragma unroll
    for (int i = 0; i < 4; ++i) {
      float vals[4];
      #pragma unroll
      for (int j = 0; j < 4; ++j) {
        float v = -dacc[i][j];
        if (d1b + i == d2b + j) v += eG;
        vals[j] = v;
      }
      *(float4*)&Dbuf[(size_t)blk*4096 + (d1b+i)*64 + d2b] =
        make_float4(vals[0],vals[1],vals[2],vals[3]);
    }
  }
  // b = Kw^T Utilde
  {
    const int d1b = (tid >> 4)*4, vb = (tid & 15)*8;
    float bacc[4][8] = {};
    #pragma unroll 4
    for (int t = 0; t < 64; ++t) {
      float4 kw = *(const float4*)&Ash[t][d1b];
      float4 u0 = *(const float4*)&Xv[t][vb];
      float4 u1 = *(const float4*)&Xv[t][vb+4];
      float kwa[4] = {kw.x,kw.y,kw.z,kw.w};
      float ua[8] = {u0.x,u0.y,u0.z,u0.w,u1.x,u1.y,u1.z,u1.w};
      #pragma unroll
      for (int i = 0; i < 4; ++i)
        #pragma unroll
        for (int j = 0; j < 8; ++j)
          bacc[i][j] = fmaf(kwa[i], ua[j], bacc[i][j]);
    }
    #pragma unroll
    for (int i = 0; i < 4; ++i) {
      *(float4*)&Bvec[(size_t)blk*8192 + (d1b+i)*128 + vb] =
        make_float4(bacc[i][0],bacc[i][1],bacc[i][2],bacc[i][3]);
      *(float4*)&Bvec[(size_t)blk*8192 + (d1b+i)*128 + vb + 4] =
        make_float4(bacc[i][4],bacc[i][5],bacc[i][6],bacc[i][7]);
    }
  }

  // transposed bf16 outputs for chunkC: UvT[v][t], WnTb[d][t] = -Wtilde^T
  {
    const int w = tid >> 6, l = tid & 63;
    #pragma unroll
    for (int i = 0; i < 32; ++i) {
      int v = w*32 + i;
      UvT[(size_t)blk*8192 + v*64 + l] = f2bu(Xv[l][v]);
    }
    #pragma unroll
    for (int i = 0; i < 16; ++i) {
      int d = w*16 + i;
      WnTb[(size_t)blk*4096 + d*64 + l] = f2bu(-Xw[l][d]);
    }
  }
}

// Phase B: h_{c+1} = D_c h_c + b_c ; 128 blocks (bh x 8 vgroups of 16)
// writes HcT bf16 [cblk][128 v][64 d]
__global__ __launch_bounds__(256) void chunkB2_k(const float* __restrict__ Dbuf,
   const float* __restrict__ Bvec, const float* __restrict__ init,
   unsigned short* __restrict__ HcT)
{
  const int blk = blockIdx.x;
  const int bh = blk >> 3, grp = blk & 7;
  const int v0 = grp*16;
  const int tid = threadIdx.x;
  const int v = tid & 15;
  const int d1b = (tid >> 4) * 4;
  __shared__ float DT[64][68];
  __shared__ float bsh[64][17];
  __shared__ float hsh[64][17];

  float hreg[4];
  #pragma unroll
  for (int j = 0; j < 4; ++j) {
    hreg[j] = init[((size_t)bh*64 + d1b + j)*128 + v0 + v];
    hsh[d1b + j][v] = hreg[j];
  }
  float Dreg[16], breg[4];
  {
    const float* Dp = Dbuf + (size_t)(bh*16)*4096;
    const float* bp = Bvec + (size_t)(bh*16)*8192;
    #pragma unroll
    for (int i = 0; i < 16; ++i) Dreg[i] = Dp[tid + i*256];
    #pragma unroll
    for (int i = 0; i < 4; ++i)  breg[i] = bp[(size_t)((tid>>4) + i*16)*128 + v0 + v];
  }
  #pragma unroll
  for (int i = 0; i < 16; ++i) {
    int cell = tid + i*256; DT[cell & 63][cell >> 6] = Dreg[i];
  }
  #pragma unroll
  for (int i = 0; i < 4; ++i) bsh[(tid>>4) + i*16][v] = breg[i];
  __syncthreads();

  for (int c = 0; c < 16; ++c) {
    if (c < 15) {
      const float* Dn = Dbuf + (size_t)(bh*16 + c + 1)*4096;
      const float* bn = Bvec + (size_t)(bh*16 + c + 1)*8192;
      #pragma unroll
      for (int i = 0; i < 16; ++i) Dreg[i] = Dn[tid + i*256];
      #pragma unroll
      for (int i = 0; i < 4; ++i)  breg[i] = bn[(size_t)((tid>>4) + i*16)*128 + v0 + v];
    }
    #pragma unroll
    for (int j = 0; j < 4; ++j)
      HcT[(size_t)(bh*16 + c)*8192 + (size_t)(v0+v)*64 + d1b + j] = f2bu(hreg[j]);
    float nh[4];
    #pragma unroll
    for (int j = 0; j < 4; ++j) nh[j] = bsh[d1b + j][v];
    #pragma unroll 8
    for (int d2 = 0; d2 < 64; ++d2) {
      float hv = hsh[d2][v];
      float4 dv = *(const float4*)&DT[d2][d1b];
      nh[0] = fmaf(dv.x, hv, nh[0]);
      nh[1] = fmaf(dv.y, hv, nh[1]);
      nh[2] = fmaf(dv.z, hv, nh[2]);
      nh[3] = fmaf(dv.w, hv, nh[3]);
    }
    __syncthreads();
    #pragma unroll
    for (int j = 0; j < 4; ++j) { hreg[j] = nh[j]; hsh[d1b + j][v] = nh[j]; }
    if (c < 15) {
      #pragma unroll
      for (int i = 0; i < 16; ++i) {
        int cell = tid + i*256; DT[cell & 63][cell >> 6] = Dreg[i];
      }
      #pragma unroll
      for (int i = 0; i < 4; ++i) bsh[(tid>>4) + i*16][v] = breg[i];
    }
    __syncthreads();
  }
}

// Phase C (MFMA): S = decayed-masked QK^T; Qt = E.Q - S Wt; o = Qt h + S U
__global__ __launch_bounds__(256) void chunkC_k(
   const unsigned short* __restrict__ qnb, const unsigned short* __restrict__ knb,
   const unsigned short* __restrict__ UvT, const unsigned short* __restrict__ WnTb,
   const float* __restrict__ Gcbuf, const unsigned short* __restrict__ HcT,
   float* __restrict__ oattn)
{
  const int blk = blockIdx.x; const int bh = blk >> 4, c = blk & 15;
  const int b = bh >> 3, h = bh & 7;
  const int row0 = b*SEQ + c*64;
  const int tid = threadIdx.x;
  const int w = tid >> 6, l = tid & 63;
  const int fr = l & 15, fq = l >> 4;

  __shared__ unsigned short Qs[64*72];
  __shared__ unsigned short Ks[64*72];   // K rows s; later Qtilde rows t
  __shared__ unsigned short Ws[64*72];   // -Wtilde^T rows d
  __shared__ unsigned short hT[128*72];  // h^T rows v
  __shared__ unsigned short UT[128*72];  // U^T rows v
  __shared__ unsigned short Ss[64*72];   // S rows t
  __shared__ float Gsh[64], Esh[64];

  #pragma unroll
  for (int j = 0; j < 2; ++j) {
    int lin = tid + j*256; int t = lin >> 3, dq = (lin & 7)*8;
    *(uint4*)&Qs[t*72+dq] = *(const uint4*)&qnb[(size_t)(row0+t)*TKD + h*64 + dq];
    *(uint4*)&Ks[t*72+dq] = *(const uint4*)&knb[(size_t)(row0+t)*TKD + h*64 + dq];
    *(uint4*)&Ws[t*72+dq] = *(const uint4*)&WnTb[(size_t)blk*4096 + t*64 + dq];
  }
  #pragma unroll
  for (int j = 0; j < 4; ++j) {
    int lin = tid + j*256; int v = lin >> 3, dq = (lin & 7)*8;
    *(uint4*)&hT[v*72+dq] = *(const uint4*)&HcT[(size_t)blk*8192 + (size_t)v*64 + dq];
    *(uint4*)&UT[v*72+dq] = *(const uint4*)&UvT[(size_t)blk*8192 + (size_t)v*64 + dq];
  }
  if (tid < 64) { float g = Gcbuf[(size_t)blk*64 + tid]; Gsh[tid] = g; Esh[tid] = expf(g); }
  __syncthreads();

  // S = Q K^T  (wave w owns rows w*16..w*16+15)
  f32x4 accS[4];
  #pragma unroll
  for (int n = 0; n < 4; ++n) accS[n] = (f32x4){0.f,0.f,0.f,0.f};
  #pragma unroll
  for (int k0 = 0; k0 < 2; ++k0) {
    bf16x8 a = *(const bf16x8*)&Qs[(w*16+fr)*72 + k0*32 + fq*8];
    #pragma unroll
    for (int n = 0; n < 4; ++n) {
      bf16x8 bb = *(const bf16x8*)&Ks[(n*16+fr)*72 + k0*32 + fq*8];
      accS[n] = __builtin_amdgcn_mfma_f32_16x16x32_bf16(a, bb, accS[n], 0, 0, 0);
    }
  }
  // decay + mask + write S (own rows only)
  #pragma unroll
  for (int n = 0; n < 4; ++n)
    #pragma unroll
    for (int r = 0; r < 4; ++r) {
      int t = w*16 + fq*4 + r, s = n*16 + fr;
      float val = (s <= t) ? expf(Gsh[t]-Gsh[s]) * accS[n][r] : 0.f;
      Ss[t*72 + s] = f2bu(val);
    }

  // Qt = E.Q + S*(-Wt^T)
  f32x4 accQ[4];
  #pragma unroll
  for (int n = 0; n < 4; ++n) {
    #pragma unroll
    for (int r = 0; r < 4; ++r) {
      int t = w*16 + fq*4 + r, d = n*16 + fr;
      accQ[n][r] = Esh[t] * b2f(Qs[t*72 + d]);
    }
    #pragma unroll
    for (int k0 = 0; k0 < 2; ++k0) {
      bf16x8 a = *(const bf16x8*)&Ss[(w*16+fr)*72 + k0*32 + fq*8];
      bf16x8 bb = *(const bf16x8*)&Ws[(n*16+fr)*72 + k0*32 + fq*8];
      accQ[n] = __builtin_amdgcn_mfma_f32_16x16x32_bf16(a, bb, accQ[n], 0, 0, 0);
    }
  }
  __syncthreads();   // all waves done reading K before overwrite

  #pragma unroll
  for (int n = 0; n < 4; ++n)
    #pragma unroll
    for (int r = 0; r < 4; ++r) {
      int t = w*16 + fq*4 + r, d = n*16 + fr;
      Ks[t*72 + d] = f2bu(accQ[n][r]);
    }

  // o = Qt h + S U   (reads own rows of Ks/Ss only)
  #pragma unroll
  for (int n = 0; n < 8; ++n) {
    f32x4 acc = (f32x4){0.f,0.f,0.f,0.f};
    #pragma unroll
    for (int k0 = 0; k0 < 2; ++k0) {
      bf16x8 a1 = *(const bf16x8*)&Ks[(w*16+fr)*72 + k0*32 + fq*8];
      bf16x8 b1 = *(const bf16x8*)&hT[(n*16+fr)*72 + k0*32 + fq*8];
      acc = __builtin_amdgcn_mfma_f32_16x16x32_bf16(a1, b1, acc, 0, 0, 0);
      bf16x8 a2 = *(const bf16x8*)&Ss[(w*16+fr)*72 + k0*32 + fq*8];
      bf16x8 b2v = *(const bf16x8*)&UT[(n*16+fr)*72 + k0*32 + fq*8];
      acc = __builtin_amdgcn_mfma_f32_16x16x32_bf16(a2, b2v, acc, 0, 0, 0);
    }
    #pragma unroll
    for (int r = 0; r < 4; ++r) {
      int t = w*16 + fq*4 + r, v = n*16 + fr;
      oattn[(size_t)(row0+t)*TVD + h*128 + v] = acc[r];
    }
  }
}

// ---------------- gated RMSNorm -> bf16 ------------------------------------
__global__ __launch_bounds__(256) void norm_k(const float* __restrict__ oattn,
   const float* __restrict__ qkvabz, const float* __restrict__ onw,
   __hip_bfloat16* __restrict__ ofin)
{
  int gid = blockIdx.x*4 + (threadIdx.x >> 6);
  int lane = threadIdx.x & 63;
  int row = gid >> 3; int h = gid & 7;
  size_t ob = (size_t)row*TVD + h*128;
  float2 ov = *(const float2*)&oattn[ob + lane*2];
  float2 zv = *(const float2*)&qkvabz[(size_t)row*NCOL + 2064 + h*128 + lane*2];
  float g0 = ov.x * siluf(zv.x), g1 = ov.y * siluf(zv.y);
  float ss = g0*g0 + g1*g1;
  #pragma unroll
  for (int o = 32; o; o >>= 1) ss += __shfl_xor(ss, o);
  float r = rsqrtf(ss * (1.f/128.f) + 1e-6f);
  ofin[ob + lane*2]     = __float2bfloat16(g0 * r * onw[lane*2]);
  ofin[ob + lane*2 + 1] = __float2bfloat16(g1 * r * onw[lane*2+1]);
}

extern "C" void kernel_launch(void* const* d_in, const int* in_sizes, int n_in,
                              void* d_out, int out_size, void* d_ws, size_t ws_size,
                              hipStream_t stream) {
  const float* hidden     = (const float*)d_in[0];
  const float* Wqkvabz    = (const float*)d_in[1];
  const float* A_log      = (const float*)d_in[2];
  const float* dt_bias    = (const float*)d_in[3];
  const float* conv_state = (const float*)d_in[4];
  const float* w1         = (const float*)d_in[5];
  const float* w2         = (const float*)d_in[6];
  const float* b2         = (const float*)d_in[7];
  const float* init_state = (const float*)d_in[8];
  const float* o_norm_w   = (const float*)d_in[9];
  const float* W_o        = (const float*)d_in[10];
  float* out = (float*)d_out;

  float* ws = (float*)d_ws;
  float* qkvabz = ws;                                  // 6,324,224 f
  float* kern   = qkvabz + (size_t)6324224;            // 8,388,608 f region
  float* qn     = kern   + (size_t)8388608;            // 1,048,576 (spare)
  float* kn     = qn     + (size_t)1048576;            // 1,048,576
  float* gbuf   = kn     + (size_t)1048576;            // 16,384
  float* bbuf   = gbuf   + (size_t)16384;              // 16,384
  float* vconv  = bbuf   + (size_t)16384;              // 2,097,152
  float* bfpool = vconv  + (size_t)2097152;
  __hip_bfloat16* hidden_bf = (__hip_bfloat16*)bfpool;       // 4,194,304 e
  __hip_bfloat16* w1t   = hidden_bf + (size_t)4194304;
  __hip_bfloat16* w2t   = w1t + (size_t)262144;
  __hip_bfloat16* Wot   = w2t + (size_t)524288;
  __hip_bfloat16* x1sb  = Wot + (size_t)2097152;
  __hip_bfloat16* ofinb = x1sb + (size_t)262144;
  float* Gcbuf  = (float*)(ofinb + (size_t)2097152);         // 16,384 f
  // aliases inside the kern region:
  __hip_bfloat16* Wqkvt  = (__hip_bfloat16*)kern;            // [3200][2048] bf16, f-off [0, 3.28M)
  __hip_bfloat16* kernbf = (__hip_bfloat16*)kern;            // 8,388,608 u16, f-off [0, 4.19M)
  float* oattn  = kern;                                      // [0, 2M)
  float* Dbuf   = kern + (size_t)2097152;                    // [2M, 3M)
  float* Bvec   = kern + (size_t)3145728;                    // [3M, 5M)
  unsigned short* UvTb  = (unsigned short*)(kern + (size_t)5242880);  // 2,097,152 u16 [5M, 6M)
  unsigned short* WnTbb = (unsigned short*)(kern + (size_t)6291456);  // 1,048,576 u16 [6M, 6.5M)
  unsigned short* qnb   = (unsigned short*)(kern + (size_t)6815744);  // 1,048,576 u16 [6.5M, 7M)
  unsigned short* knb   = (unsigned short*)(kern + (size_t)7340032);  // 1,048,576 u16 [7M, 7.5M)
  unsigned short* HcTb  = (unsigned short*)vconv;            // 2,097,152 u16 (vconv dead after chunkA)

  dim3 blk(256);
  cast_k<<<4096, blk, 0, stream>>>(hidden, (unsigned short*)hidden_bf, 1048576);
  tcast_k<<<dim3(100,64), blk, 0, stream>>>(Wqkvabz, Wqkvt, 2048, 3088, 3200);
  tcast_k<<<dim3(4,64),   blk, 0, stream>>>(w1,  w1t, 2048, 128, 128);
  tcast_k<<<dim3(128,4),  blk, 0, stream>>>(w2,  w2t, 128, 4096, 4096);
  tcast_k<<<dim3(64,32),  blk, 0, stream>>>(W_o, Wot, 1024, 2048, 2048);
  mgemm_k<0><<<dim3(25,16), blk, 0, stream>>>(hidden_bf, Wqkvt, nullptr, qkvabz, nullptr, 2048, 3088, 2048);
  mgemm_k<1><<<dim3(1,16),  blk, 0, stream>>>(hidden_bf, w1t, nullptr, nullptr, x1sb, 2048, 128, 2048);
  mgemm_k<2><<<dim3(32,16), blk, 0, stream>>>(x1sb, w2t, b2, nullptr, kernbf, 2048, 4096, 128);
  actv_k<<<4096, blk, 0, stream>>>(qkvabz, A_log, dt_bias, kn, qnb, knb, gbuf, bbuf);
  conv_k<<<8192, blk, 0, stream>>>(qkvabz, kernbf, conv_state, vconv);
  chunkA_k<<<256, blk, 0, stream>>>(kn, vconv, gbuf, bbuf, Gcbuf, Dbuf, Bvec, UvTb, WnTbb);
  chunkB2_k<<<128, blk, 0, stream>>>(Dbuf, Bvec, init_state, HcTb);
  chunkC_k<<<256, blk, 0, stream>>>(qnb, knb, UvTb, WnTbb, Gcbuf, HcTb, oattn);
  norm_k<<<4096, blk, 0, stream>>>(oattn, qkvabz, o_norm_w, ofinb);
  mgemm_k<0><<<dim3(16,16), blk, 0, stream>>>(ofinb, Wot, nullptr, out, nullptr, 2048, 2048, 1024);
}

// Round 6
// 250.457 us; speedup vs baseline: 7.2145x; 1.1336x over previous
//
#include <hip/hip_runtime.h>
#include <hip/hip_bf16.h>
#include <math.h>
#include <stdint.h>

#define BATCH 2
#define SEQ 1024
#define HIDDIM 2048
#define NH 8
#define DKD 64
#define DVD 128
#define TKD 512
#define TVD 1024
#define NCOL 3088   // TK+TK+TV+H+H+TV
#define KSZ 4
#define NCHK 16

typedef __attribute__((ext_vector_type(8))) short bf16x8;
typedef __attribute__((ext_vector_type(4))) float f32x4;

__device__ __forceinline__ float sigm(float x){ return 1.f/(1.f+expf(-x)); }
__device__ __forceinline__ float siluf(float x){ return x/(1.f+expf(-x)); }
__device__ __forceinline__ float b2f(unsigned short u){
  union { unsigned int i; float f; } x; x.i = ((unsigned int)u) << 16; return x.f;
}
__device__ __forceinline__ unsigned short f2bu(float f){
  __hip_bfloat16 h = __float2bfloat16(f);
  return *(unsigned short*)&h;
}

__device__ __forceinline__ void glds16(const __hip_bfloat16* g, void* l) {
  __builtin_amdgcn_global_load_lds((const __attribute__((address_space(1))) void*)g,
                                   (__attribute__((address_space(3))) void*)l, 16, 0, 0);
}

// ---------------- casts -----------------------------------------------------
__global__ __launch_bounds__(256) void cast_k(const float* __restrict__ in,
    unsigned short* __restrict__ out, int n4)
{
  int i = blockIdx.x*256 + threadIdx.x;
  if (i >= n4) return;
  float4 v = ((const float4*)in)[i];
  ushort4 o;
  o.x = f2bu(v.x); o.y = f2bu(v.y); o.z = f2bu(v.z); o.w = f2bu(v.w);
  ((ushort4*)out)[i] = o;
}

// transpose + cast: in fp32 [R][C] -> out bf16 [Cpad][R]
__global__ __launch_bounds__(256) void tcast_k(const float* __restrict__ in,
    __hip_bfloat16* __restrict__ out, int R, int C, int Cpad)
{
  __shared__ float tile[32][33];
  const int tx = threadIdx.x & 31, ty = threadIdx.x >> 5;
  const int c = blockIdx.x*32 + tx;
  #pragma unroll
  for (int i = 0; i < 4; ++i) {
    int r = blockIdx.y*32 + ty + i*8;
    tile[ty + i*8][tx] = (c < C) ? in[(size_t)r*C + c] : 0.f;
  }
  __syncthreads();
  #pragma unroll
  for (int i = 0; i < 4; ++i) {
    int orow = blockIdx.x*32 + ty + i*8;
    int ocol = blockIdx.y*32 + tx;
    out[(size_t)orow*R + ocol] = __float2bfloat16(tile[tx][ty + i*8]);
  }
}

// ---------------- bf16 MFMA GEMM: C = A[M][K] @ Bt[N][K]^T ------------------
// EPI: 0 = fp32 out, 1 = silu -> bf16, 2 = +bias -> bf16
template<int EPI>
__global__ __launch_bounds__(256) void mgemm_k(
    const __hip_bfloat16* __restrict__ A,
    const __hip_bfloat16* __restrict__ Bt,
    const float* __restrict__ bias,
    float* __restrict__ Cf, __hip_bfloat16* __restrict__ Cb,
    int M, int N, int K)
{
  __shared__ __hip_bfloat16 As[128*32];
  __shared__ __hip_bfloat16 Bs[128*32];
  const int tid = threadIdx.x;
  const int w = tid >> 6, l = tid & 63;
  const int wr = w >> 1, wc = w & 1;
  const int row0 = blockIdx.y*128, col0 = blockIdx.x*128;
  const int fr = l & 15, fq = l >> 4;

  f32x4 acc[4][4];
  #pragma unroll
  for (int m = 0; m < 4; ++m)
    #pragma unroll
    for (int n = 0; n < 4; ++n)
      acc[m][n] = (f32x4){0.f,0.f,0.f,0.f};

  const int e0 = w*512 + l*8;
  const int r0s = e0 >> 5, c0s = e0 & 31;

  for (int k0 = 0; k0 < K; k0 += 32) {
    glds16(&A[(size_t)(row0 + r0s)*K + k0 + c0s],       (char*)As + w*1024);
    glds16(&A[(size_t)(row0 + r0s + 64)*K + k0 + c0s],  (char*)As + 4096 + w*1024);
    glds16(&Bt[(size_t)(col0 + r0s)*K + k0 + c0s],      (char*)Bs + w*1024);
    glds16(&Bt[(size_t)(col0 + r0s + 64)*K + k0 + c0s], (char*)Bs + 4096 + w*1024);
    __syncthreads();

    bf16x8 af[4], bfv[4];
    #pragma unroll
    for (int m = 0; m < 4; ++m)
      af[m] = *(const bf16x8*)&As[(wr*64 + m*16 + fr)*32 + fq*8];
    #pragma unroll
    for (int n = 0; n < 4; ++n)
      bfv[n] = *(const bf16x8*)&Bs[(wc*64 + n*16 + fr)*32 + fq*8];
    #pragma unroll
    for (int m = 0; m < 4; ++m)
      #pragma unroll
      for (int n = 0; n < 4; ++n)
        acc[m][n] = __builtin_amdgcn_mfma_f32_16x16x32_bf16(af[m], bfv[n], acc[m][n], 0, 0, 0);
    __syncthreads();
  }

  #pragma unroll
  for (int n = 0; n < 4; ++n) {
    const int ccol = col0 + wc*64 + n*16 + fr;
    if (ccol >= N) continue;
    #pragma unroll
    for (int m = 0; m < 4; ++m) {
      #pragma unroll
      for (int r = 0; r < 4; ++r) {
        const int crow = row0 + wr*64 + m*16 + fq*4 + r;
        float v = acc[m][n][r];
        if (EPI == 1)      Cb[(size_t)crow*N + ccol] = __float2bfloat16(siluf(v));
        else if (EPI == 2) Cb[(size_t)crow*N + ccol] = __float2bfloat16(v + bias[ccol]);
        else               Cf[(size_t)crow*N + ccol] = v;
      }
    }
  }
}

// ---------------- silu + l2norm for q,k; g and beta ------------------------
__global__ __launch_bounds__(256) void actv_k(const float* __restrict__ qkvabz,
    const float* __restrict__ A_log, const float* __restrict__ dt_bias,
    float* __restrict__ kn, unsigned short* __restrict__ qnb,
    unsigned short* __restrict__ knb,
    float* __restrict__ g, float* __restrict__ beta)
{
  int gid = blockIdx.x*4 + (threadIdx.x >> 6);
  int lane = threadIdx.x & 63;
  int row = gid >> 3; int h = gid & 7;
  const float* base = qkvabz + (size_t)row * NCOL;
  float qv = base[h*64 + lane];
  float kv = base[TKD + h*64 + lane];
  float sq = siluf(qv), sk = siluf(kv);
  float ssq = sq*sq, ssk = sk*sk;
  #pragma unroll
  for (int o = 32; o; o >>= 1) { ssq += __shfl_xor(ssq, o); ssk += __shfl_xor(ssk, o); }
  float qn_v = sq * rsqrtf(ssq + 1e-6f) * 0.125f;
  float kn_v = sk * rsqrtf(ssk + 1e-6f);
  size_t idx = (size_t)row*TKD + h*64 + lane;
  kn[idx]  = kn_v;
  qnb[idx] = f2bu(qn_v);
  knb[idx] = f2bu(kn_v);
  if (lane == 0) {
    float av = base[2048 + h] + dt_bias[h];
    float sp = fmaxf(av, 0.f) + log1pf(expf(-fabsf(av)));
    g[(size_t)row*NH + h] = -expf(A_log[h]) * sp;
    float bv = base[2056 + h];
    beta[(size_t)row*NH + h] = sigm(bv);
  }
}

// ---------------- dynamic conv (bf16 kernels) -------------------------------
__global__ __launch_bounds__(256) void conv_k(const float* __restrict__ qkvabz,
   const __hip_bfloat16* __restrict__ kern, const float* __restrict__ conv_state,
   float* __restrict__ vconv)
{
  int idx = blockIdx.x*256 + threadIdx.x;
  int c = idx & (TVD-1);
  int bs = idx >> 10;
  int s = bs & (SEQ-1); int b = bs >> 10;
  ushort4 kf = *(const ushort4*)&kern[(size_t)idx * 4];
  float kj[4] = { b2f(kf.x), b2f(kf.y), b2f(kf.z), b2f(kf.w) };
  float acc = 0.f;
  #pragma unroll
  for (int j = 0; j < 4; ++j) {
    int i = s + j;
    float xv = (i < 3) ? conv_state[((size_t)b*TVD + c)*3 + i]
                       : qkvabz[((size_t)(b*SEQ + (i-3)))*NCOL + TKD*2 + c];
    acc = fmaf(xv, kj[j], acc);
  }
  vconv[idx] = siluf(acc);
}

// ============ chunked gated delta rule =====================================
// Phase A: MFMA A-build + register-column trisolve + fp32 D/b
__global__ __launch_bounds__(256) void chunkA_k(const float* __restrict__ kn,
   const unsigned short* __restrict__ knb,
   const float* __restrict__ vconv, const float* __restrict__ gb,
   const float* __restrict__ bb, float* __restrict__ Gcbuf,
   float* __restrict__ Dbuf, float* __restrict__ Bvec,
   unsigned short* __restrict__ UvT, unsigned short* __restrict__ WnTb)
{
  const int blk = blockIdx.x;
  const int bh = blk >> 4, c = blk & 15;
  const int b = bh >> 3, h = bh & 7;
  const int tid = threadIdx.x;
  const int w = tid >> 6, l = tid & 63;
  const int fr = l & 15, fq = l >> 4;
  const int row0 = b*SEQ + c*64;

  __shared__ unsigned short Kb[64*72];   // bf16 K rows (9.2 KB)
  __shared__ float Xv[64][132];          // v -> Utilde (33.8 KB)
  __shared__ float Xw[64][68];           // beta*eG*K -> Wtilde (17.4 KB)
  __shared__ float AK[64][68];           // A-matrix; later Kw (17.4 KB)
  __shared__ float Gsh[64], Bsh[64];

  // ---- loads
  #pragma unroll
  for (int j = 0; j < 2; ++j) {
    int lin = tid + j*256; int t = lin >> 3, dq = (lin & 7)*8;
    *(uint4*)&Kb[t*72+dq] = *(const uint4*)&knb[(size_t)(row0+t)*TKD + h*64 + dq];
  }
  #pragma unroll
  for (int i = 0; i < 8; ++i) {
    int lin = tid + i*256; int t = lin >> 5, v4 = (lin & 31)*4;
    float4 vv = *(const float4*)&vconv[(size_t)(row0+t)*TVD + h*128 + v4];
    Xv[t][v4]=vv.x; Xv[t][v4+1]=vv.y; Xv[t][v4+2]=vv.z; Xv[t][v4+3]=vv.w;
  }
  if (tid < 64) {
    float gv = gb[(size_t)(row0+tid)*NH + h];
    #pragma unroll
    for (int o = 1; o < 64; o <<= 1) {
      float oth = __shfl_up(gv, o);
      if (tid >= o) gv += oth;
    }
    Gsh[tid] = gv;
    Bsh[tid] = bb[(size_t)(row0+tid)*NH + h];
    Gcbuf[(size_t)blk*64 + tid] = gv;
  }
  __syncthreads();

  // ---- A = K K^T (MFMA bf16), scaled/masked -> AK fp32; and Xw = beta*eG*K
  {
    f32x4 accS[4];
    #pragma unroll
    for (int n = 0; n < 4; ++n) accS[n] = (f32x4){0.f,0.f,0.f,0.f};
    #pragma unroll
    for (int k0 = 0; k0 < 2; ++k0) {
      bf16x8 a = *(const bf16x8*)&Kb[(w*16+fr)*72 + k0*32 + fq*8];
      #pragma unroll
      for (int n = 0; n < 4; ++n) {
        bf16x8 bb2 = *(const bf16x8*)&Kb[(n*16+fr)*72 + k0*32 + fq*8];
        accS[n] = __builtin_amdgcn_mfma_f32_16x16x32_bf16(a, bb2, accS[n], 0, 0, 0);
      }
    }
    #pragma unroll
    for (int n = 0; n < 4; ++n)
      #pragma unroll
      for (int r = 0; r < 4; ++r) {
        int t = w*16 + fq*4 + r, s = n*16 + fr;
        AK[t][s] = (s < t) ? Bsh[t]*expf(Gsh[t]-Gsh[s])*accS[n][r] : 0.f;
      }
  }
  #pragma unroll
  for (int i = 0; i < 4; ++i) {
    int lin = tid + i*256; int t = lin >> 4, d4 = (lin & 15)*4;
    float4 kv = *(const float4*)&kn[(size_t)(row0+t)*TKD + h*64 + d4];
    float f = Bsh[t]*expf(Gsh[t]);
    Xw[t][d4+0]=f*kv.x; Xw[t][d4+1]=f*kv.y; Xw[t][d4+2]=f*kv.z; Xw[t][d4+3]=f*kv.w;
  }
  __syncthreads();

  // ---- register-column forward substitution (192 cols)
  if (tid < 192) {
    float x[64];
    if (tid < 128) {
      #pragma unroll
      for (int t = 0; t < 64; ++t) x[t] = Bsh[t]*Xv[t][tid];
    } else {
      #pragma unroll
      for (int t = 0; t < 64; ++t) x[t] = Xw[t][tid-128];
    }
    #pragma unroll
    for (int t = 1; t < 64; ++t) {
      float a0=0.f, a1=0.f, a2=0.f, a3=0.f;
      #pragma unroll
      for (int s4 = 0; s4 < (t+3)/4; ++s4) {
        float4 av = *(const float4*)&AK[t][s4*4];
        a0 = fmaf(av.x, x[s4*4+0], a0);
        a1 = fmaf(av.y, x[s4*4+1], a1);
        a2 = fmaf(av.z, x[s4*4+2], a2);
        a3 = fmaf(av.w, x[s4*4+3], a3);
      }
      x[t] -= (a0+a1)+(a2+a3);
    }
    if (tid < 128) {
      #pragma unroll
      for (int t = 0; t < 64; ++t) Xv[t][tid] = x[t];
    } else {
      #pragma unroll
      for (int t = 0; t < 64; ++t) Xw[t][tid-128] = x[t];
    }
  }
  __syncthreads();

  // ---- Kw = exp(Gtot-G_t)*k_t into AK (A dead)
  const float Gtot = Gsh[63];
  #pragma unroll
  for (int i = 0; i < 4; ++i) {
    int lin = tid + i*256; int t = lin >> 4, d4 = (lin & 15)*4;
    float4 kv = *(const float4*)&kn[(size_t)(row0+t)*TKD + h*64 + d4];
    float f = expf(Gtot - Gsh[t]);
    AK[t][d4+0]=f*kv.x; AK[t][d4+1]=f*kv.y; AK[t][d4+2]=f*kv.z; AK[t][d4+3]=f*kv.w;
  }
  __syncthreads();

  // ---- D = eG*I - Kw^T Wtilde
  {
    const int d1b = (tid >> 4)*4, d2b = (tid & 15)*4;
    float dacc[4][4] = {};
    #pragma unroll 8
    for (int t = 0; t < 64; ++t) {
      float4 kw = *(const float4*)&AK[t][d1b];
      float4 wv = *(const float4*)&Xw[t][d2b];
      float kwa[4] = {kw.x,kw.y,kw.z,kw.w};
      float wva[4] = {wv.x,wv.y,wv.z,wv.w};
      #pragma unroll
      for (int i = 0; i < 4; ++i)
        #pragma unroll
        for (int j = 0; j < 4; ++j)
          dacc[i][j] = fmaf(kwa[i], wva[j], dacc[i][j]);
    }
    const float eG = expf(Gtot);
    #pragma unroll
    for (int i = 0; i < 4; ++i) {
      float vals[4];
      #pragma unroll
      for (int j = 0; j < 4; ++j) {
        float v = -dacc[i][j];
        if (d1b + i == d2b + j) v += eG;
        vals[j] = v;
      }
      *(float4*)&Dbuf[(size_t)blk*4096 + (d1b+i)*64 + d2b] =
        make_float4(vals[0],vals[1],vals[2],vals[3]);
    }
  }
  // ---- b = Kw^T Utilde
  {
    const int d1b = (tid >> 4)*4, vb = (tid & 15)*8;
    float bacc[4][8] = {};
    #pragma unroll 4
    for (int t = 0; t < 64; ++t) {
      float4 kw = *(const float4*)&AK[t][d1b];
      float4 u0 = *(const float4*)&Xv[t][vb];
      float4 u1 = *(const float4*)&Xv[t][vb+4];
      float kwa[4] = {kw.x,kw.y,kw.z,kw.w};
      float ua[8] = {u0.x,u0.y,u0.z,u0.w,u1.x,u1.y,u1.z,u1.w};
      #pragma unroll
      for (int i = 0; i < 4; ++i)
        #pragma unroll
        for (int j = 0; j < 8; ++j)
          bacc[i][j] = fmaf(kwa[i], ua[j], bacc[i][j]);
    }
    #pragma unroll
    for (int i = 0; i < 4; ++i) {
      *(float4*)&Bvec[(size_t)blk*8192 + (d1b+i)*128 + vb] =
        make_float4(bacc[i][0],bacc[i][1],bacc[i][2],bacc[i][3]);
      *(float4*)&Bvec[(size_t)blk*8192 + (d1b+i)*128 + vb + 4] =
        make_float4(bacc[i][4],bacc[i][5],bacc[i][6],bacc[i][7]);
    }
  }

  // ---- transposed bf16 outputs for chunkC: UvT[v][t], WnTb[d][t]
  {
    #pragma unroll
    for (int i = 0; i < 32; ++i) {
      int v = w*32 + i;
      UvT[(size_t)blk*8192 + v*64 + l] = f2bu(Xv[l][v]);
    }
    #pragma unroll
    for (int i = 0; i < 16; ++i) {
      int d = w*16 + i;
      WnTb[(size_t)blk*4096 + d*64 + l] = f2bu(-Xw[l][d]);
    }
  }
}

// Phase B: h_{c+1} = D_c h_c + b_c ; 128 blocks (bh x 8 vgroups of 16)
__global__ __launch_bounds__(256) void chunkB2_k(const float* __restrict__ Dbuf,
   const float* __restrict__ Bvec, const float* __restrict__ init,
   unsigned short* __restrict__ HcT)
{
  const int blk = blockIdx.x;
  const int bh = blk >> 3, grp = blk & 7;
  const int v0 = grp*16;
  const int tid = threadIdx.x;
  const int v = tid & 15;
  const int d1b = (tid >> 4) * 4;
  __shared__ float DT[64][68];
  __shared__ float bsh[64][17];
  __shared__ float hsh[64][17];

  float hreg[4];
  #pragma unroll
  for (int j = 0; j < 4; ++j) {
    hreg[j] = init[((size_t)bh*64 + d1b + j)*128 + v0 + v];
    hsh[d1b + j][v] = hreg[j];
  }
  float Dreg[16], breg[4];
  {
    const float* Dp = Dbuf + (size_t)(bh*16)*4096;
    const float* bp = Bvec + (size_t)(bh*16)*8192;
    #pragma unroll
    for (int i = 0; i < 16; ++i) Dreg[i] = Dp[tid + i*256];
    #pragma unroll
    for (int i = 0; i < 4; ++i)  breg[i] = bp[(size_t)((tid>>4) + i*16)*128 + v0 + v];
  }
  #pragma unroll
  for (int i = 0; i < 16; ++i) {
    int cell = tid + i*256; DT[cell & 63][cell >> 6] = Dreg[i];
  }
  #pragma unroll
  for (int i = 0; i < 4; ++i) bsh[(tid>>4) + i*16][v] = breg[i];
  __syncthreads();

  for (int c = 0; c < 16; ++c) {
    if (c < 15) {
      const float* Dn = Dbuf + (size_t)(bh*16 + c + 1)*4096;
      const float* bn = Bvec + (size_t)(bh*16 + c + 1)*8192;
      #pragma unroll
      for (int i = 0; i < 16; ++i) Dreg[i] = Dn[tid + i*256];
      #pragma unroll
      for (int i = 0; i < 4; ++i)  breg[i] = bn[(size_t)((tid>>4) + i*16)*128 + v0 + v];
    }
    #pragma unroll
    for (int j = 0; j < 4; ++j)
      HcT[(size_t)(bh*16 + c)*8192 + (size_t)(v0+v)*64 + d1b + j] = f2bu(hreg[j]);
    float nh[4];
    #pragma unroll
    for (int j = 0; j < 4; ++j) nh[j] = bsh[d1b + j][v];
    #pragma unroll 8
    for (int d2 = 0; d2 < 64; ++d2) {
      float hv = hsh[d2][v];
      float4 dv = *(const float4*)&DT[d2][d1b];
      nh[0] = fmaf(dv.x, hv, nh[0]);
      nh[1] = fmaf(dv.y, hv, nh[1]);
      nh[2] = fmaf(dv.z, hv, nh[2]);
      nh[3] = fmaf(dv.w, hv, nh[3]);
    }
    __syncthreads();
    #pragma unroll
    for (int j = 0; j < 4; ++j) { hreg[j] = nh[j]; hsh[d1b + j][v] = nh[j]; }
    if (c < 15) {
      #pragma unroll
      for (int i = 0; i < 16; ++i) {
        int cell = tid + i*256; DT[cell & 63][cell >> 6] = Dreg[i];
      }
      #pragma unroll
      for (int i = 0; i < 4; ++i) bsh[(tid>>4) + i*16][v] = breg[i];
    }
    __syncthreads();
  }
}

// Phase C (MFMA): S = decayed-masked QK^T; Qt = E.Q - S Wt; o = Qt h + S U
__global__ __launch_bounds__(256) void chunkC_k(
   const unsigned short* __restrict__ qnb, const unsigned short* __restrict__ knb,
   const unsigned short* __restrict__ UvT, const unsigned short* __restrict__ WnTb,
   const float* __restrict__ Gcbuf, const unsigned short* __restrict__ HcT,
   float* __restrict__ oattn)
{
  const int blk = blockIdx.x; const int bh = blk >> 4, c = blk & 15;
  const int b = bh >> 3, h = bh & 7;
  const int row0 = b*SEQ + c*64;
  const int tid = threadIdx.x;
  const int w = tid >> 6, l = tid & 63;
  const int fr = l & 15, fq = l >> 4;

  __shared__ unsigned short Qs[64*72];
  __shared__ unsigned short Ks[64*72];
  __shared__ unsigned short Ws[64*72];
  __shared__ unsigned short hT[128*72];
  __shared__ unsigned short UT[128*72];
  __shared__ unsigned short Ss[64*72];
  __shared__ float Gsh[64], Esh[64];

  #pragma unroll
  for (int j = 0; j < 2; ++j) {
    int lin = tid + j*256; int t = lin >> 3, dq = (lin & 7)*8;
    *(uint4*)&Qs[t*72+dq] = *(const uint4*)&qnb[(size_t)(row0+t)*TKD + h*64 + dq];
    *(uint4*)&Ks[t*72+dq] = *(const uint4*)&knb[(size_t)(row0+t)*TKD + h*64 + dq];
    *(uint4*)&Ws[t*72+dq] = *(const uint4*)&WnTb[(size_t)blk*4096 + t*64 + dq];
  }
  #pragma unroll
  for (int j = 0; j < 4; ++j) {
    int lin = tid + j*256; int v = lin >> 3, dq = (lin & 7)*8;
    *(uint4*)&hT[v*72+dq] = *(const uint4*)&HcT[(size_t)blk*8192 + (size_t)v*64 + dq];
    *(uint4*)&UT[v*72+dq] = *(const uint4*)&UvT[(size_t)blk*8192 + (size_t)v*64 + dq];
  }
  if (tid < 64) { float g = Gcbuf[(size_t)blk*64 + tid]; Gsh[tid] = g; Esh[tid] = expf(g); }
  __syncthreads();

  f32x4 accS[4];
  #pragma unroll
  for (int n = 0; n < 4; ++n) accS[n] = (f32x4){0.f,0.f,0.f,0.f};
  #pragma unroll
  for (int k0 = 0; k0 < 2; ++k0) {
    bf16x8 a = *(const bf16x8*)&Qs[(w*16+fr)*72 + k0*32 + fq*8];
    #pragma unroll
    for (int n = 0; n < 4; ++n) {
      bf16x8 bb = *(const bf16x8*)&Ks[(n*16+fr)*72 + k0*32 + fq*8];
      accS[n] = __builtin_amdgcn_mfma_f32_16x16x32_bf16(a, bb, accS[n], 0, 0, 0);
    }
  }
  #pragma unroll
  for (int n = 0; n < 4; ++n)
    #pragma unroll
    for (int r = 0; r < 4; ++r) {
      int t = w*16 + fq*4 + r, s = n*16 + fr;
      float val = (s <= t) ? expf(Gsh[t]-Gsh[s]) * accS[n][r] : 0.f;
      Ss[t*72 + s] = f2bu(val);
    }

  f32x4 accQ[4];
  #pragma unroll
  for (int n = 0; n < 4; ++n) {
    #pragma unroll
    for (int r = 0; r < 4; ++r) {
      int t = w*16 + fq*4 + r, d = n*16 + fr;
      accQ[n][r] = Esh[t] * b2f(Qs[t*72 + d]);
    }
    #pragma unroll
    for (int k0 = 0; k0 < 2; ++k0) {
      bf16x8 a = *(const bf16x8*)&Ss[(w*16+fr)*72 + k0*32 + fq*8];
      bf16x8 bb = *(const bf16x8*)&Ws[(n*16+fr)*72 + k0*32 + fq*8];
      accQ[n] = __builtin_amdgcn_mfma_f32_16x16x32_bf16(a, bb, accQ[n], 0, 0, 0);
    }
  }
  __syncthreads();

  #pragma unroll
  for (int n = 0; n < 4; ++n)
    #pragma unroll
    for (int r = 0; r < 4; ++r) {
      int t = w*16 + fq*4 + r, d = n*16 + fr;
      Ks[t*72 + d] = f2bu(accQ[n][r]);
    }

  #pragma unroll
  for (int n = 0; n < 8; ++n) {
    f32x4 acc = (f32x4){0.f,0.f,0.f,0.f};
    #pragma unroll
    for (int k0 = 0; k0 < 2; ++k0) {
      bf16x8 a1 = *(const bf16x8*)&Ks[(w*16+fr)*72 + k0*32 + fq*8];
      bf16x8 b1 = *(const bf16x8*)&hT[(n*16+fr)*72 + k0*32 + fq*8];
      acc = __builtin_amdgcn_mfma_f32_16x16x32_bf16(a1, b1, acc, 0, 0, 0);
      bf16x8 a2 = *(const bf16x8*)&Ss[(w*16+fr)*72 + k0*32 + fq*8];
      bf16x8 b2v = *(const bf16x8*)&UT[(n*16+fr)*72 + k0*32 + fq*8];
      acc = __builtin_amdgcn_mfma_f32_16x16x32_bf16(a2, b2v, acc, 0, 0, 0);
    }
    #pragma unroll
    for (int r = 0; r < 4; ++r) {
      int t = w*16 + fq*4 + r, v = n*16 + fr;
      oattn[(size_t)(row0+t)*TVD + h*128 + v] = acc[r];
    }
  }
}

// ---------------- gated RMSNorm -> bf16 ------------------------------------
__global__ __launch_bounds__(256) void norm_k(const float* __restrict__ oattn,
   const float* __restrict__ qkvabz, const float* __restrict__ onw,
   __hip_bfloat16* __restrict__ ofin)
{
  int gid = blockIdx.x*4 + (threadIdx.x >> 6);
  int lane = threadIdx.x & 63;
  int row = gid >> 3; int h = gid & 7;
  size_t ob = (size_t)row*TVD + h*128;
  float2 ov = *(const float2*)&oattn[ob + lane*2];
  float2 zv = *(const float2*)&qkvabz[(size_t)row*NCOL + 2064 + h*128 + lane*2];
  float g0 = ov.x * siluf(zv.x), g1 = ov.y * siluf(zv.y);
  float ss = g0*g0 + g1*g1;
  #pragma unroll
  for (int o = 32; o; o >>= 1) ss += __shfl_xor(ss, o);
  float r = rsqrtf(ss * (1.f/128.f) + 1e-6f);
  ofin[ob + lane*2]     = __float2bfloat16(g0 * r * onw[lane*2]);
  ofin[ob + lane*2 + 1] = __float2bfloat16(g1 * r * onw[lane*2+1]);
}

extern "C" void kernel_launch(void* const* d_in, const int* in_sizes, int n_in,
                              void* d_out, int out_size, void* d_ws, size_t ws_size,
                              hipStream_t stream) {
  const float* hidden     = (const float*)d_in[0];
  const float* Wqkvabz    = (const float*)d_in[1];
  const float* A_log      = (const float*)d_in[2];
  const float* dt_bias    = (const float*)d_in[3];
  const float* conv_state = (const float*)d_in[4];
  const float* w1         = (const float*)d_in[5];
  const float* w2         = (const float*)d_in[6];
  const float* b2         = (const float*)d_in[7];
  const float* init_state = (const float*)d_in[8];
  const float* o_norm_w   = (const float*)d_in[9];
  const float* W_o        = (const float*)d_in[10];
  float* out = (float*)d_out;

  float* ws = (float*)d_ws;
  float* qkvabz = ws;                                  // 6,324,224 f
  float* kern   = qkvabz + (size_t)6324224;            // 8,388,608 f region
  float* qn     = kern   + (size_t)8388608;            // 1,048,576 (spare)
  float* kn     = qn     + (size_t)1048576;            // 1,048,576
  float* gbuf   = kn     + (size_t)1048576;            // 16,384
  float* bbuf   = gbuf   + (size_t)16384;              // 16,384
  float* vconv  = bbuf   + (size_t)16384;              // 2,097,152
  float* bfpool = vconv  + (size_t)2097152;
  __hip_bfloat16* hidden_bf = (__hip_bfloat16*)bfpool;       // 4,194,304 e
  __hip_bfloat16* w1t   = hidden_bf + (size_t)4194304;
  __hip_bfloat16* w2t   = w1t + (size_t)262144;
  __hip_bfloat16* Wot   = w2t + (size_t)524288;
  __hip_bfloat16* x1sb  = Wot + (size_t)2097152;
  __hip_bfloat16* ofinb = x1sb + (size_t)262144;
  float* Gcbuf  = (float*)(ofinb + (size_t)2097152);         // 16,384 f
  // aliases inside the kern region:
  __hip_bfloat16* Wqkvt  = (__hip_bfloat16*)kern;            // [3200][2048] bf16
  __hip_bfloat16* kernbf = (__hip_bfloat16*)kern;            // 8,388,608 u16
  float* oattn  = kern;                                      // [0, 2M)
  float* Dbuf   = kern + (size_t)2097152;                    // [2M, 3M)
  float* Bvec   = kern + (size_t)3145728;                    // [3M, 5M)
  unsigned short* UvTb  = (unsigned short*)(kern + (size_t)5242880);  // [5M, 6M)
  unsigned short* WnTbb = (unsigned short*)(kern + (size_t)6291456);  // [6M, 6.5M)
  unsigned short* qnb   = (unsigned short*)(kern + (size_t)6815744);  // [6.5M, 7M)
  unsigned short* knb   = (unsigned short*)(kern + (size_t)7340032);  // [7M, 7.5M)
  unsigned short* HcTb  = (unsigned short*)vconv;            // vconv dead after chunkA

  dim3 blk(256);
  cast_k<<<4096, blk, 0, stream>>>(hidden, (unsigned short*)hidden_bf, 1048576);
  tcast_k<<<dim3(100,64), blk, 0, stream>>>(Wqkvabz, Wqkvt, 2048, 3088, 3200);
  tcast_k<<<dim3(4,64),   blk, 0, stream>>>(w1,  w1t, 2048, 128, 128);
  tcast_k<<<dim3(128,4),  blk, 0, stream>>>(w2,  w2t, 128, 4096, 4096);
  tcast_k<<<dim3(64,32),  blk, 0, stream>>>(W_o, Wot, 1024, 2048, 2048);
  mgemm_k<0><<<dim3(25,16), blk, 0, stream>>>(hidden_bf, Wqkvt, nullptr, qkvabz, nullptr, 2048, 3088, 2048);
  mgemm_k<1><<<dim3(1,16),  blk, 0, stream>>>(hidden_bf, w1t, nullptr, nullptr, x1sb, 2048, 128, 2048);
  mgemm_k<2><<<dim3(32,16), blk, 0, stream>>>(x1sb, w2t, b2, nullptr, kernbf, 2048, 4096, 128);
  actv_k<<<4096, blk, 0, stream>>>(qkvabz, A_log, dt_bias, kn, qnb, knb, gbuf, bbuf);
  conv_k<<<8192, blk, 0, stream>>>(qkvabz, kernbf, conv_state, vconv);
  chunkA_k<<<256, blk, 0, stream>>>(kn, knb, vconv, gbuf, bbuf, Gcbuf, Dbuf, Bvec, UvTb, WnTbb);
  chunkB2_k<<<128, blk, 0, stream>>>(Dbuf, Bvec, init_state, HcTb);
  chunkC_k<<<256, blk, 0, stream>>>(qnb, knb, UvTb, WnTbb, Gcbuf, HcTb, oattn);
  norm_k<<<4096, blk, 0, stream>>>(oattn, qkvabz, o_norm_w, ofinb);
  mgemm_k<0><<<dim3(16,16), blk, 0, stream>>>(ofinb, Wot, nullptr, out, nullptr, 2048, 2048, 1024);
}

// Round 7
// 196.014 us; speedup vs baseline: 9.2183x; 1.2777x over previous
//
#include <hip/hip_runtime.h>
#include <hip/hip_bf16.h>
#include <math.h>
#include <stdint.h>

#define BATCH 2
#define SEQ 1024
#define HIDDIM 2048
#define NH 8
#define DKD 64
#define DVD 128
#define TKD 512
#define TVD 1024
#define NCOL 3088   // TK+TK+TV+H+H+TV
#define KSZ 4
#define NCHK 16

typedef __attribute__((ext_vector_type(8))) short bf16x8;
typedef __attribute__((ext_vector_type(4))) float f32x4;

__device__ __forceinline__ float sigm(float x){ return 1.f/(1.f+expf(-x)); }
__device__ __forceinline__ float siluf(float x){ return x/(1.f+expf(-x)); }
__device__ __forceinline__ float b2f(unsigned short u){
  union { unsigned int i; float f; } x; x.i = ((unsigned int)u) << 16; return x.f;
}
__device__ __forceinline__ unsigned short f2bu(float f){
  __hip_bfloat16 h = __float2bfloat16(f);
  return *(unsigned short*)&h;
}

__device__ __forceinline__ void glds16(const __hip_bfloat16* g, void* l) {
  __builtin_amdgcn_global_load_lds((const __attribute__((address_space(1))) void*)g,
                                   (__attribute__((address_space(3))) void*)l, 16, 0, 0);
}

// ---------------- casts -----------------------------------------------------
__global__ __launch_bounds__(256) void cast_k(const float* __restrict__ in,
    unsigned short* __restrict__ out, int n4)
{
  int i = blockIdx.x*256 + threadIdx.x;
  if (i >= n4) return;
  float4 v = ((const float4*)in)[i];
  ushort4 o;
  o.x = f2bu(v.x); o.y = f2bu(v.y); o.z = f2bu(v.z); o.w = f2bu(v.w);
  ((ushort4*)out)[i] = o;
}

// transpose + cast: in fp32 [R][C] -> out bf16 [C'][R] (c >= C rows -> 0)
__global__ __launch_bounds__(256) void tcast_k(const float* __restrict__ in,
    __hip_bfloat16* __restrict__ out, int R, int C, int Cpad)
{
  __shared__ float tile[32][33];
  const int tx = threadIdx.x & 31, ty = threadIdx.x >> 5;
  const int c = blockIdx.x*32 + tx;
  #pragma unroll
  for (int i = 0; i < 4; ++i) {
    int r = blockIdx.y*32 + ty + i*8;
    tile[ty + i*8][tx] = (c < C) ? in[(size_t)r*C + c] : 0.f;
  }
  __syncthreads();
  #pragma unroll
  for (int i = 0; i < 4; ++i) {
    int orow = blockIdx.x*32 + ty + i*8;
    int ocol = blockIdx.y*32 + tx;
    out[(size_t)orow*R + ocol] = __float2bfloat16(tile[tx][ty + i*8]);
  }
}

// ---------------- bf16 MFMA GEMM, BM=64 x BN=128 tile, 1D grid + XCD swizzle
// C = A[M][K] @ Bt[N][K]^T
// EPI: 0 = fp32 out; 2 = +bias -> bf16; 3 = fused qkvabz+w1 (split epilogue)
template<int EPI>
__global__ __launch_bounds__(256) void mgemm_k(
    const __hip_bfloat16* __restrict__ A,
    const __hip_bfloat16* __restrict__ Bt,
    const float* __restrict__ bias,
    float* __restrict__ Cf, __hip_bfloat16* __restrict__ Cb,
    int M, int N, int K, int nbx)
{
  __shared__ __hip_bfloat16 As[64*32];
  __shared__ __hip_bfloat16 Bs[128*32];
  const int tid = threadIdx.x;
  const int w = tid >> 6, l = tid & 63;
  const int wr = w >> 1, wc = w & 1;
  // bijective XCD-aware swizzle (gridDim.x % 8 == 0 for all launches)
  const int nwg = gridDim.x, q = nwg >> 3;
  const int swz = (blockIdx.x & 7)*q + (blockIdx.x >> 3);
  const int bx = swz % nbx, by = swz / nbx;
  const int row0 = by*64, col0 = bx*128;
  const int fr = l & 15, fq = l >> 4;

  f32x4 acc[2][4];
  #pragma unroll
  for (int m = 0; m < 2; ++m)
    #pragma unroll
    for (int n = 0; n < 4; ++n)
      acc[m][n] = (f32x4){0.f,0.f,0.f,0.f};

  const int ra = w*16 + (l >> 2), ca = (l & 3)*8;   // A-stage coords (1 issue)
  const int e0 = w*512 + l*8;                        // B-stage (2 issues)
  const int rb = e0 >> 5, cb = e0 & 31;

  for (int k0 = 0; k0 < K; k0 += 32) {
    glds16(&A[(size_t)(row0 + ra)*K + k0 + ca],       (char*)As + w*1024);
    glds16(&Bt[(size_t)(col0 + rb)*K + k0 + cb],      (char*)Bs + w*1024);
    glds16(&Bt[(size_t)(col0 + rb + 64)*K + k0 + cb], (char*)Bs + 4096 + w*1024);
    __syncthreads();

    bf16x8 af[2], bfv[4];
    #pragma unroll
    for (int m = 0; m < 2; ++m)
      af[m] = *(const bf16x8*)&As[(wr*32 + m*16 + fr)*32 + fq*8];
    #pragma unroll
    for (int n = 0; n < 4; ++n)
      bfv[n] = *(const bf16x8*)&Bs[(wc*64 + n*16 + fr)*32 + fq*8];
    #pragma unroll
    for (int m = 0; m < 2; ++m)
      #pragma unroll
      for (int n = 0; n < 4; ++n)
        acc[m][n] = __builtin_amdgcn_mfma_f32_16x16x32_bf16(af[m], bfv[n], acc[m][n], 0, 0, 0);
    __syncthreads();
  }

  #pragma unroll
  for (int n = 0; n < 4; ++n) {
    const int ccol = col0 + wc*64 + n*16 + fr;
    #pragma unroll
    for (int m = 0; m < 2; ++m) {
      #pragma unroll
      for (int r = 0; r < 4; ++r) {
        const int crow = row0 + wr*32 + m*16 + fq*4 + r;
        float v = acc[m][n][r];
        if (EPI == 0) {
          Cf[(size_t)crow*N + ccol] = v;
        } else if (EPI == 2) {
          Cb[(size_t)crow*N + ccol] = __float2bfloat16(v + bias[ccol]);
        } else { // EPI == 3: cols <3088 -> qkvabz fp32; cols >=3200 -> silu bf16 x1s
          if (ccol < NCOL)       Cf[(size_t)crow*NCOL + ccol] = v;
          else if (ccol >= 3200) Cb[(size_t)crow*128 + (ccol - 3200)] = __float2bfloat16(siluf(v));
        }
      }
    }
  }
}

// ---------------- silu + l2norm for q,k; g and beta ------------------------
__global__ __launch_bounds__(256) void actv_k(const float* __restrict__ qkvabz,
    const float* __restrict__ A_log, const float* __restrict__ dt_bias,
    float* __restrict__ kn, unsigned short* __restrict__ qnb,
    unsigned short* __restrict__ knb,
    float* __restrict__ g, float* __restrict__ beta)
{
  int gid = blockIdx.x*4 + (threadIdx.x >> 6);
  int lane = threadIdx.x & 63;
  int row = gid >> 3; int h = gid & 7;
  const float* base = qkvabz + (size_t)row * NCOL;
  float qv = base[h*64 + lane];
  float kv = base[TKD + h*64 + lane];
  float sq = siluf(qv), sk = siluf(kv);
  float ssq = sq*sq, ssk = sk*sk;
  #pragma unroll
  for (int o = 32; o; o >>= 1) { ssq += __shfl_xor(ssq, o); ssk += __shfl_xor(ssk, o); }
  float qn_v = sq * rsqrtf(ssq + 1e-6f) * 0.125f;
  float kn_v = sk * rsqrtf(ssk + 1e-6f);
  size_t idx = (size_t)row*TKD + h*64 + lane;
  kn[idx]  = kn_v;
  qnb[idx] = f2bu(qn_v);
  knb[idx] = f2bu(kn_v);
  if (lane == 0) {
    float av = base[2048 + h] + dt_bias[h];
    float sp = fmaxf(av, 0.f) + log1pf(expf(-fabsf(av)));
    g[(size_t)row*NH + h] = -expf(A_log[h]) * sp;
    float bv = base[2056 + h];
    beta[(size_t)row*NH + h] = sigm(bv);
  }
}

// ---------------- dynamic conv (bf16 kernels) -------------------------------
__global__ __launch_bounds__(256) void conv_k(const float* __restrict__ qkvabz,
   const __hip_bfloat16* __restrict__ kern, const float* __restrict__ conv_state,
   float* __restrict__ vconv)
{
  int idx = blockIdx.x*256 + threadIdx.x;
  int c = idx & (TVD-1);
  int bs = idx >> 10;
  int s = bs & (SEQ-1); int b = bs >> 10;
  ushort4 kf = *(const ushort4*)&kern[(size_t)idx * 4];
  float kj[4] = { b2f(kf.x), b2f(kf.y), b2f(kf.z), b2f(kf.w) };
  float acc = 0.f;
  #pragma unroll
  for (int j = 0; j < 4; ++j) {
    int i = s + j;
    float xv = (i < 3) ? conv_state[((size_t)b*TVD + c)*3 + i]
                       : qkvabz[((size_t)(b*SEQ + (i-3)))*NCOL + TKD*2 + c];
    acc = fmaf(xv, kj[j], acc);
  }
  vconv[idx] = siluf(acc);
}

// ============ chunked gated delta rule =====================================
// Phase A: MFMA A-build + register-column trisolve + fp32 D/b
__global__ __launch_bounds__(256) void chunkA_k(const float* __restrict__ kn,
   const unsigned short* __restrict__ knb,
   const float* __restrict__ vconv, const float* __restrict__ gb,
   const float* __restrict__ bb, float* __restrict__ Gcbuf,
   float* __restrict__ Dbuf, float* __restrict__ Bvec,
   unsigned short* __restrict__ UvT, unsigned short* __restrict__ WnTb)
{
  const int blk = blockIdx.x;
  const int bh = blk >> 4, c = blk & 15;
  const int b = bh >> 3, h = bh & 7;
  const int tid = threadIdx.x;
  const int w = tid >> 6, l = tid & 63;
  const int fr = l & 15, fq = l >> 4;
  const int row0 = b*SEQ + c*64;

  __shared__ unsigned short Kb[64*72];
  __shared__ float Xv[64][132];
  __shared__ float Xw[64][68];
  __shared__ float AK[64][68];
  __shared__ float Gsh[64], Bsh[64];

  #pragma unroll
  for (int j = 0; j < 2; ++j) {
    int lin = tid + j*256; int t = lin >> 3, dq = (lin & 7)*8;
    *(uint4*)&Kb[t*72+dq] = *(const uint4*)&knb[(size_t)(row0+t)*TKD + h*64 + dq];
  }
  #pragma unroll
  for (int i = 0; i < 8; ++i) {
    int lin = tid + i*256; int t = lin >> 5, v4 = (lin & 31)*4;
    float4 vv = *(const float4*)&vconv[(size_t)(row0+t)*TVD + h*128 + v4];
    Xv[t][v4]=vv.x; Xv[t][v4+1]=vv.y; Xv[t][v4+2]=vv.z; Xv[t][v4+3]=vv.w;
  }
  if (tid < 64) {
    float gv = gb[(size_t)(row0+tid)*NH + h];
    #pragma unroll
    for (int o = 1; o < 64; o <<= 1) {
      float oth = __shfl_up(gv, o);
      if (tid >= o) gv += oth;
    }
    Gsh[tid] = gv;
    Bsh[tid] = bb[(size_t)(row0+tid)*NH + h];
    Gcbuf[(size_t)blk*64 + tid] = gv;
  }
  __syncthreads();

  {
    f32x4 accS[4];
    #pragma unroll
    for (int n = 0; n < 4; ++n) accS[n] = (f32x4){0.f,0.f,0.f,0.f};
    #pragma unroll
    for (int k0 = 0; k0 < 2; ++k0) {
      bf16x8 a = *(const bf16x8*)&Kb[(w*16+fr)*72 + k0*32 + fq*8];
      #pragma unroll
      for (int n = 0; n < 4; ++n) {
        bf16x8 bb2 = *(const bf16x8*)&Kb[(n*16+fr)*72 + k0*32 + fq*8];
        accS[n] = __builtin_amdgcn_mfma_f32_16x16x32_bf16(a, bb2, accS[n], 0, 0, 0);
      }
    }
    #pragma unroll
    for (int n = 0; n < 4; ++n)
      #pragma unroll
      for (int r = 0; r < 4; ++r) {
        int t = w*16 + fq*4 + r, s = n*16 + fr;
        AK[t][s] = (s < t) ? Bsh[t]*expf(Gsh[t]-Gsh[s])*accS[n][r] : 0.f;
      }
  }
  #pragma unroll
  for (int i = 0; i < 4; ++i) {
    int lin = tid + i*256; int t = lin >> 4, d4 = (lin & 15)*4;
    float4 kv = *(const float4*)&kn[(size_t)(row0+t)*TKD + h*64 + d4];
    float f = Bsh[t]*expf(Gsh[t]);
    Xw[t][d4+0]=f*kv.x; Xw[t][d4+1]=f*kv.y; Xw[t][d4+2]=f*kv.z; Xw[t][d4+3]=f*kv.w;
  }
  __syncthreads();

  if (tid < 192) {
    float x[64];
    if (tid < 128) {
      #pragma unroll
      for (int t = 0; t < 64; ++t) x[t] = Bsh[t]*Xv[t][tid];
    } else {
      #pragma unroll
      for (int t = 0; t < 64; ++t) x[t] = Xw[t][tid-128];
    }
    #pragma unroll
    for (int t = 1; t < 64; ++t) {
      float a0=0.f, a1=0.f, a2=0.f, a3=0.f;
      #pragma unroll
      for (int s4 = 0; s4 < (t+3)/4; ++s4) {
        float4 av = *(const float4*)&AK[t][s4*4];
        a0 = fmaf(av.x, x[s4*4+0], a0);
        a1 = fmaf(av.y, x[s4*4+1], a1);
        a2 = fmaf(av.z, x[s4*4+2], a2);
        a3 = fmaf(av.w, x[s4*4+3], a3);
      }
      x[t] -= (a0+a1)+(a2+a3);
    }
    if (tid < 128) {
      #pragma unroll
      for (int t = 0; t < 64; ++t) Xv[t][tid] = x[t];
    } else {
      #pragma unroll
      for (int t = 0; t < 64; ++t) Xw[t][tid-128] = x[t];
    }
  }
  __syncthreads();

  const float Gtot = Gsh[63];
  #pragma unroll
  for (int i = 0; i < 4; ++i) {
    int lin = tid + i*256; int t = lin >> 4, d4 = (lin & 15)*4;
    float4 kv = *(const float4*)&kn[(size_t)(row0+t)*TKD + h*64 + d4];
    float f = expf(Gtot - Gsh[t]);
    AK[t][d4+0]=f*kv.x; AK[t][d4+1]=f*kv.y; AK[t][d4+2]=f*kv.z; AK[t][d4+3]=f*kv.w;
  }
  __syncthreads();

  {
    const int d1b = (tid >> 4)*4, d2b = (tid & 15)*4;
    float dacc[4][4] = {};
    #pragma unroll 8
    for (int t = 0; t < 64; ++t) {
      float4 kw = *(const float4*)&AK[t][d1b];
      float4 wv = *(const float4*)&Xw[t][d2b];
      float kwa[4] = {kw.x,kw.y,kw.z,kw.w};
      float wva[4] = {wv.x,wv.y,wv.z,wv.w};
      #pragma unroll
      for (int i = 0; i < 4; ++i)
        #pragma unroll
        for (int j = 0; j < 4; ++j)
          dacc[i][j] = fmaf(kwa[i], wva[j], dacc[i][j]);
    }
    const float eG = expf(Gtot);
    #pragma unroll
    for (int i = 0; i < 4; ++i) {
      float vals[4];
      #pragma unroll
      for (int j = 0; j < 4; ++j) {
        float v = -dacc[i][j];
        if (d1b + i == d2b + j) v += eG;
        vals[j] = v;
      }
      *(float4*)&Dbuf[(size_t)blk*4096 + (d1b+i)*64 + d2b] =
        make_float4(vals[0],vals[1],vals[2],vals[3]);
    }
  }
  {
    const int d1b = (tid >> 4)*4, vb = (tid & 15)*8;
    float bacc[4][8] = {};
    #pragma unroll 4
    for (int t = 0; t < 64; ++t) {
      float4 kw = *(const float4*)&AK[t][d1b];
      float4 u0 = *(const float4*)&Xv[t][vb];
      float4 u1 = *(const float4*)&Xv[t][vb+4];
      float kwa[4] = {kw.x,kw.y,kw.z,kw.w};
      float ua[8] = {u0.x,u0.y,u0.z,u0.w,u1.x,u1.y,u1.z,u1.w};
      #pragma unroll
      for (int i = 0; i < 4; ++i)
        #pragma unroll
        for (int j = 0; j < 8; ++j)
          bacc[i][j] = fmaf(kwa[i], ua[j], bacc[i][j]);
    }
    #pragma unroll
    for (int i = 0; i < 4; ++i) {
      *(float4*)&Bvec[(size_t)blk*8192 + (d1b+i)*128 + vb] =
        make_float4(bacc[i][0],bacc[i][1],bacc[i][2],bacc[i][3]);
      *(float4*)&Bvec[(size_t)blk*8192 + (d1b+i)*128 + vb + 4] =
        make_float4(bacc[i][4],bacc[i][5],bacc[i][6],bacc[i][7]);
    }
  }

  {
    #pragma unroll
    for (int i = 0; i < 32; ++i) {
      int v = w*32 + i;
      UvT[(size_t)blk*8192 + v*64 + l] = f2bu(Xv[l][v]);
    }
    #pragma unroll
    for (int i = 0; i < 16; ++i) {
      int d = w*16 + i;
      WnTb[(size_t)blk*4096 + d*64 + l] = f2bu(-Xw[l][d]);
    }
  }
}

// Phase B: h_{c+1} = D_c h_c + b_c ; 128 blocks (bh x 8 vgroups of 16)
__global__ __launch_bounds__(256) void chunkB2_k(const float* __restrict__ Dbuf,
   const float* __restrict__ Bvec, const float* __restrict__ init,
   unsigned short* __restrict__ HcT)
{
  const int blk = blockIdx.x;
  const int bh = blk >> 3, grp = blk & 7;
  const int v0 = grp*16;
  const int tid = threadIdx.x;
  const int v = tid & 15;
  const int d1b = (tid >> 4) * 4;
  __shared__ float DT[64][68];
  __shared__ float bsh[64][17];
  __shared__ float hsh[64][17];

  float hreg[4];
  #pragma unroll
  for (int j = 0; j < 4; ++j) {
    hreg[j] = init[((size_t)bh*64 + d1b + j)*128 + v0 + v];
    hsh[d1b + j][v] = hreg[j];
  }
  float Dreg[16], breg[4];
  {
    const float* Dp = Dbuf + (size_t)(bh*16)*4096;
    const float* bp = Bvec + (size_t)(bh*16)*8192;
    #pragma unroll
    for (int i = 0; i < 16; ++i) Dreg[i] = Dp[tid + i*256];
    #pragma unroll
    for (int i = 0; i < 4; ++i)  breg[i] = bp[(size_t)((tid>>4) + i*16)*128 + v0 + v];
  }
  #pragma unroll
  for (int i = 0; i < 16; ++i) {
    int cell = tid + i*256; DT[cell & 63][cell >> 6] = Dreg[i];
  }
  #pragma unroll
  for (int i = 0; i < 4; ++i) bsh[(tid>>4) + i*16][v] = breg[i];
  __syncthreads();

  for (int c = 0; c < 16; ++c) {
    if (c < 15) {
      const float* Dn = Dbuf + (size_t)(bh*16 + c + 1)*4096;
      const float* bn = Bvec + (size_t)(bh*16 + c + 1)*8192;
      #pragma unroll
      for (int i = 0; i < 16; ++i) Dreg[i] = Dn[tid + i*256];
      #pragma unroll
      for (int i = 0; i < 4; ++i)  breg[i] = bn[(size_t)((tid>>4) + i*16)*128 + v0 + v];
    }
    #pragma unroll
    for (int j = 0; j < 4; ++j)
      HcT[(size_t)(bh*16 + c)*8192 + (size_t)(v0+v)*64 + d1b + j] = f2bu(hreg[j]);
    float nh[4];
    #pragma unroll
    for (int j = 0; j < 4; ++j) nh[j] = bsh[d1b + j][v];
    #pragma unroll 8
    for (int d2 = 0; d2 < 64; ++d2) {
      float hv = hsh[d2][v];
      float4 dv = *(const float4*)&DT[d2][d1b];
      nh[0] = fmaf(dv.x, hv, nh[0]);
      nh[1] = fmaf(dv.y, hv, nh[1]);
      nh[2] = fmaf(dv.z, hv, nh[2]);
      nh[3] = fmaf(dv.w, hv, nh[3]);
    }
    __syncthreads();
    #pragma unroll
    for (int j = 0; j < 4; ++j) { hreg[j] = nh[j]; hsh[d1b + j][v] = nh[j]; }
    if (c < 15) {
      #pragma unroll
      for (int i = 0; i < 16; ++i) {
        int cell = tid + i*256; DT[cell & 63][cell >> 6] = Dreg[i];
      }
      #pragma unroll
      for (int i = 0; i < 4; ++i) bsh[(tid>>4) + i*16][v] = breg[i];
    }
    __syncthreads();
  }
}

// Phase C (MFMA): S = decayed-masked QK^T; Qt = E.Q - S Wt; o = Qt h + S U
__global__ __launch_bounds__(256) void chunkC_k(
   const unsigned short* __restrict__ qnb, const unsigned short* __restrict__ knb,
   const unsigned short* __restrict__ UvT, const unsigned short* __restrict__ WnTb,
   const float* __restrict__ Gcbuf, const unsigned short* __restrict__ HcT,
   float* __restrict__ oattn)
{
  const int blk = blockIdx.x; const int bh = blk >> 4, c = blk & 15;
  const int b = bh >> 3, h = bh & 7;
  const int row0 = b*SEQ + c*64;
  const int tid = threadIdx.x;
  const int w = tid >> 6, l = tid & 63;
  const int fr = l & 15, fq = l >> 4;

  __shared__ unsigned short Qs[64*72];
  __shared__ unsigned short Ks[64*72];
  __shared__ unsigned short Ws[64*72];
  __shared__ unsigned short hT[128*72];
  __shared__ unsigned short UT[128*72];
  __shared__ unsigned short Ss[64*72];
  __shared__ float Gsh[64], Esh[64];

  #pragma unroll
  for (int j = 0; j < 2; ++j) {
    int lin = tid + j*256; int t = lin >> 3, dq = (lin & 7)*8;
    *(uint4*)&Qs[t*72+dq] = *(const uint4*)&qnb[(size_t)(row0+t)*TKD + h*64 + dq];
    *(uint4*)&Ks[t*72+dq] = *(const uint4*)&knb[(size_t)(row0+t)*TKD + h*64 + dq];
    *(uint4*)&Ws[t*72+dq] = *(const uint4*)&WnTb[(size_t)blk*4096 + t*64 + dq];
  }
  #pragma unroll
  for (int j = 0; j < 4; ++j) {
    int lin = tid + j*256; int v = lin >> 3, dq = (lin & 7)*8;
    *(uint4*)&hT[v*72+dq] = *(const uint4*)&HcT[(size_t)blk*8192 + (size_t)v*64 + dq];
    *(uint4*)&UT[v*72+dq] = *(const uint4*)&UvT[(size_t)blk*8192 + (size_t)v*64 + dq];
  }
  if (tid < 64) { float g = Gcbuf[(size_t)blk*64 + tid]; Gsh[tid] = g; Esh[tid] = expf(g); }
  __syncthreads();

  f32x4 accS[4];
  #pragma unroll
  for (int n = 0; n < 4; ++n) accS[n] = (f32x4){0.f,0.f,0.f,0.f};
  #pragma unroll
  for (int k0 = 0; k0 < 2; ++k0) {
    bf16x8 a = *(const bf16x8*)&Qs[(w*16+fr)*72 + k0*32 + fq*8];
    #pragma unroll
    for (int n = 0; n < 4; ++n) {
      bf16x8 bb = *(const bf16x8*)&Ks[(n*16+fr)*72 + k0*32 + fq*8];
      accS[n] = __builtin_amdgcn_mfma_f32_16x16x32_bf16(a, bb, accS[n], 0, 0, 0);
    }
  }
  #pragma unroll
  for (int n = 0; n < 4; ++n)
    #pragma unroll
    for (int r = 0; r < 4; ++r) {
      int t = w*16 + fq*4 + r, s = n*16 + fr;
      float val = (s <= t) ? expf(Gsh[t]-Gsh[s]) * accS[n][r] : 0.f;
      Ss[t*72 + s] = f2bu(val);
    }

  f32x4 accQ[4];
  #pragma unroll
  for (int n = 0; n < 4; ++n) {
    #pragma unroll
    for (int r = 0; r < 4; ++r) {
      int t = w*16 + fq*4 + r, d = n*16 + fr;
      accQ[n][r] = Esh[t] * b2f(Qs[t*72 + d]);
    }
    #pragma unroll
    for (int k0 = 0; k0 < 2; ++k0) {
      bf16x8 a = *(const bf16x8*)&Ss[(w*16+fr)*72 + k0*32 + fq*8];
      bf16x8 bb = *(const bf16x8*)&Ws[(n*16+fr)*72 + k0*32 + fq*8];
      accQ[n] = __builtin_amdgcn_mfma_f32_16x16x32_bf16(a, bb, accQ[n], 0, 0, 0);
    }
  }
  __syncthreads();

  #pragma unroll
  for (int n = 0; n < 4; ++n)
    #pragma unroll
    for (int r = 0; r < 4; ++r) {
      int t = w*16 + fq*4 + r, d = n*16 + fr;
      Ks[t*72 + d] = f2bu(accQ[n][r]);
    }

  #pragma unroll
  for (int n = 0; n < 8; ++n) {
    f32x4 acc = (f32x4){0.f,0.f,0.f,0.f};
    #pragma unroll
    for (int k0 = 0; k0 < 2; ++k0) {
      bf16x8 a1 = *(const bf16x8*)&Ks[(w*16+fr)*72 + k0*32 + fq*8];
      bf16x8 b1 = *(const bf16x8*)&hT[(n*16+fr)*72 + k0*32 + fq*8];
      acc = __builtin_amdgcn_mfma_f32_16x16x32_bf16(a1, b1, acc, 0, 0, 0);
      bf16x8 a2 = *(const bf16x8*)&Ss[(w*16+fr)*72 + k0*32 + fq*8];
      bf16x8 b2v = *(const bf16x8*)&UT[(n*16+fr)*72 + k0*32 + fq*8];
      acc = __builtin_amdgcn_mfma_f32_16x16x32_bf16(a2, b2v, acc, 0, 0, 0);
    }
    #pragma unroll
    for (int r = 0; r < 4; ++r) {
      int t = w*16 + fq*4 + r, v = n*16 + fr;
      oattn[(size_t)(row0+t)*TVD + h*128 + v] = acc[r];
    }
  }
}

// ---------------- gated RMSNorm -> bf16 ------------------------------------
__global__ __launch_bounds__(256) void norm_k(const float* __restrict__ oattn,
   const float* __restrict__ qkvabz, const float* __restrict__ onw,
   __hip_bfloat16* __restrict__ ofin)
{
  int gid = blockIdx.x*4 + (threadIdx.x >> 6);
  int lane = threadIdx.x & 63;
  int row = gid >> 3; int h = gid & 7;
  size_t ob = (size_t)row*TVD + h*128;
  float2 ov = *(const float2*)&oattn[ob + lane*2];
  float2 zv = *(const float2*)&qkvabz[(size_t)row*NCOL + 2064 + h*128 + lane*2];
  float g0 = ov.x * siluf(zv.x), g1 = ov.y * siluf(zv.y);
  float ss = g0*g0 + g1*g1;
  #pragma unroll
  for (int o = 32; o; o >>= 1) ss += __shfl_xor(ss, o);
  float r = rsqrtf(ss * (1.f/128.f) + 1e-6f);
  ofin[ob + lane*2]     = __float2bfloat16(g0 * r * onw[lane*2]);
  ofin[ob + lane*2 + 1] = __float2bfloat16(g1 * r * onw[lane*2+1]);
}

extern "C" void kernel_launch(void* const* d_in, const int* in_sizes, int n_in,
                              void* d_out, int out_size, void* d_ws, size_t ws_size,
                              hipStream_t stream) {
  const float* hidden     = (const float*)d_in[0];
  const float* Wqkvabz    = (const float*)d_in[1];
  const float* A_log      = (const float*)d_in[2];
  const float* dt_bias    = (const float*)d_in[3];
  const float* conv_state = (const float*)d_in[4];
  const float* w1         = (const float*)d_in[5];
  const float* w2         = (const float*)d_in[6];
  const float* b2         = (const float*)d_in[7];
  const float* init_state = (const float*)d_in[8];
  const float* o_norm_w   = (const float*)d_in[9];
  const float* W_o        = (const float*)d_in[10];
  float* out = (float*)d_out;

  float* ws = (float*)d_ws;
  float* qkvabz = ws;                                  // 6,324,224 f
  float* kern   = qkvabz + (size_t)6324224;            // 8,388,608 f region
  float* qn     = kern   + (size_t)8388608;            // spare
  float* kn     = qn     + (size_t)1048576;            // 1,048,576
  float* gbuf   = kn     + (size_t)1048576;            // 16,384
  float* bbuf   = gbuf   + (size_t)16384;              // 16,384
  float* vconv  = bbuf   + (size_t)16384;              // 2,097,152
  float* bfpool = vconv  + (size_t)2097152;
  __hip_bfloat16* hidden_bf = (__hip_bfloat16*)bfpool;       // 4,194,304 e
  __hip_bfloat16* w1t   = hidden_bf + (size_t)4194304;       // (spare)
  __hip_bfloat16* w2t   = w1t + (size_t)262144;
  __hip_bfloat16* Wot   = w2t + (size_t)524288;
  __hip_bfloat16* x1sb  = Wot + (size_t)2097152;
  __hip_bfloat16* ofinb = x1sb + (size_t)262144;
  float* Gcbuf  = (float*)(ofinb + (size_t)2097152);         // 16,384 f
  // aliases inside the kern region:
  __hip_bfloat16* Wcat   = (__hip_bfloat16*)kern;            // [3328][2048] bf16 (13.6 MB)
  __hip_bfloat16* kernbf = (__hip_bfloat16*)kern;            // 8,388,608 u16 (w2 out)
  float* oattn  = kern;                                      // [0, 2M)
  float* Dbuf   = kern + (size_t)2097152;                    // [2M, 3M)
  float* Bvec   = kern + (size_t)3145728;                    // [3M, 5M)
  unsigned short* UvTb  = (unsigned short*)(kern + (size_t)5242880);  // [5M, 6M)
  unsigned short* WnTbb = (unsigned short*)(kern + (size_t)6291456);  // [6M, 6.5M)
  unsigned short* qnb   = (unsigned short*)(kern + (size_t)6815744);  // [6.5M, 7M)
  unsigned short* knb   = (unsigned short*)(kern + (size_t)7340032);  // [7M, 7.5M)
  unsigned short* HcTb  = (unsigned short*)vconv;            // vconv dead after chunkA

  dim3 blk(256);
  cast_k<<<4096, blk, 0, stream>>>(hidden, (unsigned short*)hidden_bf, 1048576);
  // Wcat rows 0..3199 (3088 real + 112 zero), rows 3200..3327 = w1^T
  tcast_k<<<dim3(100,64), blk, 0, stream>>>(Wqkvabz, Wcat, 2048, 3088, 3200);
  tcast_k<<<dim3(4,64),   blk, 0, stream>>>(w1, Wcat + (size_t)3200*2048, 2048, 128, 128);
  tcast_k<<<dim3(128,4),  blk, 0, stream>>>(w2,  w2t, 128, 4096, 4096);
  tcast_k<<<dim3(64,32),  blk, 0, stream>>>(W_o, Wot, 1024, 2048, 2048);
  // fused qkvabz + w1 GEMM: M=2048, N=3328, K=2048 -> grid 26x32 = 832
  mgemm_k<3><<<dim3(832),  blk, 0, stream>>>(hidden_bf, Wcat, nullptr, qkvabz, x1sb, 2048, 3328, 2048, 26);
  // w2 GEMM: M=2048, N=4096, K=128 -> grid 32x32 = 1024
  mgemm_k<2><<<dim3(1024), blk, 0, stream>>>(x1sb, w2t, b2, nullptr, kernbf, 2048, 4096, 128, 32);
  actv_k<<<4096, blk, 0, stream>>>(qkvabz, A_log, dt_bias, kn, qnb, knb, gbuf, bbuf);
  conv_k<<<8192, blk, 0, stream>>>(qkvabz, kernbf, conv_state, vconv);
  chunkA_k<<<256, blk, 0, stream>>>(kn, knb, vconv, gbuf, bbuf, Gcbuf, Dbuf, Bvec, UvTb, WnTbb);
  chunkB2_k<<<128, blk, 0, stream>>>(Dbuf, Bvec, init_state, HcTb);
  chunkC_k<<<256, blk, 0, stream>>>(qnb, knb, UvTb, WnTbb, Gcbuf, HcTb, oattn);
  norm_k<<<4096, blk, 0, stream>>>(oattn, qkvabz, o_norm_w, ofinb);
  // out GEMM: M=2048, N=2048, K=1024 -> grid 16x32 = 512
  mgemm_k<0><<<dim3(512),  blk, 0, stream>>>(ofinb, Wot, nullptr, out, nullptr, 2048, 2048, 1024, 16);
}

// Round 8
// 181.724 us; speedup vs baseline: 9.9431x; 1.0786x over previous
//
#include <hip/hip_runtime.h>
#include <hip/hip_bf16.h>
#include <math.h>
#include <stdint.h>

#define BATCH 2
#define SEQ 1024
#define HIDDIM 2048
#define NH 8
#define DKD 64
#define DVD 128
#define TKD 512
#define TVD 1024
#define NCOL 3088   // TK+TK+TV+H+H+TV
#define KSZ 4
#define NCHK 16

typedef __attribute__((ext_vector_type(8))) short bf16x8;
typedef __attribute__((ext_vector_type(4))) float f32x4;

__device__ __forceinline__ float sigm(float x){ return 1.f/(1.f+expf(-x)); }
__device__ __forceinline__ float siluf(float x){ return x/(1.f+expf(-x)); }
__device__ __forceinline__ float b2f(unsigned short u){
  union { unsigned int i; float f; } x; x.i = ((unsigned int)u) << 16; return x.f;
}
__device__ __forceinline__ unsigned short f2bu(float f){
  __hip_bfloat16 h = __float2bfloat16(f);
  return *(unsigned short*)&h;
}

__device__ __forceinline__ void glds16(const __hip_bfloat16* g, void* l) {
  __builtin_amdgcn_global_load_lds((const __attribute__((address_space(1))) void*)g,
                                   (__attribute__((address_space(3))) void*)l, 16, 0, 0);
}

// ---------------- fused prep: 4 transposing casts + hidden cast -------------
__global__ __launch_bounds__(256) void prep_k(
    const float* __restrict__ Wqkvabz, const float* __restrict__ w1,
    const float* __restrict__ w2, const float* __restrict__ W_o,
    const float* __restrict__ hidden,
    __hip_bfloat16* __restrict__ Wcat, __hip_bfloat16* __restrict__ w2t,
    __hip_bfloat16* __restrict__ Wot, unsigned short* __restrict__ hidden_bf)
{
  __shared__ float tile[32][33];
  const int blk = blockIdx.x;
  const float* in; __hip_bfloat16* out; int R, C, bx, by;
  if (blk < 6400)      { in=Wqkvabz; out=Wcat; R=2048; C=3088; bx=blk%100; by=blk/100; }
  else if (blk < 6656) { int t=blk-6400; in=w1;  out=Wcat+(size_t)3200*2048; R=2048; C=128;  bx=t%4;   by=t/4; }
  else if (blk < 7168) { int t=blk-6656; in=w2;  out=w2t; R=128;  C=4096; bx=t%128; by=t/128; }
  else if (blk < 9216) { int t=blk-7168; in=W_o; out=Wot; R=1024; C=2048; bx=t%64;  by=t/64; }
  else {
    int i = (blk - 9216)*256 + threadIdx.x;
    float4 v = ((const float4*)hidden)[i];
    ushort4 o; o.x=f2bu(v.x); o.y=f2bu(v.y); o.z=f2bu(v.z); o.w=f2bu(v.w);
    ((ushort4*)hidden_bf)[i] = o;
    return;
  }
  const int tx = threadIdx.x & 31, ty = threadIdx.x >> 5;
  const int c = bx*32 + tx;
  #pragma unroll
  for (int i = 0; i < 4; ++i) {
    int r = by*32 + ty + i*8;
    tile[ty + i*8][tx] = (c < C) ? in[(size_t)r*C + c] : 0.f;
  }
  __syncthreads();
  #pragma unroll
  for (int i = 0; i < 4; ++i) {
    int orow = bx*32 + ty + i*8;
    int ocol = by*32 + tx;
    out[(size_t)orow*R + ocol] = __float2bfloat16(tile[tx][ty + i*8]);
  }
}

// ---------------- bf16 MFMA GEMM, BM=64 x BN=128, double-buffered LDS -------
// C = A[M][K] @ Bt[N][K]^T ; 1D grid + XCD swizzle
// EPI: 0 = fp32 out; 2 = +bias -> bf16; 3 = fused qkvabz+w1 (split epilogue)
template<int EPI>
__global__ __launch_bounds__(256) void mgemm_k(
    const __hip_bfloat16* __restrict__ A,
    const __hip_bfloat16* __restrict__ Bt,
    const float* __restrict__ bias,
    float* __restrict__ Cf, __hip_bfloat16* __restrict__ Cb,
    int M, int N, int K, int nbx)
{
  __shared__ __hip_bfloat16 As[2][64*32];
  __shared__ __hip_bfloat16 Bs[2][128*32];
  const int tid = threadIdx.x;
  const int w = tid >> 6, l = tid & 63;
  const int wr = w >> 1, wc = w & 1;
  const int nwg = gridDim.x, q = nwg >> 3;
  const int swz = (blockIdx.x & 7)*q + (blockIdx.x >> 3);
  const int bx = swz % nbx, by = swz / nbx;
  const int row0 = by*64, col0 = bx*128;
  const int fr = l & 15, fq = l >> 4;

  f32x4 acc[2][4];
  #pragma unroll
  for (int m = 0; m < 2; ++m)
    #pragma unroll
    for (int n = 0; n < 4; ++n)
      acc[m][n] = (f32x4){0.f,0.f,0.f,0.f};

  const int ra = w*16 + (l >> 2), ca = (l & 3)*8;   // A-stage (1 issue/wave)
  const int e0 = w*512 + l*8;                        // B-stage (2 issues/wave)
  const int rb = e0 >> 5, cb = e0 & 31;

  const __hip_bfloat16* pA  = &A[(size_t)(row0 + ra)*K + ca];
  const __hip_bfloat16* pB0 = &Bt[(size_t)(col0 + rb)*K + cb];
  const __hip_bfloat16* pB1 = &Bt[(size_t)(col0 + rb + 64)*K + cb];

  // prologue: stage tile 0 into buffer 0
  glds16(pA,  (char*)&As[0][0] + w*1024);
  glds16(pB0, (char*)&Bs[0][0] + w*1024);
  glds16(pB1, (char*)&Bs[0][0] + 4096 + w*1024);
  __syncthreads();

  int cur = 0;
  for (int k0 = 0; k0 < K; k0 += 32) {
    if (k0 + 32 < K) {   // issue next-tile stage BEFORE compute (T3 minimum)
      glds16(pA  + k0 + 32, (char*)&As[cur^1][0] + w*1024);
      glds16(pB0 + k0 + 32, (char*)&Bs[cur^1][0] + w*1024);
      glds16(pB1 + k0 + 32, (char*)&Bs[cur^1][0] + 4096 + w*1024);
    }
    bf16x8 af[2], bfv[4];
    #pragma unroll
    for (int m = 0; m < 2; ++m)
      af[m] = *(const bf16x8*)&As[cur][(wr*32 + m*16 + fr)*32 + fq*8];
    #pragma unroll
    for (int n = 0; n < 4; ++n)
      bfv[n] = *(const bf16x8*)&Bs[cur][(wc*64 + n*16 + fr)*32 + fq*8];
    #pragma unroll
    for (int m = 0; m < 2; ++m)
      #pragma unroll
      for (int n = 0; n < 4; ++n)
        acc[m][n] = __builtin_amdgcn_mfma_f32_16x16x32_bf16(af[m], bfv[n], acc[m][n], 0, 0, 0);
    __syncthreads();   // auto vmcnt(0): next-tile stage (hidden under MFMA) lands
    cur ^= 1;
  }

  #pragma unroll
  for (int n = 0; n < 4; ++n) {
    const int ccol = col0 + wc*64 + n*16 + fr;
    #pragma unroll
    for (int m = 0; m < 2; ++m) {
      #pragma unroll
      for (int r = 0; r < 4; ++r) {
        const int crow = row0 + wr*32 + m*16 + fq*4 + r;
        float v = acc[m][n][r];
        if (EPI == 0) {
          Cf[(size_t)crow*N + ccol] = v;
        } else if (EPI == 2) {
          Cb[(size_t)crow*N + ccol] = __float2bfloat16(v + bias[ccol]);
        } else { // EPI == 3
          if (ccol < NCOL)       Cf[(size_t)crow*NCOL + ccol] = v;
          else if (ccol >= 3200) Cb[(size_t)crow*128 + (ccol - 3200)] = __float2bfloat16(siluf(v));
        }
      }
    }
  }
}

// ---------------- fused actv (silu+l2norm q/k, g, beta) + dynamic conv -----
__global__ __launch_bounds__(256) void ac_k(const float* __restrict__ qkvabz,
    const float* __restrict__ A_log, const float* __restrict__ dt_bias,
    const __hip_bfloat16* __restrict__ kern, const float* __restrict__ conv_state,
    float* __restrict__ kn, unsigned short* __restrict__ qnb,
    unsigned short* __restrict__ knb,
    float* __restrict__ g, float* __restrict__ beta, float* __restrict__ vconv)
{
  if (blockIdx.x < 4096) {
    int gid = blockIdx.x*4 + (threadIdx.x >> 6);
    int lane = threadIdx.x & 63;
    int row = gid >> 3; int h = gid & 7;
    const float* base = qkvabz + (size_t)row * NCOL;
    float qv = base[h*64 + lane];
    float kv = base[TKD + h*64 + lane];
    float sq = siluf(qv), sk = siluf(kv);
    float ssq = sq*sq, ssk = sk*sk;
    #pragma unroll
    for (int o = 32; o; o >>= 1) { ssq += __shfl_xor(ssq, o); ssk += __shfl_xor(ssk, o); }
    float qn_v = sq * rsqrtf(ssq + 1e-6f) * 0.125f;
    float kn_v = sk * rsqrtf(ssk + 1e-6f);
    size_t idx = (size_t)row*TKD + h*64 + lane;
    kn[idx]  = kn_v;
    qnb[idx] = f2bu(qn_v);
    knb[idx] = f2bu(kn_v);
    if (lane == 0) {
      float av = base[2048 + h] + dt_bias[h];
      float sp = fmaxf(av, 0.f) + log1pf(expf(-fabsf(av)));
      g[(size_t)row*NH + h] = -expf(A_log[h]) * sp;
      float bv = base[2056 + h];
      beta[(size_t)row*NH + h] = sigm(bv);
    }
  } else {
    int idx = (blockIdx.x - 4096)*256 + threadIdx.x;
    int c = idx & (TVD-1);
    int bs = idx >> 10;
    int s = bs & (SEQ-1); int b = bs >> 10;
    ushort4 kf = *(const ushort4*)&kern[(size_t)idx * 4];
    float kj[4] = { b2f(kf.x), b2f(kf.y), b2f(kf.z), b2f(kf.w) };
    float acc = 0.f;
    #pragma unroll
    for (int j = 0; j < 4; ++j) {
      int i = s + j;
      float xv = (i < 3) ? conv_state[((size_t)b*TVD + c)*3 + i]
                         : qkvabz[((size_t)(b*SEQ + (i-3)))*NCOL + TKD*2 + c];
      acc = fmaf(xv, kj[j], acc);
    }
    vconv[idx] = siluf(acc);
  }
}

// ============ chunked gated delta rule =====================================
// Phase A: MFMA A-build + register-column trisolve + fp32 D/b
__global__ __launch_bounds__(256) void chunkA_k(const float* __restrict__ kn,
   const unsigned short* __restrict__ knb,
   const float* __restrict__ vconv, const float* __restrict__ gb,
   const float* __restrict__ bb, float* __restrict__ Gcbuf,
   float* __restrict__ Dbuf, float* __restrict__ Bvec,
   unsigned short* __restrict__ UvT, unsigned short* __restrict__ WnTb)
{
  const int blk = blockIdx.x;
  const int bh = blk >> 4, c = blk & 15;
  const int b = bh >> 3, h = bh & 7;
  const int tid = threadIdx.x;
  const int w = tid >> 6, l = tid & 63;
  const int fr = l & 15, fq = l >> 4;
  const int row0 = b*SEQ + c*64;

  __shared__ unsigned short Kb[64*72];
  __shared__ float Xv[64][132];
  __shared__ float Xw[64][68];
  __shared__ float AK[64][68];
  __shared__ float Gsh[64], Bsh[64];

  #pragma unroll
  for (int j = 0; j < 2; ++j) {
    int lin = tid + j*256; int t = lin >> 3, dq = (lin & 7)*8;
    *(uint4*)&Kb[t*72+dq] = *(const uint4*)&knb[(size_t)(row0+t)*TKD + h*64 + dq];
  }
  #pragma unroll
  for (int i = 0; i < 8; ++i) {
    int lin = tid + i*256; int t = lin >> 5, v4 = (lin & 31)*4;
    float4 vv = *(const float4*)&vconv[(size_t)(row0+t)*TVD + h*128 + v4];
    Xv[t][v4]=vv.x; Xv[t][v4+1]=vv.y; Xv[t][v4+2]=vv.z; Xv[t][v4+3]=vv.w;
  }
  if (tid < 64) {
    float gv = gb[(size_t)(row0+tid)*NH + h];
    #pragma unroll
    for (int o = 1; o < 64; o <<= 1) {
      float oth = __shfl_up(gv, o);
      if (tid >= o) gv += oth;
    }
    Gsh[tid] = gv;
    Bsh[tid] = bb[(size_t)(row0+tid)*NH + h];
    Gcbuf[(size_t)blk*64 + tid] = gv;
  }
  __syncthreads();

  {
    f32x4 accS[4];
    #pragma unroll
    for (int n = 0; n < 4; ++n) accS[n] = (f32x4){0.f,0.f,0.f,0.f};
    #pragma unroll
    for (int k0 = 0; k0 < 2; ++k0) {
      bf16x8 a = *(const bf16x8*)&Kb[(w*16+fr)*72 + k0*32 + fq*8];
      #pragma unroll
      for (int n = 0; n < 4; ++n) {
        bf16x8 bb2 = *(const bf16x8*)&Kb[(n*16+fr)*72 + k0*32 + fq*8];
        accS[n] = __builtin_amdgcn_mfma_f32_16x16x32_bf16(a, bb2, accS[n], 0, 0, 0);
      }
    }
    #pragma unroll
    for (int n = 0; n < 4; ++n)
      #pragma unroll
      for (int r = 0; r < 4; ++r) {
        int t = w*16 + fq*4 + r, s = n*16 + fr;
        AK[t][s] = (s < t) ? Bsh[t]*expf(Gsh[t]-Gsh[s])*accS[n][r] : 0.f;
      }
  }
  #pragma unroll
  for (int i = 0; i < 4; ++i) {
    int lin = tid + i*256; int t = lin >> 4, d4 = (lin & 15)*4;
    float4 kv = *(const float4*)&kn[(size_t)(row0+t)*TKD + h*64 + d4];
    float f = Bsh[t]*expf(Gsh[t]);
    Xw[t][d4+0]=f*kv.x; Xw[t][d4+1]=f*kv.y; Xw[t][d4+2]=f*kv.z; Xw[t][d4+3]=f*kv.w;
  }
  __syncthreads();

  if (tid < 192) {
    float x[64];
    if (tid < 128) {
      #pragma unroll
      for (int t = 0; t < 64; ++t) x[t] = Bsh[t]*Xv[t][tid];
    } else {
      #pragma unroll
      for (int t = 0; t < 64; ++t) x[t] = Xw[t][tid-128];
    }
    #pragma unroll
    for (int t = 1; t < 64; ++t) {
      float a0=0.f, a1=0.f, a2=0.f, a3=0.f;
      #pragma unroll
      for (int s4 = 0; s4 < (t+3)/4; ++s4) {
        float4 av = *(const float4*)&AK[t][s4*4];
        a0 = fmaf(av.x, x[s4*4+0], a0);
        a1 = fmaf(av.y, x[s4*4+1], a1);
        a2 = fmaf(av.z, x[s4*4+2], a2);
        a3 = fmaf(av.w, x[s4*4+3], a3);
      }
      x[t] -= (a0+a1)+(a2+a3);
    }
    if (tid < 128) {
      #pragma unroll
      for (int t = 0; t < 64; ++t) Xv[t][tid] = x[t];
    } else {
      #pragma unroll
      for (int t = 0; t < 64; ++t) Xw[t][tid-128] = x[t];
    }
  }
  __syncthreads();

  const float Gtot = Gsh[63];
  #pragma unroll
  for (int i = 0; i < 4; ++i) {
    int lin = tid + i*256; int t = lin >> 4, d4 = (lin & 15)*4;
    float4 kv = *(const float4*)&kn[(size_t)(row0+t)*TKD + h*64 + d4];
    float f = expf(Gtot - Gsh[t]);
    AK[t][d4+0]=f*kv.x; AK[t][d4+1]=f*kv.y; AK[t][d4+2]=f*kv.z; AK[t][d4+3]=f*kv.w;
  }
  __syncthreads();

  {
    const int d1b = (tid >> 4)*4, d2b = (tid & 15)*4;
    float dacc[4][4] = {};
    #pragma unroll 8
    for (int t = 0; t < 64; ++t) {
      float4 kw = *(const float4*)&AK[t][d1b];
      float4 wv = *(const float4*)&Xw[t][d2b];
      float kwa[4] = {kw.x,kw.y,kw.z,kw.w};
      float wva[4] = {wv.x,wv.y,wv.z,wv.w};
      #pragma unroll
      for (int i = 0; i < 4; ++i)
        #pragma unroll
        for (int j = 0; j < 4; ++j)
          dacc[i][j] = fmaf(kwa[i], wva[j], dacc[i][j]);
    }
    const float eG = expf(Gtot);
    #pragma unroll
    for (int i = 0; i < 4; ++i) {
      float vals[4];
      #pragma unroll
      for (int j = 0; j < 4; ++j) {
        float v = -dacc[i][j];
        if (d1b + i == d2b + j) v += eG;
        vals[j] = v;
      }
      *(float4*)&Dbuf[(size_t)blk*4096 + (d1b+i)*64 + d2b] =
        make_float4(vals[0],vals[1],vals[2],vals[3]);
    }
  }
  {
    const int d1b = (tid >> 4)*4, vb = (tid & 15)*8;
    float bacc[4][8] = {};
    #pragma unroll 4
    for (int t = 0; t < 64; ++t) {
      float4 kw = *(const float4*)&AK[t][d1b];
      float4 u0 = *(const float4*)&Xv[t][vb];
      float4 u1 = *(const float4*)&Xv[t][vb+4];
      float kwa[4] = {kw.x,kw.y,kw.z,kw.w};
      float ua[8] = {u0.x,u0.y,u0.z,u0.w,u1.x,u1.y,u1.z,u1.w};
      #pragma unroll
      for (int i = 0; i < 4; ++i)
        #pragma unroll
        for (int j = 0; j < 8; ++j)
          bacc[i][j] = fmaf(kwa[i], ua[j], bacc[i][j]);
    }
    #pragma unroll
    for (int i = 0; i < 4; ++i) {
      *(float4*)&Bvec[(size_t)blk*8192 + (d1b+i)*128 + vb] =
        make_float4(bacc[i][0],bacc[i][1],bacc[i][2],bacc[i][3]);
      *(float4*)&Bvec[(size_t)blk*8192 + (d1b+i)*128 + vb + 4] =
        make_float4(bacc[i][4],bacc[i][5],bacc[i][6],bacc[i][7]);
    }
  }

  {
    #pragma unroll
    for (int i = 0; i < 32; ++i) {
      int v = w*32 + i;
      UvT[(size_t)blk*8192 + v*64 + l] = f2bu(Xv[l][v]);
    }
    #pragma unroll
    for (int i = 0; i < 16; ++i) {
      int d = w*16 + i;
      WnTb[(size_t)blk*4096 + d*64 + l] = f2bu(-Xw[l][d]);
    }
  }
}

// Phase B: h_{c+1} = D_c h_c + b_c ; 128 blocks (bh x 8 vgroups of 16)
__global__ __launch_bounds__(256) void chunkB2_k(const float* __restrict__ Dbuf,
   const float* __restrict__ Bvec, const float* __restrict__ init,
   unsigned short* __restrict__ HcT)
{
  const int blk = blockIdx.x;
  const int bh = blk >> 3, grp = blk & 7;
  const int v0 = grp*16;
  const int tid = threadIdx.x;
  const int v = tid & 15;
  const int d1b = (tid >> 4) * 4;
  __shared__ float DT[64][68];
  __shared__ float bsh[64][17];
  __shared__ float hsh[64][17];

  float hreg[4];
  #pragma unroll
  for (int j = 0; j < 4; ++j) {
    hreg[j] = init[((size_t)bh*64 + d1b + j)*128 + v0 + v];
    hsh[d1b + j][v] = hreg[j];
  }
  float Dreg[16], breg[4];
  {
    const float* Dp = Dbuf + (size_t)(bh*16)*4096;
    const float* bp = Bvec + (size_t)(bh*16)*8192;
    #pragma unroll
    for (int i = 0; i < 16; ++i) Dreg[i] = Dp[tid + i*256];
    #pragma unroll
    for (int i = 0; i < 4; ++i)  breg[i] = bp[(size_t)((tid>>4) + i*16)*128 + v0 + v];
  }
  #pragma unroll
  for (int i = 0; i < 16; ++i) {
    int cell = tid + i*256; DT[cell & 63][cell >> 6] = Dreg[i];
  }
  #pragma unroll
  for (int i = 0; i < 4; ++i) bsh[(tid>>4) + i*16][v] = breg[i];
  __syncthreads();

  for (int c = 0; c < 16; ++c) {
    if (c < 15) {
      const float* Dn = Dbuf + (size_t)(bh*16 + c + 1)*4096;
      const float* bn = Bvec + (size_t)(bh*16 + c + 1)*8192;
      #pragma unroll
      for (int i = 0; i < 16; ++i) Dreg[i] = Dn[tid + i*256];
      #pragma unroll
      for (int i = 0; i < 4; ++i)  breg[i] = bn[(size_t)((tid>>4) + i*16)*128 + v0 + v];
    }
    #pragma unroll
    for (int j = 0; j < 4; ++j)
      HcT[(size_t)(bh*16 + c)*8192 + (size_t)(v0+v)*64 + d1b + j] = f2bu(hreg[j]);
    float nh[4];
    #pragma unroll
    for (int j = 0; j < 4; ++j) nh[j] = bsh[d1b + j][v];
    #pragma unroll 8
    for (int d2 = 0; d2 < 64; ++d2) {
      float hv = hsh[d2][v];
      float4 dv = *(const float4*)&DT[d2][d1b];
      nh[0] = fmaf(dv.x, hv, nh[0]);
      nh[1] = fmaf(dv.y, hv, nh[1]);
      nh[2] = fmaf(dv.z, hv, nh[2]);
      nh[3] = fmaf(dv.w, hv, nh[3]);
    }
    __syncthreads();
    #pragma unroll
    for (int j = 0; j < 4; ++j) { hreg[j] = nh[j]; hsh[d1b + j][v] = nh[j]; }
    if (c < 15) {
      #pragma unroll
      for (int i = 0; i < 16; ++i) {
        int cell = tid + i*256; DT[cell & 63][cell >> 6] = Dreg[i];
      }
      #pragma unroll
      for (int i = 0; i < 4; ++i) bsh[(tid>>4) + i*16][v] = breg[i];
    }
    __syncthreads();
  }
}

// Phase C (MFMA): S = decayed-masked QK^T; Qt = E.Q - S Wt; o = Qt h + S U
__global__ __launch_bounds__(256) void chunkC_k(
   const unsigned short* __restrict__ qnb, const unsigned short* __restrict__ knb,
   const unsigned short* __restrict__ UvT, const unsigned short* __restrict__ WnTb,
   const float* __restrict__ Gcbuf, const unsigned short* __restrict__ HcT,
   float* __restrict__ oattn)
{
  const int blk = blockIdx.x; const int bh = blk >> 4, c = blk & 15;
  const int b = bh >> 3, h = bh & 7;
  const int row0 = b*SEQ + c*64;
  const int tid = threadIdx.x;
  const int w = tid >> 6, l = tid & 63;
  const int fr = l & 15, fq = l >> 4;

  __shared__ unsigned short Qs[64*72];
  __shared__ unsigned short Ks[64*72];
  __shared__ unsigned short Ws[64*72];
  __shared__ unsigned short hT[128*72];
  __shared__ unsigned short UT[128*72];
  __shared__ unsigned short Ss[64*72];
  __shared__ float Gsh[64], Esh[64];

  #pragma unroll
  for (int j = 0; j < 2; ++j) {
    int lin = tid + j*256; int t = lin >> 3, dq = (lin & 7)*8;
    *(uint4*)&Qs[t*72+dq] = *(const uint4*)&qnb[(size_t)(row0+t)*TKD + h*64 + dq];
    *(uint4*)&Ks[t*72+dq] = *(const uint4*)&knb[(size_t)(row0+t)*TKD + h*64 + dq];
    *(uint4*)&Ws[t*72+dq] = *(const uint4*)&WnTb[(size_t)blk*4096 + t*64 + dq];
  }
  #pragma unroll
  for (int j = 0; j < 4; ++j) {
    int lin = tid + j*256; int v = lin >> 3, dq = (lin & 7)*8;
    *(uint4*)&hT[v*72+dq] = *(const uint4*)&HcT[(size_t)blk*8192 + (size_t)v*64 + dq];
    *(uint4*)&UT[v*72+dq] = *(const uint4*)&UvT[(size_t)blk*8192 + (size_t)v*64 + dq];
  }
  if (tid < 64) { float g = Gcbuf[(size_t)blk*64 + tid]; Gsh[tid] = g; Esh[tid] = expf(g); }
  __syncthreads();

  f32x4 accS[4];
  #pragma unroll
  for (int n = 0; n < 4; ++n) accS[n] = (f32x4){0.f,0.f,0.f,0.f};
  #pragma unroll
  for (int k0 = 0; k0 < 2; ++k0) {
    bf16x8 a = *(const bf16x8*)&Qs[(w*16+fr)*72 + k0*32 + fq*8];
    #pragma unroll
    for (int n = 0; n < 4; ++n) {
      bf16x8 bb = *(const bf16x8*)&Ks[(n*16+fr)*72 + k0*32 + fq*8];
      accS[n] = __builtin_amdgcn_mfma_f32_16x16x32_bf16(a, bb, accS[n], 0, 0, 0);
    }
  }
  #pragma unroll
  for (int n = 0; n < 4; ++n)
    #pragma unroll
    for (int r = 0; r < 4; ++r) {
      int t = w*16 + fq*4 + r, s = n*16 + fr;
      float val = (s <= t) ? expf(Gsh[t]-Gsh[s]) * accS[n][r] : 0.f;
      Ss[t*72 + s] = f2bu(val);
    }

  f32x4 accQ[4];
  #pragma unroll
  for (int n = 0; n < 4; ++n) {
    #pragma unroll
    for (int r = 0; r < 4; ++r) {
      int t = w*16 + fq*4 + r, d = n*16 + fr;
      accQ[n][r] = Esh[t] * b2f(Qs[t*72 + d]);
    }
    #pragma unroll
    for (int k0 = 0; k0 < 2; ++k0) {
      bf16x8 a = *(const bf16x8*)&Ss[(w*16+fr)*72 + k0*32 + fq*8];
      bf16x8 bb = *(const bf16x8*)&Ws[(n*16+fr)*72 + k0*32 + fq*8];
      accQ[n] = __builtin_amdgcn_mfma_f32_16x16x32_bf16(a, bb, accQ[n], 0, 0, 0);
    }
  }
  __syncthreads();

  #pragma unroll
  for (int n = 0; n < 4; ++n)
    #pragma unroll
    for (int r = 0; r < 4; ++r) {
      int t = w*16 + fq*4 + r, d = n*16 + fr;
      Ks[t*72 + d] = f2bu(accQ[n][r]);
    }

  #pragma unroll
  for (int n = 0; n < 8; ++n) {
    f32x4 acc = (f32x4){0.f,0.f,0.f,0.f};
    #pragma unroll
    for (int k0 = 0; k0 < 2; ++k0) {
      bf16x8 a1 = *(const bf16x8*)&Ks[(w*16+fr)*72 + k0*32 + fq*8];
      bf16x8 b1 = *(const bf16x8*)&hT[(n*16+fr)*72 + k0*32 + fq*8];
      acc = __builtin_amdgcn_mfma_f32_16x16x32_bf16(a1, b1, acc, 0, 0, 0);
      bf16x8 a2 = *(const bf16x8*)&Ss[(w*16+fr)*72 + k0*32 + fq*8];
      bf16x8 b2v = *(const bf16x8*)&UT[(n*16+fr)*72 + k0*32 + fq*8];
      acc = __builtin_amdgcn_mfma_f32_16x16x32_bf16(a2, b2v, acc, 0, 0, 0);
    }
    #pragma unroll
    for (int r = 0; r < 4; ++r) {
      int t = w*16 + fq*4 + r, v = n*16 + fr;
      oattn[(size_t)(row0+t)*TVD + h*128 + v] = acc[r];
    }
  }
}

// ---------------- gated RMSNorm -> bf16 ------------------------------------
__global__ __launch_bounds__(256) void norm_k(const float* __restrict__ oattn,
   const float* __restrict__ qkvabz, const float* __restrict__ onw,
   __hip_bfloat16* __restrict__ ofin)
{
  int gid = blockIdx.x*4 + (threadIdx.x >> 6);
  int lane = threadIdx.x & 63;
  int row = gid >> 3; int h = gid & 7;
  size_t ob = (size_t)row*TVD + h*128;
  float2 ov = *(const float2*)&oattn[ob + lane*2];
  float2 zv = *(const float2*)&qkvabz[(size_t)row*NCOL + 2064 + h*128 + lane*2];
  float g0 = ov.x * siluf(zv.x), g1 = ov.y * siluf(zv.y);
  float ss = g0*g0 + g1*g1;
  #pragma unroll
  for (int o = 32; o; o >>= 1) ss += __shfl_xor(ss, o);
  float r = rsqrtf(ss * (1.f/128.f) + 1e-6f);
  ofin[ob + lane*2]     = __float2bfloat16(g0 * r * onw[lane*2]);
  ofin[ob + lane*2 + 1] = __float2bfloat16(g1 * r * onw[lane*2+1]);
}

extern "C" void kernel_launch(void* const* d_in, const int* in_sizes, int n_in,
                              void* d_out, int out_size, void* d_ws, size_t ws_size,
                              hipStream_t stream) {
  const float* hidden     = (const float*)d_in[0];
  const float* Wqkvabz    = (const float*)d_in[1];
  const float* A_log      = (const float*)d_in[2];
  const float* dt_bias    = (const float*)d_in[3];
  const float* conv_state = (const float*)d_in[4];
  const float* w1         = (const float*)d_in[5];
  const float* w2         = (const float*)d_in[6];
  const float* b2         = (const float*)d_in[7];
  const float* init_state = (const float*)d_in[8];
  const float* o_norm_w   = (const float*)d_in[9];
  const float* W_o        = (const float*)d_in[10];
  float* out = (float*)d_out;

  float* ws = (float*)d_ws;
  float* qkvabz = ws;                                  // 6,324,224 f
  float* kern   = qkvabz + (size_t)6324224;            // 8,388,608 f region
  float* qn     = kern   + (size_t)8388608;            // spare
  float* kn     = qn     + (size_t)1048576;            // 1,048,576
  float* gbuf   = kn     + (size_t)1048576;            // 16,384
  float* bbuf   = gbuf   + (size_t)16384;              // 16,384
  float* vconv  = bbuf   + (size_t)16384;              // 2,097,152
  float* bfpool = vconv  + (size_t)2097152;
  __hip_bfloat16* hidden_bf = (__hip_bfloat16*)bfpool;       // 4,194,304 e
  __hip_bfloat16* w1t   = hidden_bf + (size_t)4194304;       // (spare)
  __hip_bfloat16* w2t   = w1t + (size_t)262144;
  __hip_bfloat16* Wot   = w2t + (size_t)524288;
  __hip_bfloat16* x1sb  = Wot + (size_t)2097152;
  __hip_bfloat16* ofinb = x1sb + (size_t)262144;
  float* Gcbuf  = (float*)(ofinb + (size_t)2097152);         // 16,384 f
  // aliases inside the kern region:
  __hip_bfloat16* Wcat   = (__hip_bfloat16*)kern;            // [3328][2048] bf16 (13.6 MB)
  __hip_bfloat16* kernbf = (__hip_bfloat16*)kern;            // 8,388,608 u16 (w2 out)
  float* oattn  = kern;                                      // [0, 2M)
  float* Dbuf   = kern + (size_t)2097152;                    // [2M, 3M)
  float* Bvec   = kern + (size_t)3145728;                    // [3M, 5M)
  unsigned short* UvTb  = (unsigned short*)(kern + (size_t)5242880);  // [5M, 6M)
  unsigned short* WnTbb = (unsigned short*)(kern + (size_t)6291456);  // [6M, 6.5M)
  unsigned short* qnb   = (unsigned short*)(kern + (size_t)6815744);  // [6.5M, 7M)
  unsigned short* knb   = (unsigned short*)(kern + (size_t)7340032);  // [7M, 7.5M)
  unsigned short* HcTb  = (unsigned short*)vconv;            // vconv dead after chunkA

  dim3 blk(256);
  prep_k<<<13312, blk, 0, stream>>>(Wqkvabz, w1, w2, W_o, hidden,
                                    Wcat, w2t, Wot, (unsigned short*)hidden_bf);
  // fused qkvabz + w1 GEMM: M=2048, N=3328, K=2048 -> grid 26x32 = 832
  mgemm_k<3><<<dim3(832),  blk, 0, stream>>>(hidden_bf, Wcat, nullptr, qkvabz, x1sb, 2048, 3328, 2048, 26);
  // w2 GEMM: M=2048, N=4096, K=128 -> grid 32x32 = 1024
  mgemm_k<2><<<dim3(1024), blk, 0, stream>>>(x1sb, w2t, b2, nullptr, kernbf, 2048, 4096, 128, 32);
  // fused actv + conv
  ac_k<<<12288, blk, 0, stream>>>(qkvabz, A_log, dt_bias, kernbf, conv_state,
                                  kn, qnb, knb, gbuf, bbuf, vconv);
  chunkA_k<<<256, blk, 0, stream>>>(kn, knb, vconv, gbuf, bbuf, Gcbuf, Dbuf, Bvec, UvTb, WnTbb);
  chunkB2_k<<<128, blk, 0, stream>>>(Dbuf, Bvec, init_state, HcTb);
  chunkC_k<<<256, blk, 0, stream>>>(qnb, knb, UvTb, WnTbb, Gcbuf, HcTb, oattn);
  norm_k<<<4096, blk, 0, stream>>>(oattn, qkvabz, o_norm_w, ofinb);
  // out GEMM: M=2048, N=2048, K=1024 -> grid 16x32 = 512
  mgemm_k<0><<<dim3(512),  blk, 0, stream>>>(ofinb, Wot, nullptr, out, nullptr, 2048, 2048, 1024, 16);
}